// Round 1
// baseline (1314.451 us; speedup 1.0000x reference)
//
#include <hip/hip_runtime.h>
#include <math.h>

// Problem dims
#define BSZ 256
#define DIM 128
#define NHD 4
#define NPATCH 196
#define NACT 15

__device__ __forceinline__ float wred_sum(float v) {
#pragma unroll
    for (int m = 1; m < 64; m <<= 1) v += __shfl_xor(v, m, 64);
    return v;
}
__device__ __forceinline__ float wred_max(float v) {
#pragma unroll
    for (int m = 1; m < 64; m <<= 1) v = fmaxf(v, __shfl_xor(v, m, 64));
    return v;
}

// ---------------------------------------------------------------------------
// Fused patchify + patch-embed GEMM.
// grid = (14 [h], 256 [b]), block = 256.
// Stages image[b, :, h*16:(h+1)*16, :] (3*16*224 floats, contiguous rows) in
// LDS, then each thread computes 2 patches x 4 output cols over K=768.
// src[(p*256+b)*128 + d] = sum_k X[b,p,k]*patch_W[k,d] + patch_b[d] + pos_emb[p,d]
// ---------------------------------------------------------------------------
__global__ __launch_bounds__(256) void k_patch_embed(
    const float* __restrict__ img, const float* __restrict__ pw,
    const float* __restrict__ pb, const float* __restrict__ pe,
    float* __restrict__ src)
{
    __shared__ float xi[3 * 16 * 224];  // 10752 floats = 43 KB
    const int h = blockIdx.x;
    const int b = blockIdx.y;
    const int t = threadIdx.x;
    const float* gsrc = img + (size_t)b * (3 * 224 * 224) + h * (16 * 224);
#pragma unroll
    for (int c = 0; c < 3; ++c) {
        const float* g = gsrc + c * (224 * 224);
        float* d = xi + c * 3584;
        for (int i = t; i < 3584; i += 256) d[i] = g[i];
    }
    __syncthreads();

    const int tx = t & 31;   // output cols d = tx*4 .. tx*4+3
    const int ty = t >> 5;   // patches pw0 = ty, pw1 = ty+8
    const bool has1 = (ty + 8) < 14;
    const int off0 = ty * 16;
    const int off1 = has1 ? (ty + 8) * 16 : 0;  // keep index in-bounds; result discarded

    float4 a0acc = make_float4(0.f, 0.f, 0.f, 0.f);
    float4 a1acc = make_float4(0.f, 0.f, 0.f, 0.f);
    const float4* wp = (const float4*)(pw) + tx;  // pw[k*128 + tx*4] = wp[k*32]

    int k = 0;
    for (int p1 = 0; p1 < 16; ++p1) {
        const int rowb = p1 * 224;
        for (int p2 = 0; p2 < 16; ++p2) {
            const int xb = rowb + p2;
#pragma unroll
            for (int c = 0; c < 3; ++c, ++k) {
                const float4 wv = wp[k * 32];
                const float a0 = xi[c * 3584 + xb + off0];
                const float a1 = xi[c * 3584 + xb + off1];
                a0acc.x += a0 * wv.x; a0acc.y += a0 * wv.y;
                a0acc.z += a0 * wv.z; a0acc.w += a0 * wv.w;
                a1acc.x += a1 * wv.x; a1acc.y += a1 * wv.y;
                a1acc.z += a1 * wv.z; a1acc.w += a1 * wv.w;
            }
        }
    }

    const float4 pbv = *(const float4*)(pb + tx * 4);
    {
        const int p0 = h * 14 + ty;
        const float4 pev = *(const float4*)(pe + (size_t)p0 * 128 + tx * 4);
        float4 o;
        o.x = a0acc.x + pbv.x + pev.x; o.y = a0acc.y + pbv.y + pev.y;
        o.z = a0acc.z + pbv.z + pev.z; o.w = a0acc.w + pbv.w + pev.w;
        *(float4*)(src + ((size_t)p0 * 256 + b) * 128 + tx * 4) = o;
    }
    if (has1) {
        const int p1i = h * 14 + ty + 8;
        const float4 pev = *(const float4*)(pe + (size_t)p1i * 128 + tx * 4);
        float4 o;
        o.x = a1acc.x + pbv.x + pev.x; o.y = a1acc.y + pbv.y + pev.y;
        o.z = a1acc.z + pbv.z + pev.z; o.w = a1acc.w + pbv.w + pev.w;
        *(float4*)(src + ((size_t)p1i * 256 + b) * 128 + tx * 4) = o;
    }
}

// ---------------------------------------------------------------------------
// Generic tiled GEMM: C[M,N] = act(A[M,K] @ W[K,N'] + bias), K in {64,128},
// M % 64 == 0, tile 64x64 per block (256 threads, 4x4 register tile/thread).
// W indexed with runtime row stride (supports column-slices of packed QKV).
// grid = (M/64, Ncall/64).
// ---------------------------------------------------------------------------
__global__ __launch_bounds__(256) void k_gemm64(
    const float* __restrict__ A, int K,
    const float* __restrict__ W, int wstride,
    const float* __restrict__ bias,
    float* __restrict__ C, int cstride, int relu)
{
    __shared__ float As[64 * 132];  // stride K+4 (<=132)
    __shared__ float Ws[128 * 68];  // stride 68
    const int t = threadIdx.x;
    const int r0 = blockIdx.x * 64;
    const int n0 = blockIdx.y * 64;
    const int as = K + 4;
    const int lg = (K == 128) ? 5 : 4;   // log2(K/4)
    const int kmask = (K >> 2) - 1;

    for (int idx = t; idx < (K << 4); idx += 256) {  // 64*K/4 float4s
        const int row = idx >> lg;
        const int kk = idx & kmask;
        const float4 v = *(const float4*)(A + (size_t)(r0 + row) * K + kk * 4);
        *(float4*)(&As[row * as + kk * 4]) = v;
    }
    for (int idx = t; idx < (K << 4); idx += 256) {  // K*64/4 float4s
        const int kk = idx >> 4;
        const int nq = idx & 15;
        const float4 v = *(const float4*)(W + (size_t)kk * wstride + n0 + nq * 4);
        *(float4*)(&Ws[kk * 68 + nq * 4]) = v;
    }
    __syncthreads();

    const int tx = t & 15;
    const int ty = t >> 4;
    float4 acc[4];
#pragma unroll
    for (int i = 0; i < 4; ++i) acc[i] = make_float4(0.f, 0.f, 0.f, 0.f);

    const float* arow = &As[(ty * 4) * as];
    for (int k = 0; k < K; ++k) {
        const float4 wv = *(const float4*)(&Ws[k * 68 + tx * 4]);
#pragma unroll
        for (int i = 0; i < 4; ++i) {
            const float av = arow[i * as + k];
            acc[i].x += av * wv.x; acc[i].y += av * wv.y;
            acc[i].z += av * wv.z; acc[i].w += av * wv.w;
        }
    }

    const float4 bv = *(const float4*)(bias + n0 + tx * 4);
#pragma unroll
    for (int i = 0; i < 4; ++i) {
        float4 o;
        o.x = acc[i].x + bv.x; o.y = acc[i].y + bv.y;
        o.z = acc[i].z + bv.z; o.w = acc[i].w + bv.w;
        if (relu) {
            o.x = fmaxf(o.x, 0.f); o.y = fmaxf(o.y, 0.f);
            o.z = fmaxf(o.z, 0.f); o.w = fmaxf(o.w, 0.f);
        }
        *(float4*)(C + (size_t)(r0 + ty * 4 + i) * cstride + n0 + tx * 4) = o;
    }
}

// ---------------------------------------------------------------------------
// Fused attention: one block per (b, h). K/V rows staged in LDS; each wave
// owns q-rows (jq = wave + 4*i); score row distributed over 64 lanes,
// online softmax via wave shuffles, PV via LDS p-buffer. Lk <= 196.
// out[(jq*256+b)*128 + h*32 + d], token strides parameterized.
// ---------------------------------------------------------------------------
__global__ __launch_bounds__(256) void k_attn(
    const float* __restrict__ qp, int qstride,
    const float* __restrict__ kvp, int kvstride, int koff, int voff,
    float* __restrict__ op, int Lq, int Lk, float scale)
{
    __shared__ float Kl[196 * 36];    // padded stride 36 -> conflict-free b128
    __shared__ float Vl[196 * 32];
    __shared__ float pbuf[4][256];
    const int bh = blockIdx.x;
    const int b = bh >> 2;
    const int h = bh & 3;
    const int t = threadIdx.x;
    const int w = t >> 6;
    const int l = t & 63;

    for (int idx = t; idx < Lk * 8; idx += 256) {
        const int j = idx >> 3;
        const int kq = idx & 7;
        const size_t row = ((size_t)j * 256 + b) * kvstride + h * 32 + kq * 4;
        *(float4*)(&Kl[j * 36 + kq * 4]) = *(const float4*)(kvp + row + koff);
        *(float4*)(&Vl[j * 32 + kq * 4]) = *(const float4*)(kvp + row + voff);
    }
    if ((Lk & 1) && t < 8) *(float4*)(&Vl[Lk * 32 + t * 4]) = make_float4(0.f, 0.f, 0.f, 0.f);
    __syncthreads();

    const int Lh = (Lk + 1) >> 1;
    const int half = l >> 5;
    const int kk = l & 31;
    const int jb = half * Lh;

    for (int jq = w; jq < Lq; jq += 4) {
        const float* qrow = qp + ((size_t)jq * 256 + b) * qstride + h * 32;
        float4 q4[8];
#pragma unroll
        for (int kq = 0; kq < 8; ++kq) q4[kq] = *(const float4*)(qrow + kq * 4);

        float s[4];
#pragma unroll
        for (int r = 0; r < 4; ++r) {
            const int j = l + (r << 6);
            float acc = -3.0e38f;
            if (j < Lk) {
                acc = 0.f;
#pragma unroll
                for (int kq = 0; kq < 8; ++kq) {
                    const float4 kv = *(const float4*)(&Kl[j * 36 + kq * 4]);
                    acc += q4[kq].x * kv.x + q4[kq].y * kv.y +
                           q4[kq].z * kv.z + q4[kq].w * kv.w;
                }
                acc *= scale;
            }
            s[r] = acc;
        }
        float m = fmaxf(fmaxf(s[0], s[1]), fmaxf(s[2], s[3]));
        m = wred_max(m);
        float sum = 0.f;
#pragma unroll
        for (int r = 0; r < 4; ++r) {
            const int j = l + (r << 6);
            float p = __expf(s[r] - m);
            if (j >= Lk) p = 0.f;
            pbuf[w][j] = p;
            sum += p;
        }
        sum = wred_sum(sum);
        const float inv = 1.0f / sum;
        __threadfence_block();

        float o = 0.f;
        for (int jj = 0; jj < Lh; ++jj) {
            const float pv = pbuf[w][jb + jj];
            const float vv = Vl[(jb + jj) * 32 + kk];
            o += pv * vv;
        }
        o += __shfl_xor(o, 32, 64);
        o *= inv;
        if (l < 32) op[((size_t)jq * 256 + b) * 128 + h * 32 + l] = o;
        __threadfence_block();
    }
}

// ---------------------------------------------------------------------------
// LayerNorm over D=128, optional residual: out = LN(a [+ r]) * s + bi.
// One wave per token; 4 tokens per block.
// ---------------------------------------------------------------------------
__global__ __launch_bounds__(256) void k_ln(
    const float* __restrict__ a, const float* __restrict__ r,
    const float* __restrict__ s, const float* __restrict__ bi,
    float* __restrict__ o, int ntok)
{
    const int tok = blockIdx.x * 4 + (threadIdx.x >> 6);
    const int l = threadIdx.x & 63;
    float2 x = ((const float2*)a)[(size_t)tok * 64 + l];
    if (r) {
        const float2 rr = ((const float2*)r)[(size_t)tok * 64 + l];
        x.x += rr.x; x.y += rr.y;
    }
    const float mean = wred_sum(x.x + x.y) * (1.f / 128.f);
    const float dx = x.x - mean, dy = x.y - mean;
    const float var = wred_sum(dx * dx + dy * dy) * (1.f / 128.f);
    const float rstd = rsqrtf(var + 1e-5f);
    const float2 sv = ((const float2*)s)[l];
    const float2 bv = ((const float2*)bi)[l];
    float2 out;
    out.x = dx * rstd * sv.x + bv.x;
    out.y = dy * rstd * sv.y + bv.y;
    ((float2*)o)[(size_t)tok * 64 + l] = out;
}

// ---------------------------------------------------------------------------
// Small row GEMM (sketch MLP): one block per row, thread n computes col n.
// K <= 256, N <= 256.
// ---------------------------------------------------------------------------
__global__ __launch_bounds__(256) void k_smallgemm(
    const float* __restrict__ x, int K,
    const float* __restrict__ W, const float* __restrict__ bi,
    float* __restrict__ o, int N, int relu)
{
    __shared__ float xr[256];
    const int row = blockIdx.x;
    const int t = threadIdx.x;
    if (t < K) xr[t] = x[(size_t)row * K + t];
    __syncthreads();
    if (t < N) {
        float acc = bi[t];
        for (int k = 0; k < K; ++k) acc += xr[k] * W[(size_t)k * N + t];
        if (relu) acc = fmaxf(acc, 0.f);
        o[(size_t)row * N + t] = acc;
    }
}

// ---------------------------------------------------------------------------
// Action-token embedding: tgt[i,b,:] = act_W[i,:] + ang*W[15] + px*W[16]
//   + py*W[17] + s3[b] @ W[18:118] + act_b. One block per b, 128 threads (d).
// ---------------------------------------------------------------------------
__global__ __launch_bounds__(128) void k_tgt(
    const float* __restrict__ s3, const float* __restrict__ ang,
    const float* __restrict__ px, const float* __restrict__ py,
    const float* __restrict__ W, const float* __restrict__ bi,
    float* __restrict__ tg)
{
    const int b = blockIdx.x;
    const int d = threadIdx.x;
    float acc = bi[d] + ang[b] * W[15 * 128 + d] + px[b] * W[16 * 128 + d] +
                py[b] * W[17 * 128 + d];
    for (int k = 0; k < 100; ++k) acc += s3[b * 100 + k] * W[(18 + k) * 128 + d];
#pragma unroll
    for (int i = 0; i < 15; ++i)
        tg[((size_t)i * 256 + b) * 128 + d] = acc + W[i * 128 + d];
}

// ---------------------------------------------------------------------------
// Final head: q[b,i] = dot(h[i*256+b, :128], l2_W) + l2_b. One wave per token.
// ---------------------------------------------------------------------------
__global__ __launch_bounds__(256) void k_head(
    const float* __restrict__ hbuf, const float* __restrict__ w2,
    const float* __restrict__ b2, float* __restrict__ out)
{
    const int tok = blockIdx.x * 4 + (threadIdx.x >> 6);
    const int l = threadIdx.x & 63;
    const float2 x = ((const float2*)hbuf)[(size_t)tok * 64 + l];
    const float2 wv = ((const float2*)w2)[l];
    const float v = wred_sum(x.x * wv.x + x.y * wv.y);
    if (l == 0) {
        const int i = tok >> 8;
        const int b = tok & 255;
        out[b * 15 + i] = v + b2[0];
    }
}

// ---------------------------------------------------------------------------
extern "C" void kernel_launch(void* const* d_in, const int* in_sizes, int n_in,
                              void* d_out, int out_size, void* d_ws, size_t ws_size,
                              hipStream_t stream)
{
    (void)in_sizes; (void)n_in; (void)out_size; (void)ws_size;
    const float* image      = (const float*)d_in[0];
    const float* angle      = (const float*)d_in[1];
    const float* pos_x      = (const float*)d_in[2];
    const float* pos_y      = (const float*)d_in[3];
    const float* sk         = (const float*)d_in[4];
    const float* patch_W    = (const float*)d_in[5];
    const float* patch_b    = (const float*)d_in[6];
    const float* pos_emb    = (const float*)d_in[7];
    const float* enc_qkv_W  = (const float*)d_in[8];
    const float* enc_qkv_b  = (const float*)d_in[9];
    const float* enc_out_W  = (const float*)d_in[10];
    const float* enc_out_b  = (const float*)d_in[11];
    const float* enc_ln1_s  = (const float*)d_in[12];
    const float* enc_ln1_b  = (const float*)d_in[13];
    const float* enc_ff1_W  = (const float*)d_in[14];
    const float* enc_ff1_b  = (const float*)d_in[15];
    const float* enc_ff2_W  = (const float*)d_in[16];
    const float* enc_ff2_b  = (const float*)d_in[17];
    const float* enc_ln2_s  = (const float*)d_in[18];
    const float* enc_ln2_b  = (const float*)d_in[19];
    const float* dec_sa_qkv_W = (const float*)d_in[20];
    const float* dec_sa_qkv_b = (const float*)d_in[21];
    const float* dec_sa_out_W = (const float*)d_in[22];
    const float* dec_sa_out_b = (const float*)d_in[23];
    const float* dec_ca_qkv_W = (const float*)d_in[24];
    const float* dec_ca_qkv_b = (const float*)d_in[25];
    const float* dec_ca_out_W = (const float*)d_in[26];
    const float* dec_ca_out_b = (const float*)d_in[27];
    const float* dec_ln1_s  = (const float*)d_in[28];
    const float* dec_ln1_b  = (const float*)d_in[29];
    const float* dec_ln2_s  = (const float*)d_in[30];
    const float* dec_ln2_b  = (const float*)d_in[31];
    const float* dec_ln3_s  = (const float*)d_in[32];
    const float* dec_ln3_b  = (const float*)d_in[33];
    const float* dec_ff1_W  = (const float*)d_in[34];
    const float* dec_ff1_b  = (const float*)d_in[35];
    const float* dec_ff2_W  = (const float*)d_in[36];
    const float* dec_ff2_b  = (const float*)d_in[37];
    const float* dec_norm_s = (const float*)d_in[38];
    const float* dec_norm_b = (const float*)d_in[39];
    const float* sk1_W = (const float*)d_in[40];
    const float* sk1_b = (const float*)d_in[41];
    const float* sk2_W = (const float*)d_in[42];
    const float* sk2_b = (const float*)d_in[43];
    const float* sk3_W = (const float*)d_in[44];
    const float* sk3_b = (const float*)d_in[45];
    const float* act_W = (const float*)d_in[46];
    const float* act_b = (const float*)d_in[47];
    const float* l1_W  = (const float*)d_in[48];
    const float* l1_b  = (const float*)d_in[49];
    const float* l2_W  = (const float*)d_in[50];
    const float* l2_b  = (const float*)d_in[51];

    // Workspace layout (floats). Peak usage ~187 MB.
    float* ws = (float*)d_ws;
    float* S0   = ws;              // src            196*256*128 = 6,422,528
    float* QKVr = ws + 6422528;    // enc QKV        196*256*384 = 19,267,584
    float* T0   = ws + 25690112;   // attn out       6,422,528
    float* T1   = ws + 32112640;   // proj/ff2 out   6,422,528
    float* F1   = ws + 38535168;   // ff1 out        196*256*64 = 3,211,264
    float* M0   = ws + 41746432;   // memory         6,422,528
    float* S1s  = ws + 48168960;   // sketch h1      65,536
    float* S2s  = S1s + 65536;     // sketch h2      65,536
    float* S3s  = S2s + 65536;     // sketch out     25,600
    float* TG   = S3s + 25600;     // tgt            15*256*128 = 491,520
    // Overlays inside the (dead-after-encoder-attn) enc-QKV region:
    float* KV   = QKVr;                 // cross K/V  196*256*256 = 12,845,056
    float* DQKV = QKVr + 12845056;      // dec self QKV 15*256*384 = 1,474,560
    float* DQ   = QKVr + 14319616;      // dec cross Q  491,520
    float* DH   = QKVr + 14811136;      // head hidden  491,520
    float* DT0  = T0;
    float* DT1  = T1;
    float* DF1  = F1;

    const float rs = 0.17677669529663687f;  // 1/sqrt(32)

    // ---- encoder ----
    k_patch_embed<<<dim3(14, 256), 256, 0, stream>>>(image, patch_W, patch_b, pos_emb, S0);
    k_gemm64<<<dim3(784, 6), 256, 0, stream>>>(S0, 128, enc_qkv_W, 384, enc_qkv_b, QKVr, 384, 0);
    k_attn<<<dim3(1024), 256, 0, stream>>>(QKVr, 384, QKVr, 384, 128, 256, T0, 196, 196, rs);
    k_gemm64<<<dim3(784, 2), 256, 0, stream>>>(T0, 128, enc_out_W, 128, enc_out_b, T1, 128, 0);
    k_ln<<<dim3(12544), 256, 0, stream>>>(S0, T1, enc_ln1_s, enc_ln1_b, S0, 50176);
    k_gemm64<<<dim3(784, 1), 256, 0, stream>>>(S0, 128, enc_ff1_W, 64, enc_ff1_b, F1, 64, 1);
    k_gemm64<<<dim3(784, 2), 256, 0, stream>>>(F1, 64, enc_ff2_W, 128, enc_ff2_b, T1, 128, 0);
    k_ln<<<dim3(12544), 256, 0, stream>>>(S0, T1, enc_ln2_s, enc_ln2_b, M0, 50176);

    // ---- sketch MLP + action tokens ----
    k_smallgemm<<<dim3(256), 256, 0, stream>>>(sk, 200, sk1_W, sk1_b, S1s, 256, 1);
    k_smallgemm<<<dim3(256), 256, 0, stream>>>(S1s, 256, sk2_W, sk2_b, S2s, 256, 1);
    k_smallgemm<<<dim3(256), 256, 0, stream>>>(S2s, 256, sk3_W, sk3_b, S3s, 100, 0);
    k_tgt<<<dim3(256), 128, 0, stream>>>(S3s, angle, pos_x, pos_y, act_W, act_b, TG);

    // ---- decoder self-attention ----
    k_gemm64<<<dim3(60, 6), 256, 0, stream>>>(TG, 128, dec_sa_qkv_W, 384, dec_sa_qkv_b, DQKV, 384, 0);
    k_attn<<<dim3(1024), 256, 0, stream>>>(DQKV, 384, DQKV, 384, 128, 256, DT0, 15, 15, rs);
    k_gemm64<<<dim3(60, 2), 256, 0, stream>>>(DT0, 128, dec_sa_out_W, 128, dec_sa_out_b, DT1, 128, 0);
    k_ln<<<dim3(960), 256, 0, stream>>>(TG, DT1, dec_ln1_s, dec_ln1_b, TG, 3840);

    // ---- decoder cross-attention ----
    k_gemm64<<<dim3(60, 2), 256, 0, stream>>>(TG, 128, dec_ca_qkv_W, 384, dec_ca_qkv_b, DQ, 128, 0);
    k_gemm64<<<dim3(784, 4), 256, 0, stream>>>(M0, 128, dec_ca_qkv_W + 128, 384, dec_ca_qkv_b + 128, KV, 256, 0);
    k_attn<<<dim3(1024), 256, 0, stream>>>(DQ, 128, KV, 256, 0, 128, DT0, 15, 196, rs);
    k_gemm64<<<dim3(60, 2), 256, 0, stream>>>(DT0, 128, dec_ca_out_W, 128, dec_ca_out_b, DT1, 128, 0);
    k_ln<<<dim3(960), 256, 0, stream>>>(TG, DT1, dec_ln2_s, dec_ln2_b, TG, 3840);

    // ---- decoder FF + final norms ----
    k_gemm64<<<dim3(60, 1), 256, 0, stream>>>(TG, 128, dec_ff1_W, 64, dec_ff1_b, DF1, 64, 1);
    k_gemm64<<<dim3(60, 2), 256, 0, stream>>>(DF1, 64, dec_ff2_W, 128, dec_ff2_b, DT1, 128, 0);
    k_ln<<<dim3(960), 256, 0, stream>>>(TG, DT1, dec_ln3_s, dec_ln3_b, TG, 3840);
    k_ln<<<dim3(960), 256, 0, stream>>>(TG, nullptr, dec_norm_s, dec_norm_b, DT0, 3840);

    // ---- head ----
    k_gemm64<<<dim3(60, 2), 256, 0, stream>>>(DT0, 128, l1_W, 128, l1_b, DH, 128, 1);
    k_head<<<dim3(960), 256, 0, stream>>>(DH, l2_W, l2_b, (float*)d_out);
}

// Round 2
// 822.756 us; speedup vs baseline: 1.5976x; 1.5976x over previous
//
#include <hip/hip_runtime.h>
#include <math.h>

#define BSZ 256
#define DIM 128
#define NHD 4
#define NPATCH 196
#define NACT 15

typedef float f32x4 __attribute__((ext_vector_type(4)));
typedef __bf16 bf16x8 __attribute__((ext_vector_type(8)));
typedef short short8 __attribute__((ext_vector_type(8)));

__device__ __forceinline__ float wred_sum(float v) {
#pragma unroll
    for (int m = 1; m < 64; m <<= 1) v += __shfl_xor(v, m, 64);
    return v;
}
__device__ __forceinline__ float wred_max(float v) {
#pragma unroll
    for (int m = 1; m < 64; m <<= 1) v = fmaxf(v, __shfl_xor(v, m, 64));
    return v;
}
__device__ __forceinline__ ushort f2bf(float f) {  // RNE bf16
    unsigned u = __float_as_uint(f);
    return (ushort)((u + 0x7fffu + ((u >> 16) & 1u)) >> 16);
}

// ---------------------------------------------------------------------------
// Patchify: image (f32) -> Apm[m][k] bf16, m = p*256+b, k = p1*48+p2*3+c.
// grid (14,256), block 256. Strip staged in LDS (coalesced), bf16 out.
// ---------------------------------------------------------------------------
__global__ __launch_bounds__(256) void k_patchify(
    const float* __restrict__ img, ushort* __restrict__ Apm)
{
    __shared__ float xi[3 * 16 * 224];
    const int h = blockIdx.x, b = blockIdx.y, t = threadIdx.x;
    const float* g = img + (size_t)b * 150528 + h * 3584;
#pragma unroll
    for (int c = 0; c < 3; ++c)
        for (int i = t; i < 3584; i += 256) xi[c * 3584 + i] = g[c * 50176 + i];
    __syncthreads();
    for (int wq = 0; wq < 14; ++wq) {
        const size_t mrow = ((size_t)(h * 14 + wq) * 256 + b) * 768;
        for (int i = t; i < 384; i += 256) {
            const int k0 = 2 * i;
            ushort2 o;
            {
                const int c = k0 % 3, q = k0 / 3;
                o.x = f2bf(xi[c * 3584 + (q >> 4) * 224 + wq * 16 + (q & 15)]);
            }
            {
                const int k1 = k0 + 1;
                const int c = k1 % 3, q = k1 / 3;
                o.y = f2bf(xi[c * 3584 + (q >> 4) * 224 + wq * 16 + (q & 15)]);
            }
            *(ushort2*)(Apm + mrow + k0) = o;
        }
    }
}

// ---------------------------------------------------------------------------
// Weight convert+transpose to bf16 [N][K] layouts, packed into WTS buffer.
// ranges: patch(128x768) | qkv(384x128) | out(128x128) | ff1(64x128)
//         | ff2(128x64) | ckv(256x128, col-offset 128)
// ---------------------------------------------------------------------------
__global__ __launch_bounds__(256) void k_wconv(
    const float* __restrict__ pW, const float* __restrict__ qkvW,
    const float* __restrict__ outW, const float* __restrict__ ff1W,
    const float* __restrict__ ff2W, const float* __restrict__ ckvW,
    ushort* __restrict__ o)
{
    int i = blockIdx.x * 256 + threadIdx.x;
    if (i < 98304) { int n = i / 768, k = i % 768; o[i] = f2bf(pW[k * 128 + n]); return; }
    i -= 98304;
    if (i < 49152) { int n = i >> 7, k = i & 127; o[98304 + i] = f2bf(qkvW[k * 384 + n]); return; }
    i -= 49152;
    if (i < 16384) { int n = i >> 7, k = i & 127; o[147456 + i] = f2bf(outW[k * 128 + n]); return; }
    i -= 16384;
    if (i < 8192)  { int n = i >> 7, k = i & 127; o[163840 + i] = f2bf(ff1W[k * 64 + n]); return; }
    i -= 8192;
    if (i < 8192)  { int n = i >> 6, k = i & 63;  o[172032 + i] = f2bf(ff2W[k * 128 + n]); return; }
    i -= 8192;
    if (i < 32768) { int n = i >> 7, k = i & 127; o[180224 + i] = f2bf(ckvW[k * 384 + 128 + n]); return; }
}

// ---------------------------------------------------------------------------
// bf16 MFMA GEMM: C[M,N] = act(A[M,K] @ Wt^T + bias [+ pe]), A bf16 [M][lda],
// Wt bf16 [N][K]. BM=128, BN template {64,128}, BK=64, 4 waves.
// XOR-swizzled LDS (byte ^= (row&7)<<4) -> conflict-free ds_read_b128.
// C (f32) and Cb (bf16) outputs each optional. grid (M/128, N/BN).
// ---------------------------------------------------------------------------
template <int BN>
__global__ __launch_bounds__(256) void k_gemm_bf16(
    const ushort* __restrict__ A, int lda,
    const ushort* __restrict__ Wt, int K,
    const float* __restrict__ bias,
    float* __restrict__ C, ushort* __restrict__ Cb, int ldc,
    const float* __restrict__ pe, int relu)
{
    constexpr int NWN = BN / 64;   // waves along N
    constexpr int NWM = 4 / NWN;   // waves along M
    constexpr int WTM = 128 / NWM; // wave tile rows (32 or 64)
    constexpr int MF = WTM / 16;   // 2 or 4
    __shared__ ushort As[128 * 64];
    __shared__ ushort Ws[BN * 64];
    const int t = threadIdx.x;
    const int w = t >> 6, l = t & 63;
    const int r0 = blockIdx.x * 128;
    const int n0 = blockIdx.y * BN;
    const int wm = w / NWN, wn = w % NWN;
    const int lrow = l & 15, lk = l >> 4;

    f32x4 acc[MF][4];
#pragma unroll
    for (int m = 0; m < MF; ++m)
#pragma unroll
        for (int n = 0; n < 4; ++n) acc[m][n] = (f32x4)0.f;

    for (int kc = 0; kc < K; kc += 64) {
        __syncthreads();
#pragma unroll
        for (int i = t; i < 128 * 8; i += 256) {  // A tile: 128 rows x 64 k
            const int row = i >> 3, ch = i & 7;
            const int sw = (ch * 16) ^ ((row & 7) << 4);
            *(short8*)((char*)As + row * 128 + sw) =
                *(const short8*)(A + (size_t)(r0 + row) * lda + kc + ch * 8);
        }
#pragma unroll
        for (int i = t; i < BN * 8; i += 256) {   // W tile: BN rows x 64 k
            const int row = i >> 3, ch = i & 7;
            const int sw = (ch * 16) ^ ((row & 7) << 4);
            *(short8*)((char*)Ws + row * 128 + sw) =
                *(const short8*)(Wt + (size_t)(n0 + row) * K + kc + ch * 8);
        }
        __syncthreads();
#pragma unroll
        for (int ks = 0; ks < 2; ++ks) {
            bf16x8 af[MF], bfr[4];
#pragma unroll
            for (int m = 0; m < MF; ++m) {
                const int row = wm * WTM + m * 16 + lrow;
                const int col = (ks * 64 + lk * 16) ^ ((row & 7) << 4);
                af[m] = *(const bf16x8*)((const char*)As + row * 128 + col);
            }
#pragma unroll
            for (int n = 0; n < 4; ++n) {
                const int row = wn * 64 + n * 16 + lrow;
                const int col = (ks * 64 + lk * 16) ^ ((row & 7) << 4);
                bfr[n] = *(const bf16x8*)((const char*)Ws + row * 128 + col);
            }
#pragma unroll
            for (int m = 0; m < MF; ++m)
#pragma unroll
                for (int n = 0; n < 4; ++n)
                    acc[m][n] = __builtin_amdgcn_mfma_f32_16x16x32_bf16(
                        af[m], bfr[n], acc[m][n], 0, 0, 0);
        }
    }

    const int crow0 = (l >> 4) * 4;
    const int ccol = l & 15;
#pragma unroll
    for (int m = 0; m < MF; ++m) {
        const int growb = r0 + wm * WTM + m * 16 + crow0;
#pragma unroll
        for (int n = 0; n < 4; ++n) {
            const int gcol = n0 + wn * 64 + n * 16 + ccol;
            const float bv = bias[gcol];
#pragma unroll
            for (int j = 0; j < 4; ++j) {
                const int grow = growb + j;
                float v = acc[m][n][j] + bv;
                if (pe) v += pe[(grow >> 8) * 128 + gcol];
                if (relu) v = fmaxf(v, 0.f);
                if (C)  C[(size_t)grow * ldc + gcol] = v;
                if (Cb) Cb[(size_t)grow * ldc + gcol] = f2bf(v);
            }
        }
    }
}

// ---------------------------------------------------------------------------
// f32 tiled GEMM (decoder-sized, M%64==0): kept from round 1.
// ---------------------------------------------------------------------------
__global__ __launch_bounds__(256) void k_gemm64(
    const float* __restrict__ A, int K,
    const float* __restrict__ W, int wstride,
    const float* __restrict__ bias,
    float* __restrict__ C, int cstride, int relu)
{
    __shared__ float As[64 * 132];
    __shared__ float Ws2[128 * 68];
    const int t = threadIdx.x;
    const int r0 = blockIdx.x * 64;
    const int n0 = blockIdx.y * 64;
    const int as = K + 4;
    const int lg = (K == 128) ? 5 : 4;
    const int kmask = (K >> 2) - 1;

    for (int idx = t; idx < (K << 4); idx += 256) {
        const int row = idx >> lg;
        const int kk = idx & kmask;
        *(float4*)(&As[row * as + kk * 4]) =
            *(const float4*)(A + (size_t)(r0 + row) * K + kk * 4);
    }
    for (int idx = t; idx < (K << 4); idx += 256) {
        const int kk = idx >> 4;
        const int nq = idx & 15;
        *(float4*)(&Ws2[kk * 68 + nq * 4]) =
            *(const float4*)(W + (size_t)kk * wstride + n0 + nq * 4);
    }
    __syncthreads();

    const int tx = t & 15, ty = t >> 4;
    float4 acc[4];
#pragma unroll
    for (int i = 0; i < 4; ++i) acc[i] = make_float4(0.f, 0.f, 0.f, 0.f);
    const float* arow = &As[(ty * 4) * as];
    for (int k = 0; k < K; ++k) {
        const float4 wv = *(const float4*)(&Ws2[k * 68 + tx * 4]);
#pragma unroll
        for (int i = 0; i < 4; ++i) {
            const float av = arow[i * as + k];
            acc[i].x += av * wv.x; acc[i].y += av * wv.y;
            acc[i].z += av * wv.z; acc[i].w += av * wv.w;
        }
    }
    const float4 bv = *(const float4*)(bias + n0 + tx * 4);
#pragma unroll
    for (int i = 0; i < 4; ++i) {
        float4 o;
        o.x = acc[i].x + bv.x; o.y = acc[i].y + bv.y;
        o.z = acc[i].z + bv.z; o.w = acc[i].w + bv.w;
        if (relu) {
            o.x = fmaxf(o.x, 0.f); o.y = fmaxf(o.y, 0.f);
            o.z = fmaxf(o.z, 0.f); o.w = fmaxf(o.w, 0.f);
        }
        *(float4*)(C + (size_t)(r0 + ty * 4 + i) * cstride + n0 + tx * 4) = o;
    }
}

// ---------------------------------------------------------------------------
// Fused attention (f32): one block per (b,h); K/V in LDS; online softmax.
// op (f32) and ob (bf16) outputs each optional.
// ---------------------------------------------------------------------------
__global__ __launch_bounds__(256) void k_attn(
    const float* __restrict__ qp, int qstride,
    const float* __restrict__ kvp, int kvstride, int koff, int voff,
    float* __restrict__ op, ushort* __restrict__ ob,
    int Lq, int Lk, float scale)
{
    __shared__ float Kl[196 * 36];
    __shared__ float Vl[196 * 32];
    __shared__ float pbuf[4][256];
    const int bh = blockIdx.x;
    const int b = bh >> 2;
    const int h = bh & 3;
    const int t = threadIdx.x;
    const int w = t >> 6;
    const int l = t & 63;

    for (int idx = t; idx < Lk * 8; idx += 256) {
        const int j = idx >> 3;
        const int kq = idx & 7;
        const size_t row = ((size_t)j * 256 + b) * kvstride + h * 32 + kq * 4;
        *(float4*)(&Kl[j * 36 + kq * 4]) = *(const float4*)(kvp + row + koff);
        *(float4*)(&Vl[j * 32 + kq * 4]) = *(const float4*)(kvp + row + voff);
    }
    if ((Lk & 1) && t < 8) *(float4*)(&Vl[Lk * 32 + t * 4]) = make_float4(0.f, 0.f, 0.f, 0.f);
    __syncthreads();

    const int Lh = (Lk + 1) >> 1;
    const int half = l >> 5;
    const int kk = l & 31;
    const int jb = half * Lh;

    for (int jq = w; jq < Lq; jq += 4) {
        const float* qrow = qp + ((size_t)jq * 256 + b) * qstride + h * 32;
        float4 q4[8];
#pragma unroll
        for (int kq = 0; kq < 8; ++kq) q4[kq] = *(const float4*)(qrow + kq * 4);

        float s[4];
#pragma unroll
        for (int r = 0; r < 4; ++r) {
            const int j = l + (r << 6);
            float acc = -3.0e38f;
            if (j < Lk) {
                acc = 0.f;
#pragma unroll
                for (int kq = 0; kq < 8; ++kq) {
                    const float4 kv = *(const float4*)(&Kl[j * 36 + kq * 4]);
                    acc += q4[kq].x * kv.x + q4[kq].y * kv.y +
                           q4[kq].z * kv.z + q4[kq].w * kv.w;
                }
                acc *= scale;
            }
            s[r] = acc;
        }
        float m = fmaxf(fmaxf(s[0], s[1]), fmaxf(s[2], s[3]));
        m = wred_max(m);
        float sum = 0.f;
#pragma unroll
        for (int r = 0; r < 4; ++r) {
            const int j = l + (r << 6);
            float p = __expf(s[r] - m);
            if (j >= Lk) p = 0.f;
            pbuf[w][j] = p;
            sum += p;
        }
        sum = wred_sum(sum);
        const float inv = 1.0f / sum;
        __threadfence_block();

        float o = 0.f;
        for (int jj = 0; jj < Lh; ++jj) {
            const float pv = pbuf[w][jb + jj];
            const float vv = Vl[(jb + jj) * 32 + kk];
            o += pv * vv;
        }
        o += __shfl_xor(o, 32, 64);
        o *= inv;
        if (l < 32) {
            const size_t oi = ((size_t)jq * 256 + b) * 128 + h * 32 + l;
            if (op) op[oi] = o;
            if (ob) ob[oi] = f2bf(o);
        }
        __threadfence_block();
    }
}

// ---------------------------------------------------------------------------
// LayerNorm over D=128, optional residual; f32 and/or bf16 outputs.
// ---------------------------------------------------------------------------
__global__ __launch_bounds__(256) void k_ln(
    const float* __restrict__ a, const float* __restrict__ r,
    const float* __restrict__ s, const float* __restrict__ bi,
    float* __restrict__ o, ushort* __restrict__ ob, int ntok)
{
    const int tok = blockIdx.x * 4 + (threadIdx.x >> 6);
    const int l = threadIdx.x & 63;
    float2 x = ((const float2*)a)[(size_t)tok * 64 + l];
    if (r) {
        const float2 rr = ((const float2*)r)[(size_t)tok * 64 + l];
        x.x += rr.x; x.y += rr.y;
    }
    const float mean = wred_sum(x.x + x.y) * (1.f / 128.f);
    const float dx = x.x - mean, dy = x.y - mean;
    const float var = wred_sum(dx * dx + dy * dy) * (1.f / 128.f);
    const float rstd = rsqrtf(var + 1e-5f);
    const float2 sv = ((const float2*)s)[l];
    const float2 bv = ((const float2*)bi)[l];
    float2 out;
    out.x = dx * rstd * sv.x + bv.x;
    out.y = dy * rstd * sv.y + bv.y;
    if (o) ((float2*)o)[(size_t)tok * 64 + l] = out;
    if (ob) {
        ushort2 ov; ov.x = f2bf(out.x); ov.y = f2bf(out.y);
        ((ushort2*)ob)[(size_t)tok * 64 + l] = ov;
    }
}

__global__ __launch_bounds__(256) void k_smallgemm(
    const float* __restrict__ x, int K,
    const float* __restrict__ W, const float* __restrict__ bi,
    float* __restrict__ o, int N, int relu)
{
    __shared__ float xr[256];
    const int row = blockIdx.x;
    const int t = threadIdx.x;
    if (t < K) xr[t] = x[(size_t)row * K + t];
    __syncthreads();
    if (t < N) {
        float acc = bi[t];
        for (int k = 0; k < K; ++k) acc += xr[k] * W[(size_t)k * N + t];
        if (relu) acc = fmaxf(acc, 0.f);
        o[(size_t)row * N + t] = acc;
    }
}

__global__ __launch_bounds__(128) void k_tgt(
    const float* __restrict__ s3, const float* __restrict__ ang,
    const float* __restrict__ px, const float* __restrict__ py,
    const float* __restrict__ W, const float* __restrict__ bi,
    float* __restrict__ tg)
{
    const int b = blockIdx.x;
    const int d = threadIdx.x;
    float acc = bi[d] + ang[b] * W[15 * 128 + d] + px[b] * W[16 * 128 + d] +
                py[b] * W[17 * 128 + d];
    for (int k = 0; k < 100; ++k) acc += s3[b * 100 + k] * W[(18 + k) * 128 + d];
#pragma unroll
    for (int i = 0; i < 15; ++i)
        tg[((size_t)i * 256 + b) * 128 + d] = acc + W[i * 128 + d];
}

__global__ __launch_bounds__(256) void k_head(
    const float* __restrict__ hbuf, const float* __restrict__ w2,
    const float* __restrict__ b2, float* __restrict__ out)
{
    const int tok = blockIdx.x * 4 + (threadIdx.x >> 6);
    const int l = threadIdx.x & 63;
    const float2 x = ((const float2*)hbuf)[(size_t)tok * 64 + l];
    const float2 wv = ((const float2*)w2)[l];
    const float v = wred_sum(x.x * wv.x + x.y * wv.y);
    if (l == 0) {
        const int i = tok >> 8;
        const int b = tok & 255;
        out[b * 15 + i] = v + b2[0];
    }
}

// ---------------------------------------------------------------------------
extern "C" void kernel_launch(void* const* d_in, const int* in_sizes, int n_in,
                              void* d_out, int out_size, void* d_ws, size_t ws_size,
                              hipStream_t stream)
{
    (void)in_sizes; (void)n_in; (void)out_size; (void)ws_size;
    const float* image      = (const float*)d_in[0];
    const float* angle      = (const float*)d_in[1];
    const float* pos_x      = (const float*)d_in[2];
    const float* pos_y      = (const float*)d_in[3];
    const float* sk         = (const float*)d_in[4];
    const float* patch_W    = (const float*)d_in[5];
    const float* patch_b    = (const float*)d_in[6];
    const float* pos_emb    = (const float*)d_in[7];
    const float* enc_qkv_W  = (const float*)d_in[8];
    const float* enc_qkv_b  = (const float*)d_in[9];
    const float* enc_out_W  = (const float*)d_in[10];
    const float* enc_out_b  = (const float*)d_in[11];
    const float* enc_ln1_s  = (const float*)d_in[12];
    const float* enc_ln1_b  = (const float*)d_in[13];
    const float* enc_ff1_W  = (const float*)d_in[14];
    const float* enc_ff1_b  = (const float*)d_in[15];
    const float* enc_ff2_W  = (const float*)d_in[16];
    const float* enc_ff2_b  = (const float*)d_in[17];
    const float* enc_ln2_s  = (const float*)d_in[18];
    const float* enc_ln2_b  = (const float*)d_in[19];
    const float* dec_sa_qkv_W = (const float*)d_in[20];
    const float* dec_sa_qkv_b = (const float*)d_in[21];
    const float* dec_sa_out_W = (const float*)d_in[22];
    const float* dec_sa_out_b = (const float*)d_in[23];
    const float* dec_ca_qkv_W = (const float*)d_in[24];
    const float* dec_ca_qkv_b = (const float*)d_in[25];
    const float* dec_ca_out_W = (const float*)d_in[26];
    const float* dec_ca_out_b = (const float*)d_in[27];
    const float* dec_ln1_s  = (const float*)d_in[28];
    const float* dec_ln1_b  = (const float*)d_in[29];
    const float* dec_ln2_s  = (const float*)d_in[30];
    const float* dec_ln2_b  = (const float*)d_in[31];
    const float* dec_ln3_s  = (const float*)d_in[32];
    const float* dec_ln3_b  = (const float*)d_in[33];
    const float* dec_ff1_W  = (const float*)d_in[34];
    const float* dec_ff1_b  = (const float*)d_in[35];
    const float* dec_ff2_W  = (const float*)d_in[36];
    const float* dec_ff2_b  = (const float*)d_in[37];
    const float* dec_norm_s = (const float*)d_in[38];
    const float* dec_norm_b = (const float*)d_in[39];
    const float* sk1_W = (const float*)d_in[40];
    const float* sk1_b = (const float*)d_in[41];
    const float* sk2_W = (const float*)d_in[42];
    const float* sk2_b = (const float*)d_in[43];
    const float* sk3_W = (const float*)d_in[44];
    const float* sk3_b = (const float*)d_in[45];
    const float* act_W = (const float*)d_in[46];
    const float* act_b = (const float*)d_in[47];
    const float* l1_W  = (const float*)d_in[48];
    const float* l1_b  = (const float*)d_in[49];
    const float* l2_W  = (const float*)d_in[50];
    const float* l2_b  = (const float*)d_in[51];

    // Workspace layout (float offsets); peak ~195.7 MB.
    float* ws = (float*)d_ws;
    float* S0   = ws;               // src f32                 [6,422,528]
    float* QKVr = ws + 6422528;     // enc QKV f32             [19,267,584]
    float* T0   = ws + 25690112;    // f32 attn out (decoder)  [6,422,528]
    float* T1   = ws + 32112640;    // proj/ff2 out f32        [6,422,528]
    float* F1   = ws + 38535168;    // [3,211,264] F1b bf16 -> M0b bf16
    float* M0r  = ws + 41746432;    // [6,422,528] srcb/T0b bf16 | lnb bf16
    float* S1s  = ws + 48168960;
    float* S2s  = S1s + 65536;
    float* S3s  = S2s + 65536;
    float* TG   = S3s + 25600;
    ushort* WTS = (ushort*)(ws + 48817152);  // 212,992 bf16 weights

    // Overlays
    ushort* Apm = (ushort*)QKVr;             // 38,535,168 bf16 (patch phase)
    float*  KV  = QKVr;                      // cross K/V f32 [12,845,056]
    float* DQKV = QKVr + 12845056;
    float* DQ   = QKVr + 14319616;
    float* DH   = QKVr + 14811136;
    float* DT0  = T0;
    float* DT1  = T1;
    float* DF1  = F1;
    ushort* srcb = (ushort*)M0r;             // 6,422,528 bf16
    ushort* T0b  = (ushort*)M0r;             // reuses srcb slot (disjoint lifetime)
    ushort* lnb  = (ushort*)(M0r + 3211264); // 6,422,528 bf16
    ushort* F1b  = (ushort*)F1;              // 3,211,264 bf16
    ushort* M0b  = (ushort*)F1;              // 6,422,528 bf16 (after ff2)
    ushort* wt_patch = WTS;
    ushort* wt_qkv   = WTS + 98304;
    ushort* wt_out   = WTS + 147456;
    ushort* wt_ff1   = WTS + 163840;
    ushort* wt_ff2   = WTS + 172032;
    ushort* wt_ckv   = WTS + 180224;

    const float rs = 0.17677669529663687f;  // 1/sqrt(32)

    // ---- weight convert + patchify ----
    k_wconv<<<dim3(832), 256, 0, stream>>>(patch_W, enc_qkv_W, enc_out_W,
                                           enc_ff1_W, enc_ff2_W, dec_ca_qkv_W, WTS);
    k_patchify<<<dim3(14, 256), 256, 0, stream>>>(image, Apm);

    // ---- encoder ----
    k_gemm_bf16<128><<<dim3(392, 1), 256, 0, stream>>>(
        Apm, 768, wt_patch, 768, patch_b, S0, srcb, 128, pos_emb, 0);
    k_gemm_bf16<128><<<dim3(392, 3), 256, 0, stream>>>(
        srcb, 128, wt_qkv, 128, enc_qkv_b, QKVr, nullptr, 384, nullptr, 0);
    k_attn<<<dim3(1024), 256, 0, stream>>>(QKVr, 384, QKVr, 384, 128, 256,
                                           nullptr, T0b, 196, 196, rs);
    k_gemm_bf16<128><<<dim3(392, 1), 256, 0, stream>>>(
        T0b, 128, wt_out, 128, enc_out_b, T1, nullptr, 128, nullptr, 0);
    k_ln<<<dim3(12544), 256, 0, stream>>>(S0, T1, enc_ln1_s, enc_ln1_b, S0, lnb, 50176);
    k_gemm_bf16<64><<<dim3(392, 1), 256, 0, stream>>>(
        lnb, 128, wt_ff1, 128, enc_ff1_b, nullptr, F1b, 64, nullptr, 1);
    k_gemm_bf16<128><<<dim3(392, 1), 256, 0, stream>>>(
        F1b, 64, wt_ff2, 64, enc_ff2_b, T1, nullptr, 128, nullptr, 0);
    k_ln<<<dim3(12544), 256, 0, stream>>>(S0, T1, enc_ln2_s, enc_ln2_b, nullptr, M0b, 50176);

    // ---- sketch MLP + action tokens ----
    k_smallgemm<<<dim3(256), 256, 0, stream>>>(sk, 200, sk1_W, sk1_b, S1s, 256, 1);
    k_smallgemm<<<dim3(256), 256, 0, stream>>>(S1s, 256, sk2_W, sk2_b, S2s, 256, 1);
    k_smallgemm<<<dim3(256), 256, 0, stream>>>(S2s, 256, sk3_W, sk3_b, S3s, 100, 0);
    k_tgt<<<dim3(256), 128, 0, stream>>>(S3s, angle, pos_x, pos_y, act_W, act_b, TG);

    // ---- decoder self-attention ----
    k_gemm64<<<dim3(60, 6), 256, 0, stream>>>(TG, 128, dec_sa_qkv_W, 384, dec_sa_qkv_b, DQKV, 384, 0);
    k_attn<<<dim3(1024), 256, 0, stream>>>(DQKV, 384, DQKV, 384, 128, 256,
                                           DT0, nullptr, 15, 15, rs);
    k_gemm64<<<dim3(60, 2), 256, 0, stream>>>(DT0, 128, dec_sa_out_W, 128, dec_sa_out_b, DT1, 128, 0);
    k_ln<<<dim3(960), 256, 0, stream>>>(TG, DT1, dec_ln1_s, dec_ln1_b, TG, nullptr, 3840);

    // ---- decoder cross-attention ----
    k_gemm64<<<dim3(60, 2), 256, 0, stream>>>(TG, 128, dec_ca_qkv_W, 384, dec_ca_qkv_b, DQ, 128, 0);
    k_gemm_bf16<128><<<dim3(392, 2), 256, 0, stream>>>(
        M0b, 128, wt_ckv, 128, dec_ca_qkv_b + 128, KV, nullptr, 256, nullptr, 0);
    k_attn<<<dim3(1024), 256, 0, stream>>>(DQ, 128, KV, 256, 0, 128,
                                           DT0, nullptr, 15, 196, rs);
    k_gemm64<<<dim3(60, 2), 256, 0, stream>>>(DT0, 128, dec_ca_out_W, 128, dec_ca_out_b, DT1, 128, 0);
    k_ln<<<dim3(960), 256, 0, stream>>>(TG, DT1, dec_ln2_s, dec_ln2_b, TG, nullptr, 3840);

    // ---- decoder FF + final norms ----
    k_gemm64<<<dim3(60, 1), 256, 0, stream>>>(TG, 128, dec_ff1_W, 64, dec_ff1_b, DF1, 64, 1);
    k_gemm64<<<dim3(60, 2), 256, 0, stream>>>(DF1, 64, dec_ff2_W, 128, dec_ff2_b, DT1, 128, 0);
    k_ln<<<dim3(960), 256, 0, stream>>>(TG, DT1, dec_ln3_s, dec_ln3_b, TG, nullptr, 3840);
    k_ln<<<dim3(960), 256, 0, stream>>>(TG, nullptr, dec_norm_s, dec_norm_b, DT0, nullptr, 3840);

    // ---- head ----
    k_gemm64<<<dim3(60, 2), 256, 0, stream>>>(DT0, 128, l1_W, 128, l1_b, DH, 128, 1);
    k_head<<<dim3(960), 256, 0, stream>>>(DH, l2_W, l2_b, (float*)d_out);
}

// Round 3
// 568.281 us; speedup vs baseline: 2.3130x; 1.4478x over previous
//
#include <hip/hip_runtime.h>
#include <math.h>

#define BSZ 256
#define DIM 128
#define NHD 4
#define NPATCH 196
#define NACT 15

typedef float f32x4 __attribute__((ext_vector_type(4)));
typedef __bf16 bf16x8 __attribute__((ext_vector_type(8)));
typedef short short8 __attribute__((ext_vector_type(8)));

__device__ __forceinline__ float wred_sum(float v) {
#pragma unroll
    for (int m = 1; m < 64; m <<= 1) v += __shfl_xor(v, m, 64);
    return v;
}
__device__ __forceinline__ float wred_max(float v) {
#pragma unroll
    for (int m = 1; m < 64; m <<= 1) v = fmaxf(v, __shfl_xor(v, m, 64));
    return v;
}
__device__ __forceinline__ ushort f2bf(float f) {  // RNE bf16
    unsigned u = __float_as_uint(f);
    return (ushort)((u + 0x7fffu + ((u >> 16) & 1u)) >> 16);
}

// ---------------------------------------------------------------------------
// Patchify: image (f32) -> Apm[m][k] bf16, m = p*256+b, k = p1*48+p2*3+c.
// ---------------------------------------------------------------------------
__global__ __launch_bounds__(256) void k_patchify(
    const float* __restrict__ img, ushort* __restrict__ Apm)
{
    __shared__ float xi[3 * 16 * 224];
    const int h = blockIdx.x, b = blockIdx.y, t = threadIdx.x;
    const float* g = img + (size_t)b * 150528 + h * 3584;
#pragma unroll
    for (int c = 0; c < 3; ++c)
        for (int i = t; i < 3584; i += 256) xi[c * 3584 + i] = g[c * 50176 + i];
    __syncthreads();
    for (int wq = 0; wq < 14; ++wq) {
        const size_t mrow = ((size_t)(h * 14 + wq) * 256 + b) * 768;
        for (int i = t; i < 384; i += 256) {
            const int k0 = 2 * i;
            ushort2 o;
            {
                const int c = k0 % 3, q = k0 / 3;
                o.x = f2bf(xi[c * 3584 + (q >> 4) * 224 + wq * 16 + (q & 15)]);
            }
            {
                const int k1 = k0 + 1;
                const int c = k1 % 3, q = k1 / 3;
                o.y = f2bf(xi[c * 3584 + (q >> 4) * 224 + wq * 16 + (q & 15)]);
            }
            *(ushort2*)(Apm + mrow + k0) = o;
        }
    }
}

// ---------------------------------------------------------------------------
// Weight convert+transpose to bf16 [N][K], packed.
// ---------------------------------------------------------------------------
__global__ __launch_bounds__(256) void k_wconv(
    const float* __restrict__ pW, const float* __restrict__ qkvW,
    const float* __restrict__ outW, const float* __restrict__ ff1W,
    const float* __restrict__ ff2W, const float* __restrict__ ckvW,
    ushort* __restrict__ o)
{
    int i = blockIdx.x * 256 + threadIdx.x;
    if (i < 98304) { int n = i / 768, k = i % 768; o[i] = f2bf(pW[k * 128 + n]); return; }
    i -= 98304;
    if (i < 49152) { int n = i >> 7, k = i & 127; o[98304 + i] = f2bf(qkvW[k * 384 + n]); return; }
    i -= 49152;
    if (i < 16384) { int n = i >> 7, k = i & 127; o[147456 + i] = f2bf(outW[k * 128 + n]); return; }
    i -= 16384;
    if (i < 8192)  { int n = i >> 7, k = i & 127; o[163840 + i] = f2bf(ff1W[k * 64 + n]); return; }
    i -= 8192;
    if (i < 8192)  { int n = i >> 6, k = i & 63;  o[172032 + i] = f2bf(ff2W[k * 128 + n]); return; }
    i -= 8192;
    if (i < 32768) { int n = i >> 7, k = i & 127; o[180224 + i] = f2bf(ckvW[k * 384 + 128 + n]); return; }
}

// ---------------------------------------------------------------------------
// bf16 MFMA GEMM (as round 2, verified): BM=128, BN {64,128}, BK=64.
// ---------------------------------------------------------------------------
template <int BN>
__global__ __launch_bounds__(256) void k_gemm_bf16(
    const ushort* __restrict__ A, int lda,
    const ushort* __restrict__ Wt, int K,
    const float* __restrict__ bias,
    float* __restrict__ C, ushort* __restrict__ Cb, int ldc,
    const float* __restrict__ pe, int relu)
{
    constexpr int NWN = BN / 64;
    constexpr int NWM = 4 / NWN;
    constexpr int WTM = 128 / NWM;
    constexpr int MF = WTM / 16;
    __shared__ ushort As[128 * 64];
    __shared__ ushort Ws[BN * 64];
    const int t = threadIdx.x;
    const int w = t >> 6, l = t & 63;
    const int r0 = blockIdx.x * 128;
    const int n0 = blockIdx.y * BN;
    const int wm = w / NWN, wn = w % NWN;
    const int lrow = l & 15, lk = l >> 4;

    f32x4 acc[MF][4];
#pragma unroll
    for (int m = 0; m < MF; ++m)
#pragma unroll
        for (int n = 0; n < 4; ++n) acc[m][n] = (f32x4)0.f;

    for (int kc = 0; kc < K; kc += 64) {
        __syncthreads();
#pragma unroll
        for (int i = t; i < 128 * 8; i += 256) {
            const int row = i >> 3, ch = i & 7;
            const int sw = (ch * 16) ^ ((row & 7) << 4);
            *(short8*)((char*)As + row * 128 + sw) =
                *(const short8*)(A + (size_t)(r0 + row) * lda + kc + ch * 8);
        }
#pragma unroll
        for (int i = t; i < BN * 8; i += 256) {
            const int row = i >> 3, ch = i & 7;
            const int sw = (ch * 16) ^ ((row & 7) << 4);
            *(short8*)((char*)Ws + row * 128 + sw) =
                *(const short8*)(Wt + (size_t)(n0 + row) * K + kc + ch * 8);
        }
        __syncthreads();
#pragma unroll
        for (int ks = 0; ks < 2; ++ks) {
            bf16x8 af[MF], bfr[4];
#pragma unroll
            for (int m = 0; m < MF; ++m) {
                const int row = wm * WTM + m * 16 + lrow;
                const int col = (ks * 64 + lk * 16) ^ ((row & 7) << 4);
                af[m] = *(const bf16x8*)((const char*)As + row * 128 + col);
            }
#pragma unroll
            for (int n = 0; n < 4; ++n) {
                const int row = wn * 64 + n * 16 + lrow;
                const int col = (ks * 64 + lk * 16) ^ ((row & 7) << 4);
                bfr[n] = *(const bf16x8*)((const char*)Ws + row * 128 + col);
            }
#pragma unroll
            for (int m = 0; m < MF; ++m)
#pragma unroll
                for (int n = 0; n < 4; ++n)
                    acc[m][n] = __builtin_amdgcn_mfma_f32_16x16x32_bf16(
                        af[m], bfr[n], acc[m][n], 0, 0, 0);
        }
    }

    const int crow0 = (l >> 4) * 4;
    const int ccol = l & 15;
#pragma unroll
    for (int m = 0; m < MF; ++m) {
        const int growb = r0 + wm * WTM + m * 16 + crow0;
#pragma unroll
        for (int n = 0; n < 4; ++n) {
            const int gcol = n0 + wn * 64 + n * 16 + ccol;
            const float bv = bias[gcol];
#pragma unroll
            for (int j = 0; j < 4; ++j) {
                const int grow = growb + j;
                float v = acc[m][n][j] + bv;
                if (pe) v += pe[(grow >> 8) * 128 + gcol];
                if (relu) v = fmaxf(v, 0.f);
                if (C)  C[(size_t)grow * ldc + gcol] = v;
                if (Cb) Cb[(size_t)grow * ldc + gcol] = f2bf(v);
            }
        }
    }
}

// ---------------------------------------------------------------------------
// MFMA flash attention, encoder self-attn: Lq=Lk=196, hd=32, heads packed in
// qkv bf16 [token=p*256+b][384] (q@0, k@128, v@256). One block per (b,h),
// 4 waves, each wave owns q-tiles qt = w, w+4, w+8 (+12 for w=0).
// K LDS [208][40] (stride 20 banks: 2-way free); V^T LDS [32][232]
// (stride 20 banks); P per-wave LDS [16][232] for C/D->A frag relayout.
// ---------------------------------------------------------------------------
__global__ __launch_bounds__(256) void k_attn_mfma(
    const ushort* __restrict__ qkv, ushort* __restrict__ ob, float scale)
{
    __shared__ ushort Ks[208 * 40];
    __shared__ ushort Vt[32 * 232];
    __shared__ ushort Ps[4][16 * 232];
    const int bh = blockIdx.x;
    const int b = bh >> 2, h = bh & 3;
    const int t = threadIdx.x, w = t >> 6, l = t & 63;
    const int lr = l & 15, lg = l >> 4;

    // stage K rows + V transposed
    for (int idx = t; idx < 784; idx += 256) {
        const int j = idx >> 2, ch = idx & 3;
        const size_t base = ((size_t)j * 256 + b) * 384 + h * 32 + ch * 8;
        *(short8*)(Ks + j * 40 + ch * 8) = *(const short8*)(qkv + base + 128);
        short8 v = *(const short8*)(qkv + base + 256);
#pragma unroll
        for (int q = 0; q < 8; ++q)
            Vt[(ch * 8 + q) * 232 + j] = (ushort)v[q];
    }
    // zero V^T cols 196..231 (PV k-padding must be 0, not garbage)
    for (int idx = t; idx < 32 * 36; idx += 256)
        Vt[(idx / 36) * 232 + 196 + (idx % 36)] = 0;
    // zero P cols 208..223 (per wave)
    for (int i = l; i < 256; i += 64)
        Ps[w][(i >> 4) * 232 + 208 + (i & 15)] = 0;
    __syncthreads();

    for (int qt = w; qt < 13; qt += 4) {
        int qr = qt * 16 + lr; if (qr > 195) qr = 195;  // clamp; rows >=196 discarded
        const bf16x8 qf = *(const bf16x8*)(qkv + ((size_t)qr * 256 + b) * 384 + h * 32 + lg * 8);

        f32x4 s[13];
#pragma unroll
        for (int jn = 0; jn < 13; ++jn) {
            const bf16x8 kf = *(const bf16x8*)(Ks + (jn * 16 + lr) * 40 + lg * 8);
            s[jn] = __builtin_amdgcn_mfma_f32_16x16x32_bf16(qf, kf, (f32x4)0.f, 0, 0, 0);
        }
        if (lr >= 4) {  // cols 196..207 invalid
            s[12][0] = -3.0e38f; s[12][1] = -3.0e38f;
            s[12][2] = -3.0e38f; s[12][3] = -3.0e38f;
        }

        float inv[4];
        ushort* pw = Ps[w];
#pragma unroll
        for (int j = 0; j < 4; ++j) {
            float m = s[0][j];
#pragma unroll
            for (int jn = 1; jn < 13; ++jn) m = fmaxf(m, s[jn][j]);
            m = fmaxf(m, __shfl_xor(m, 1, 64));
            m = fmaxf(m, __shfl_xor(m, 2, 64));
            m = fmaxf(m, __shfl_xor(m, 4, 64));
            m = fmaxf(m, __shfl_xor(m, 8, 64));
            float sum = 0.f;
#pragma unroll
            for (int jn = 0; jn < 13; ++jn) {
                const float p = __expf((s[jn][j] - m) * scale);
                s[jn][j] = p;
                sum += p;
            }
            sum += __shfl_xor(sum, 1, 64);
            sum += __shfl_xor(sum, 2, 64);
            sum += __shfl_xor(sum, 4, 64);
            sum += __shfl_xor(sum, 8, 64);
            inv[j] = 1.0f / sum;
        }
#pragma unroll
        for (int jn = 0; jn < 13; ++jn)
#pragma unroll
            for (int j = 0; j < 4; ++j)
                pw[(lg * 4 + j) * 232 + jn * 16 + lr] = f2bf(s[jn][j]);

        f32x4 o0 = (f32x4)0.f, o1 = (f32x4)0.f;
#pragma unroll
        for (int kt = 0; kt < 7; ++kt) {
            const bf16x8 pf = *(const bf16x8*)(pw + lr * 232 + kt * 32 + lg * 8);
            const bf16x8 v0 = *(const bf16x8*)(Vt + lr * 232 + kt * 32 + lg * 8);
            const bf16x8 v1 = *(const bf16x8*)(Vt + (16 + lr) * 232 + kt * 32 + lg * 8);
            o0 = __builtin_amdgcn_mfma_f32_16x16x32_bf16(pf, v0, o0, 0, 0, 0);
            o1 = __builtin_amdgcn_mfma_f32_16x16x32_bf16(pf, v1, o1, 0, 0, 0);
        }
#pragma unroll
        for (int j = 0; j < 4; ++j) {
            const int r = qt * 16 + lg * 4 + j;
            if (r < 196) {
                const size_t o = ((size_t)r * 256 + b) * 128 + h * 32;
                ob[o + lr]      = f2bf(o0[j] * inv[j]);
                ob[o + 16 + lr] = f2bf(o1[j] * inv[j]);
            }
        }
    }
}

// ---------------------------------------------------------------------------
// f32 tiled GEMM (decoder-sized).
// ---------------------------------------------------------------------------
__global__ __launch_bounds__(256) void k_gemm64(
    const float* __restrict__ A, int K,
    const float* __restrict__ W, int wstride,
    const float* __restrict__ bias,
    float* __restrict__ C, int cstride, int relu)
{
    __shared__ float As[64 * 132];
    __shared__ float Ws2[128 * 68];
    const int t = threadIdx.x;
    const int r0 = blockIdx.x * 64;
    const int n0 = blockIdx.y * 64;
    const int as = K + 4;
    const int lg = (K == 128) ? 5 : 4;
    const int kmask = (K >> 2) - 1;

    for (int idx = t; idx < (K << 4); idx += 256) {
        const int row = idx >> lg;
        const int kk = idx & kmask;
        *(float4*)(&As[row * as + kk * 4]) =
            *(const float4*)(A + (size_t)(r0 + row) * K + kk * 4);
    }
    for (int idx = t; idx < (K << 4); idx += 256) {
        const int kk = idx >> 4;
        const int nq = idx & 15;
        *(float4*)(&Ws2[kk * 68 + nq * 4]) =
            *(const float4*)(W + (size_t)kk * wstride + n0 + nq * 4);
    }
    __syncthreads();

    const int tx = t & 15, ty = t >> 4;
    float4 acc[4];
#pragma unroll
    for (int i = 0; i < 4; ++i) acc[i] = make_float4(0.f, 0.f, 0.f, 0.f);
    const float* arow = &As[(ty * 4) * as];
    for (int k = 0; k < K; ++k) {
        const float4 wv = *(const float4*)(&Ws2[k * 68 + tx * 4]);
#pragma unroll
        for (int i = 0; i < 4; ++i) {
            const float av = arow[i * as + k];
            acc[i].x += av * wv.x; acc[i].y += av * wv.y;
            acc[i].z += av * wv.z; acc[i].w += av * wv.w;
        }
    }
    const float4 bv = *(const float4*)(bias + n0 + tx * 4);
#pragma unroll
    for (int i = 0; i < 4; ++i) {
        float4 o;
        o.x = acc[i].x + bv.x; o.y = acc[i].y + bv.y;
        o.z = acc[i].z + bv.z; o.w = acc[i].w + bv.w;
        if (relu) {
            o.x = fmaxf(o.x, 0.f); o.y = fmaxf(o.y, 0.f);
            o.z = fmaxf(o.z, 0.f); o.w = fmaxf(o.w, 0.f);
        }
        *(float4*)(C + (size_t)(r0 + ty * 4 + i) * cstride + n0 + tx * 4) = o;
    }
}

// ---------------------------------------------------------------------------
// Fused attention (f32, decoder paths): block per (b,h); K/V in LDS.
// ---------------------------------------------------------------------------
__global__ __launch_bounds__(256) void k_attn(
    const float* __restrict__ qp, int qstride,
    const float* __restrict__ kvp, int kvstride, int koff, int voff,
    float* __restrict__ op, ushort* __restrict__ ob,
    int Lq, int Lk, float scale)
{
    __shared__ float Kl[196 * 36];
    __shared__ float Vl[196 * 32];
    __shared__ float pbuf[4][256];
    const int bh = blockIdx.x;
    const int b = bh >> 2;
    const int h = bh & 3;
    const int t = threadIdx.x;
    const int w = t >> 6;
    const int l = t & 63;

    for (int idx = t; idx < Lk * 8; idx += 256) {
        const int j = idx >> 3;
        const int kq = idx & 7;
        const size_t row = ((size_t)j * 256 + b) * kvstride + h * 32 + kq * 4;
        *(float4*)(&Kl[j * 36 + kq * 4]) = *(const float4*)(kvp + row + koff);
        *(float4*)(&Vl[j * 32 + kq * 4]) = *(const float4*)(kvp + row + voff);
    }
    if ((Lk & 1) && t < 8) *(float4*)(&Vl[Lk * 32 + t * 4]) = make_float4(0.f, 0.f, 0.f, 0.f);
    __syncthreads();

    const int Lh = (Lk + 1) >> 1;
    const int half = l >> 5;
    const int kk = l & 31;
    const int jb = half * Lh;

    for (int jq = w; jq < Lq; jq += 4) {
        const float* qrow = qp + ((size_t)jq * 256 + b) * qstride + h * 32;
        float4 q4[8];
#pragma unroll
        for (int kq = 0; kq < 8; ++kq) q4[kq] = *(const float4*)(qrow + kq * 4);

        float s[4];
#pragma unroll
        for (int r = 0; r < 4; ++r) {
            const int j = l + (r << 6);
            float acc = -3.0e38f;
            if (j < Lk) {
                acc = 0.f;
#pragma unroll
                for (int kq = 0; kq < 8; ++kq) {
                    const float4 kv = *(const float4*)(&Kl[j * 36 + kq * 4]);
                    acc += q4[kq].x * kv.x + q4[kq].y * kv.y +
                           q4[kq].z * kv.z + q4[kq].w * kv.w;
                }
                acc *= scale;
            }
            s[r] = acc;
        }
        float m = fmaxf(fmaxf(s[0], s[1]), fmaxf(s[2], s[3]));
        m = wred_max(m);
        float sum = 0.f;
#pragma unroll
        for (int r = 0; r < 4; ++r) {
            const int j = l + (r << 6);
            float p = __expf(s[r] - m);
            if (j >= Lk) p = 0.f;
            pbuf[w][j] = p;
            sum += p;
        }
        sum = wred_sum(sum);
        const float inv = 1.0f / sum;
        __threadfence_block();

        float o = 0.f;
        for (int jj = 0; jj < Lh; ++jj) {
            const float pv = pbuf[w][jb + jj];
            const float vv = Vl[(jb + jj) * 32 + kk];
            o += pv * vv;
        }
        o += __shfl_xor(o, 32, 64);
        o *= inv;
        if (l < 32) {
            const size_t oi = ((size_t)jq * 256 + b) * 128 + h * 32 + l;
            if (op) op[oi] = o;
            if (ob) ob[oi] = f2bf(o);
        }
        __threadfence_block();
    }
}

// ---------------------------------------------------------------------------
// LayerNorm over D=128, optional residual; f32 and/or bf16 outputs.
// ---------------------------------------------------------------------------
__global__ __launch_bounds__(256) void k_ln(
    const float* __restrict__ a, const float* __restrict__ r,
    const float* __restrict__ s, const float* __restrict__ bi,
    float* __restrict__ o, ushort* __restrict__ ob, int ntok)
{
    const int tok = blockIdx.x * 4 + (threadIdx.x >> 6);
    const int l = threadIdx.x & 63;
    float2 x = ((const float2*)a)[(size_t)tok * 64 + l];
    if (r) {
        const float2 rr = ((const float2*)r)[(size_t)tok * 64 + l];
        x.x += rr.x; x.y += rr.y;
    }
    const float mean = wred_sum(x.x + x.y) * (1.f / 128.f);
    const float dx = x.x - mean, dy = x.y - mean;
    const float var = wred_sum(dx * dx + dy * dy) * (1.f / 128.f);
    const float rstd = rsqrtf(var + 1e-5f);
    const float2 sv = ((const float2*)s)[l];
    const float2 bv = ((const float2*)bi)[l];
    float2 out;
    out.x = dx * rstd * sv.x + bv.x;
    out.y = dy * rstd * sv.y + bv.y;
    if (o) ((float2*)o)[(size_t)tok * 64 + l] = out;
    if (ob) {
        ushort2 ov; ov.x = f2bf(out.x); ov.y = f2bf(out.y);
        ((ushort2*)ob)[(size_t)tok * 64 + l] = ov;
    }
}

__global__ __launch_bounds__(256) void k_smallgemm(
    const float* __restrict__ x, int K,
    const float* __restrict__ W, const float* __restrict__ bi,
    float* __restrict__ o, int N, int relu)
{
    __shared__ float xr[256];
    const int row = blockIdx.x;
    const int t = threadIdx.x;
    if (t < K) xr[t] = x[(size_t)row * K + t];
    __syncthreads();
    if (t < N) {
        float acc = bi[t];
        for (int k = 0; k < K; ++k) acc += xr[k] * W[(size_t)k * N + t];
        if (relu) acc = fmaxf(acc, 0.f);
        o[(size_t)row * N + t] = acc;
    }
}

__global__ __launch_bounds__(128) void k_tgt(
    const float* __restrict__ s3, const float* __restrict__ ang,
    const float* __restrict__ px, const float* __restrict__ py,
    const float* __restrict__ W, const float* __restrict__ bi,
    float* __restrict__ tg)
{
    const int b = blockIdx.x;
    const int d = threadIdx.x;
    float acc = bi[d] + ang[b] * W[15 * 128 + d] + px[b] * W[16 * 128 + d] +
                py[b] * W[17 * 128 + d];
    for (int k = 0; k < 100; ++k) acc += s3[b * 100 + k] * W[(18 + k) * 128 + d];
#pragma unroll
    for (int i = 0; i < 15; ++i)
        tg[((size_t)i * 256 + b) * 128 + d] = acc + W[i * 128 + d];
}

__global__ __launch_bounds__(256) void k_head(
    const float* __restrict__ hbuf, const float* __restrict__ w2,
    const float* __restrict__ b2, float* __restrict__ out)
{
    const int tok = blockIdx.x * 4 + (threadIdx.x >> 6);
    const int l = threadIdx.x & 63;
    const float2 x = ((const float2*)hbuf)[(size_t)tok * 64 + l];
    const float2 wv = ((const float2*)w2)[l];
    const float v = wred_sum(x.x * wv.x + x.y * wv.y);
    if (l == 0) {
        const int i = tok >> 8;
        const int b = tok & 255;
        out[b * 15 + i] = v + b2[0];
    }
}

// ---------------------------------------------------------------------------
extern "C" void kernel_launch(void* const* d_in, const int* in_sizes, int n_in,
                              void* d_out, int out_size, void* d_ws, size_t ws_size,
                              hipStream_t stream)
{
    (void)in_sizes; (void)n_in; (void)out_size; (void)ws_size;
    const float* image      = (const float*)d_in[0];
    const float* angle      = (const float*)d_in[1];
    const float* pos_x      = (const float*)d_in[2];
    const float* pos_y      = (const float*)d_in[3];
    const float* sk         = (const float*)d_in[4];
    const float* patch_W    = (const float*)d_in[5];
    const float* patch_b    = (const float*)d_in[6];
    const float* pos_emb    = (const float*)d_in[7];
    const float* enc_qkv_W  = (const float*)d_in[8];
    const float* enc_qkv_b  = (const float*)d_in[9];
    const float* enc_out_W  = (const float*)d_in[10];
    const float* enc_out_b  = (const float*)d_in[11];
    const float* enc_ln1_s  = (const float*)d_in[12];
    const float* enc_ln1_b  = (const float*)d_in[13];
    const float* enc_ff1_W  = (const float*)d_in[14];
    const float* enc_ff1_b  = (const float*)d_in[15];
    const float* enc_ff2_W  = (const float*)d_in[16];
    const float* enc_ff2_b  = (const float*)d_in[17];
    const float* enc_ln2_s  = (const float*)d_in[18];
    const float* enc_ln2_b  = (const float*)d_in[19];
    const float* dec_sa_qkv_W = (const float*)d_in[20];
    const float* dec_sa_qkv_b = (const float*)d_in[21];
    const float* dec_sa_out_W = (const float*)d_in[22];
    const float* dec_sa_out_b = (const float*)d_in[23];
    const float* dec_ca_qkv_W = (const float*)d_in[24];
    const float* dec_ca_qkv_b = (const float*)d_in[25];
    const float* dec_ca_out_W = (const float*)d_in[26];
    const float* dec_ca_out_b = (const float*)d_in[27];
    const float* dec_ln1_s  = (const float*)d_in[28];
    const float* dec_ln1_b  = (const float*)d_in[29];
    const float* dec_ln2_s  = (const float*)d_in[30];
    const float* dec_ln2_b  = (const float*)d_in[31];
    const float* dec_ln3_s  = (const float*)d_in[32];
    const float* dec_ln3_b  = (const float*)d_in[33];
    const float* dec_ff1_W  = (const float*)d_in[34];
    const float* dec_ff1_b  = (const float*)d_in[35];
    const float* dec_ff2_W  = (const float*)d_in[36];
    const float* dec_ff2_b  = (const float*)d_in[37];
    const float* dec_norm_s = (const float*)d_in[38];
    const float* dec_norm_b = (const float*)d_in[39];
    const float* sk1_W = (const float*)d_in[40];
    const float* sk1_b = (const float*)d_in[41];
    const float* sk2_W = (const float*)d_in[42];
    const float* sk2_b = (const float*)d_in[43];
    const float* sk3_W = (const float*)d_in[44];
    const float* sk3_b = (const float*)d_in[45];
    const float* act_W = (const float*)d_in[46];
    const float* act_b = (const float*)d_in[47];
    const float* l1_W  = (const float*)d_in[48];
    const float* l1_b  = (const float*)d_in[49];
    const float* l2_W  = (const float*)d_in[50];
    const float* l2_b  = (const float*)d_in[51];

    // Workspace layout (float offsets); peak ~195.7 MB.
    float* ws = (float*)d_ws;
    float* S0   = ws;               // src f32                 [6,422,528]
    float* QKVr = ws + 6422528;     // big overlay region      [19,267,584]
    float* T0   = ws + 25690112;    // f32 attn out (decoder)  [6,422,528]
    float* T1   = ws + 32112640;    // proj/ff2 out f32        [6,422,528]
    float* F1   = ws + 38535168;    // [3,211,264] F1b bf16 -> M0b bf16
    float* M0r  = ws + 41746432;    // [6,422,528] srcb/T0b | lnb bf16
    float* S1s  = ws + 48168960;
    float* S2s  = S1s + 65536;
    float* S3s  = S2s + 65536;
    float* TG   = S3s + 25600;
    ushort* WTS = (ushort*)(ws + 48817152);

    // Overlays
    ushort* Apm  = (ushort*)QKVr;            // patch matrix (patch phase)
    ushort* QKVb = (ushort*)QKVr;            // enc QKV bf16 [50176][384]
    float*  KV   = QKVr;                     // cross K/V f32 (after enc attn)
    float* DQKV = QKVr + 12845056;
    float* DQ   = QKVr + 14319616;
    float* DH   = QKVr + 14811136;
    float* DT0  = T0;
    float* DT1  = T1;
    float* DF1  = F1;
    ushort* srcb = (ushort*)M0r;
    ushort* T0b  = (ushort*)M0r;             // disjoint lifetime with srcb
    ushort* lnb  = (ushort*)(M0r + 3211264);
    ushort* F1b  = (ushort*)F1;
    ushort* M0b  = (ushort*)F1;
    ushort* wt_patch = WTS;
    ushort* wt_qkv   = WTS + 98304;
    ushort* wt_out   = WTS + 147456;
    ushort* wt_ff1   = WTS + 163840;
    ushort* wt_ff2   = WTS + 172032;
    ushort* wt_ckv   = WTS + 180224;

    const float rs = 0.17677669529663687f;  // 1/sqrt(32)

    // ---- weight convert + patchify ----
    k_wconv<<<dim3(832), 256, 0, stream>>>(patch_W, enc_qkv_W, enc_out_W,
                                           enc_ff1_W, enc_ff2_W, dec_ca_qkv_W, WTS);
    k_patchify<<<dim3(14, 256), 256, 0, stream>>>(image, Apm);

    // ---- encoder ----
    k_gemm_bf16<128><<<dim3(392, 1), 256, 0, stream>>>(
        Apm, 768, wt_patch, 768, patch_b, S0, srcb, 128, pos_emb, 0);
    k_gemm_bf16<128><<<dim3(392, 3), 256, 0, stream>>>(
        srcb, 128, wt_qkv, 128, enc_qkv_b, nullptr, QKVb, 384, nullptr, 0);
    k_attn_mfma<<<dim3(1024), 256, 0, stream>>>(QKVb, T0b, rs);
    k_gemm_bf16<128><<<dim3(392, 1), 256, 0, stream>>>(
        T0b, 128, wt_out, 128, enc_out_b, T1, nullptr, 128, nullptr, 0);
    k_ln<<<dim3(12544), 256, 0, stream>>>(S0, T1, enc_ln1_s, enc_ln1_b, S0, lnb, 50176);
    k_gemm_bf16<64><<<dim3(392, 1), 256, 0, stream>>>(
        lnb, 128, wt_ff1, 128, enc_ff1_b, nullptr, F1b, 64, nullptr, 1);
    k_gemm_bf16<128><<<dim3(392, 1), 256, 0, stream>>>(
        F1b, 64, wt_ff2, 64, enc_ff2_b, T1, nullptr, 128, nullptr, 0);
    k_ln<<<dim3(12544), 256, 0, stream>>>(S0, T1, enc_ln2_s, enc_ln2_b, nullptr, M0b, 50176);

    // ---- sketch MLP + action tokens ----
    k_smallgemm<<<dim3(256), 256, 0, stream>>>(sk, 200, sk1_W, sk1_b, S1s, 256, 1);
    k_smallgemm<<<dim3(256), 256, 0, stream>>>(S1s, 256, sk2_W, sk2_b, S2s, 256, 1);
    k_smallgemm<<<dim3(256), 256, 0, stream>>>(S2s, 256, sk3_W, sk3_b, S3s, 100, 0);
    k_tgt<<<dim3(256), 128, 0, stream>>>(S3s, angle, pos_x, pos_y, act_W, act_b, TG);

    // ---- decoder self-attention ----
    k_gemm64<<<dim3(60, 6), 256, 0, stream>>>(TG, 128, dec_sa_qkv_W, 384, dec_sa_qkv_b, DQKV, 384, 0);
    k_attn<<<dim3(1024), 256, 0, stream>>>(DQKV, 384, DQKV, 384, 128, 256,
                                           DT0, nullptr, 15, 15, rs);
    k_gemm64<<<dim3(60, 2), 256, 0, stream>>>(DT0, 128, dec_sa_out_W, 128, dec_sa_out_b, DT1, 128, 0);
    k_ln<<<dim3(960), 256, 0, stream>>>(TG, DT1, dec_ln1_s, dec_ln1_b, TG, nullptr, 3840);

    // ---- decoder cross-attention ----
    k_gemm64<<<dim3(60, 2), 256, 0, stream>>>(TG, 128, dec_ca_qkv_W, 384, dec_ca_qkv_b, DQ, 128, 0);
    k_gemm_bf16<128><<<dim3(392, 2), 256, 0, stream>>>(
        M0b, 128, wt_ckv, 128, dec_ca_qkv_b + 128, KV, nullptr, 256, nullptr, 0);
    k_attn<<<dim3(1024), 256, 0, stream>>>(DQ, 128, KV, 256, 0, 128,
                                           DT0, nullptr, 15, 196, rs);
    k_gemm64<<<dim3(60, 2), 256, 0, stream>>>(DT0, 128, dec_ca_out_W, 128, dec_ca_out_b, DT1, 128, 0);
    k_ln<<<dim3(960), 256, 0, stream>>>(TG, DT1, dec_ln2_s, dec_ln2_b, TG, nullptr, 3840);

    // ---- decoder FF + final norms ----
    k_gemm64<<<dim3(60, 1), 256, 0, stream>>>(TG, 128, dec_ff1_W, 64, dec_ff1_b, DF1, 64, 1);
    k_gemm64<<<dim3(60, 2), 256, 0, stream>>>(DF1, 64, dec_ff2_W, 128, dec_ff2_b, DT1, 128, 0);
    k_ln<<<dim3(960), 256, 0, stream>>>(TG, DT1, dec_ln3_s, dec_ln3_b, TG, nullptr, 3840);
    k_ln<<<dim3(960), 256, 0, stream>>>(TG, nullptr, dec_norm_s, dec_norm_b, DT0, nullptr, 3840);

    // ---- head ----
    k_gemm64<<<dim3(60, 2), 256, 0, stream>>>(DT0, 128, l1_W, 128, l1_b, DH, 128, 1);
    k_head<<<dim3(960), 256, 0, stream>>>(DH, l2_W, l2_b, (float*)d_out);
}

// Round 4
// 487.253 us; speedup vs baseline: 2.6977x; 1.1663x over previous
//
#include <hip/hip_runtime.h>
#include <math.h>

#define BSZ 256
#define DIM 128
#define NHD 4
#define NPATCH 196
#define NACT 15

typedef float f32x4 __attribute__((ext_vector_type(4)));
typedef __bf16 bf16x8 __attribute__((ext_vector_type(8)));
typedef short short8 __attribute__((ext_vector_type(8)));

__device__ __forceinline__ float wred_sum(float v) {
#pragma unroll
    for (int m = 1; m < 64; m <<= 1) v += __shfl_xor(v, m, 64);
    return v;
}
__device__ __forceinline__ float wred_max(float v) {
#pragma unroll
    for (int m = 1; m < 64; m <<= 1) v = fmaxf(v, __shfl_xor(v, m, 64));
    return v;
}
__device__ __forceinline__ ushort f2bf(float f) {  // RNE bf16
    unsigned u = __float_as_uint(f);
    return (ushort)((u + 0x7fffu + ((u >> 16) & 1u)) >> 16);
}

// ---------------------------------------------------------------------------
// Patchify: image (f32) -> Apm[m][k'] bf16, m = p*256+b, PERMUTED K:
// k' = c*256 + p1*16 + p2  (wt_patch uses the same permutation).
// grid (14 [h], 256 [b]); float4 coalesced reads -> LDS [14][776] bf16
// (stride 776 ushort = 1552 B = +4 banks/patch -> <=2-way conflicts) ->
// ushort8 fully-coalesced writes of contiguous 1536 B patch rows.
// ---------------------------------------------------------------------------
__global__ __launch_bounds__(256) void k_patchify(
    const float* __restrict__ img, ushort* __restrict__ Apm)
{
    __shared__ ushort xb[14 * 776];
    const int h = blockIdx.x, b = blockIdx.y, t = threadIdx.x;
    const float* g = img + (size_t)b * 150528 + h * (16 * 224);
    for (int idx = t; idx < 2688; idx += 256) {  // 48 rows x 56 float4
        const int row = idx / 56;   // c*16 + p1
        const int xq = idx % 56;    // float4 index along width
        const int c = row >> 4, p1 = row & 15;
        const float4 v = *(const float4*)(g + c * 50176 + p1 * 224 + xq * 4);
        const int wq = xq >> 2;
        const int dst = wq * 776 + c * 256 + p1 * 16 + (xq & 3) * 4;
        ushort4 o;
        o.x = f2bf(v.x); o.y = f2bf(v.y); o.z = f2bf(v.z); o.w = f2bf(v.w);
        *(ushort4*)(xb + dst) = o;
    }
    __syncthreads();
    for (int idx = t; idx < 1344; idx += 256) {  // 14 patches x 96 ushort8
        const int wq = idx / 96, j = idx % 96;
        const size_t o = ((size_t)(h * 14 + wq) * 256 + b) * 768 + j * 8;
        *(short8*)(Apm + o) = *(const short8*)(xb + wq * 776 + j * 8);
    }
}

// ---------------------------------------------------------------------------
// Weight convert+transpose to bf16 [N][K], packed. Patch weights use the
// patchify K-permutation: k' = c*256 + q  <->  k = q*3 + c.
// ---------------------------------------------------------------------------
__global__ __launch_bounds__(256) void k_wconv(
    const float* __restrict__ pW, const float* __restrict__ qkvW,
    const float* __restrict__ outW, const float* __restrict__ ff1W,
    const float* __restrict__ ff2W, const float* __restrict__ ckvW,
    ushort* __restrict__ o)
{
    int i = blockIdx.x * 256 + threadIdx.x;
    if (i < 98304) {
        int n = i / 768, kp = i % 768;
        int c = kp >> 8, q = kp & 255;
        o[i] = f2bf(pW[(q * 3 + c) * 128 + n]); return;
    }
    i -= 98304;
    if (i < 49152) { int n = i >> 7, k = i & 127; o[98304 + i] = f2bf(qkvW[k * 384 + n]); return; }
    i -= 49152;
    if (i < 16384) { int n = i >> 7, k = i & 127; o[147456 + i] = f2bf(outW[k * 128 + n]); return; }
    i -= 16384;
    if (i < 8192)  { int n = i >> 7, k = i & 127; o[163840 + i] = f2bf(ff1W[k * 64 + n]); return; }
    i -= 8192;
    if (i < 8192)  { int n = i >> 6, k = i & 63;  o[172032 + i] = f2bf(ff2W[k * 128 + n]); return; }
    i -= 8192;
    if (i < 32768) { int n = i >> 7, k = i & 127; o[180224 + i] = f2bf(ckvW[k * 384 + 128 + n]); return; }
}

// ---------------------------------------------------------------------------
// bf16 MFMA GEMM (verified): BM=128, BN {64,128}, BK=64.
// ---------------------------------------------------------------------------
template <int BN>
__global__ __launch_bounds__(256) void k_gemm_bf16(
    const ushort* __restrict__ A, int lda,
    const ushort* __restrict__ Wt, int K,
    const float* __restrict__ bias,
    float* __restrict__ C, ushort* __restrict__ Cb, int ldc,
    const float* __restrict__ pe, int relu)
{
    constexpr int NWN = BN / 64;
    constexpr int NWM = 4 / NWN;
    constexpr int WTM = 128 / NWM;
    constexpr int MF = WTM / 16;
    __shared__ ushort As[128 * 64];
    __shared__ ushort Ws[BN * 64];
    const int t = threadIdx.x;
    const int w = t >> 6, l = t & 63;
    const int r0 = blockIdx.x * 128;
    const int n0 = blockIdx.y * BN;
    const int wm = w / NWN, wn = w % NWN;
    const int lrow = l & 15, lk = l >> 4;

    f32x4 acc[MF][4];
#pragma unroll
    for (int m = 0; m < MF; ++m)
#pragma unroll
        for (int n = 0; n < 4; ++n) acc[m][n] = (f32x4)0.f;

    for (int kc = 0; kc < K; kc += 64) {
        __syncthreads();
#pragma unroll
        for (int i = t; i < 128 * 8; i += 256) {
            const int row = i >> 3, ch = i & 7;
            const int sw = (ch * 16) ^ ((row & 7) << 4);
            *(short8*)((char*)As + row * 128 + sw) =
                *(const short8*)(A + (size_t)(r0 + row) * lda + kc + ch * 8);
        }
#pragma unroll
        for (int i = t; i < BN * 8; i += 256) {
            const int row = i >> 3, ch = i & 7;
            const int sw = (ch * 16) ^ ((row & 7) << 4);
            *(short8*)((char*)Ws + row * 128 + sw) =
                *(const short8*)(Wt + (size_t)(n0 + row) * K + kc + ch * 8);
        }
        __syncthreads();
#pragma unroll
        for (int ks = 0; ks < 2; ++ks) {
            bf16x8 af[MF], bfr[4];
#pragma unroll
            for (int m = 0; m < MF; ++m) {
                const int row = wm * WTM + m * 16 + lrow;
                const int col = (ks * 64 + lk * 16) ^ ((row & 7) << 4);
                af[m] = *(const bf16x8*)((const char*)As + row * 128 + col);
            }
#pragma unroll
            for (int n = 0; n < 4; ++n) {
                const int row = wn * 64 + n * 16 + lrow;
                const int col = (ks * 64 + lk * 16) ^ ((row & 7) << 4);
                bfr[n] = *(const bf16x8*)((const char*)Ws + row * 128 + col);
            }
#pragma unroll
            for (int m = 0; m < MF; ++m)
#pragma unroll
                for (int n = 0; n < 4; ++n)
                    acc[m][n] = __builtin_amdgcn_mfma_f32_16x16x32_bf16(
                        af[m], bfr[n], acc[m][n], 0, 0, 0);
        }
    }

    const int crow0 = (l >> 4) * 4;
    const int ccol = l & 15;
#pragma unroll
    for (int m = 0; m < MF; ++m) {
        const int growb = r0 + wm * WTM + m * 16 + crow0;
#pragma unroll
        for (int n = 0; n < 4; ++n) {
            const int gcol = n0 + wn * 64 + n * 16 + ccol;
            const float bv = bias[gcol];
#pragma unroll
            for (int j = 0; j < 4; ++j) {
                const int grow = growb + j;
                float v = acc[m][n][j] + bv;
                if (pe) v += pe[(grow >> 8) * 128 + gcol];
                if (relu) v = fmaxf(v, 0.f);
                if (C)  C[(size_t)grow * ldc + gcol] = v;
                if (Cb) Cb[(size_t)grow * ldc + gcol] = f2bf(v);
            }
        }
    }
}

// ---------------------------------------------------------------------------
// MFMA flash attention, encoder self-attn (as round 3, verified).
// ---------------------------------------------------------------------------
__global__ __launch_bounds__(256) void k_attn_mfma(
    const ushort* __restrict__ qkv, ushort* __restrict__ ob, float scale)
{
    __shared__ ushort Ks[208 * 40];
    __shared__ ushort Vt[32 * 232];
    __shared__ ushort Ps[4][16 * 232];
    const int bh = blockIdx.x;
    const int b = bh >> 2, h = bh & 3;
    const int t = threadIdx.x, w = t >> 6, l = t & 63;
    const int lr = l & 15, lg = l >> 4;

    for (int idx = t; idx < 784; idx += 256) {
        const int j = idx >> 2, ch = idx & 3;
        const size_t base = ((size_t)j * 256 + b) * 384 + h * 32 + ch * 8;
        *(short8*)(Ks + j * 40 + ch * 8) = *(const short8*)(qkv + base + 128);
        short8 v = *(const short8*)(qkv + base + 256);
#pragma unroll
        for (int q = 0; q < 8; ++q)
            Vt[(ch * 8 + q) * 232 + j] = (ushort)v[q];
    }
    for (int idx = t; idx < 32 * 36; idx += 256)
        Vt[(idx / 36) * 232 + 196 + (idx % 36)] = 0;
    for (int i = l; i < 256; i += 64)
        Ps[w][(i >> 4) * 232 + 208 + (i & 15)] = 0;
    __syncthreads();

    for (int qt = w; qt < 13; qt += 4) {
        int qr = qt * 16 + lr; if (qr > 195) qr = 195;
        const bf16x8 qf = *(const bf16x8*)(qkv + ((size_t)qr * 256 + b) * 384 + h * 32 + lg * 8);

        f32x4 s[13];
#pragma unroll
        for (int jn = 0; jn < 13; ++jn) {
            const bf16x8 kf = *(const bf16x8*)(Ks + (jn * 16 + lr) * 40 + lg * 8);
            s[jn] = __builtin_amdgcn_mfma_f32_16x16x32_bf16(qf, kf, (f32x4)0.f, 0, 0, 0);
        }
        if (lr >= 4) {
            s[12][0] = -3.0e38f; s[12][1] = -3.0e38f;
            s[12][2] = -3.0e38f; s[12][3] = -3.0e38f;
        }

        float inv[4];
        ushort* pw = Ps[w];
#pragma unroll
        for (int j = 0; j < 4; ++j) {
            float m = s[0][j];
#pragma unroll
            for (int jn = 1; jn < 13; ++jn) m = fmaxf(m, s[jn][j]);
            m = fmaxf(m, __shfl_xor(m, 1, 64));
            m = fmaxf(m, __shfl_xor(m, 2, 64));
            m = fmaxf(m, __shfl_xor(m, 4, 64));
            m = fmaxf(m, __shfl_xor(m, 8, 64));
            float sum = 0.f;
#pragma unroll
            for (int jn = 0; jn < 13; ++jn) {
                const float p = __expf((s[jn][j] - m) * scale);
                s[jn][j] = p;
                sum += p;
            }
            sum += __shfl_xor(sum, 1, 64);
            sum += __shfl_xor(sum, 2, 64);
            sum += __shfl_xor(sum, 4, 64);
            sum += __shfl_xor(sum, 8, 64);
            inv[j] = 1.0f / sum;
        }
#pragma unroll
        for (int jn = 0; jn < 13; ++jn)
#pragma unroll
            for (int j = 0; j < 4; ++j)
                pw[(lg * 4 + j) * 232 + jn * 16 + lr] = f2bf(s[jn][j]);

        f32x4 o0 = (f32x4)0.f, o1 = (f32x4)0.f;
#pragma unroll
        for (int kt = 0; kt < 7; ++kt) {
            const bf16x8 pf = *(const bf16x8*)(pw + lr * 232 + kt * 32 + lg * 8);
            const bf16x8 v0 = *(const bf16x8*)(Vt + lr * 232 + kt * 32 + lg * 8);
            const bf16x8 v1 = *(const bf16x8*)(Vt + (16 + lr) * 232 + kt * 32 + lg * 8);
            o0 = __builtin_amdgcn_mfma_f32_16x16x32_bf16(pf, v0, o0, 0, 0, 0);
            o1 = __builtin_amdgcn_mfma_f32_16x16x32_bf16(pf, v1, o1, 0, 0, 0);
        }
#pragma unroll
        for (int j = 0; j < 4; ++j) {
            const int r = qt * 16 + lg * 4 + j;
            if (r < 196) {
                const size_t o = ((size_t)r * 256 + b) * 128 + h * 32;
                ob[o + lr]      = f2bf(o0[j] * inv[j]);
                ob[o + 16 + lr] = f2bf(o1[j] * inv[j]);
            }
        }
    }
}

// ---------------------------------------------------------------------------
// f32 tiled GEMM (decoder-sized).
// ---------------------------------------------------------------------------
__global__ __launch_bounds__(256) void k_gemm64(
    const float* __restrict__ A, int K,
    const float* __restrict__ W, int wstride,
    const float* __restrict__ bias,
    float* __restrict__ C, int cstride, int relu)
{
    __shared__ float As[64 * 132];
    __shared__ float Ws2[128 * 68];
    const int t = threadIdx.x;
    const int r0 = blockIdx.x * 64;
    const int n0 = blockIdx.y * 64;
    const int as = K + 4;
    const int lg = (K == 128) ? 5 : 4;
    const int kmask = (K >> 2) - 1;

    for (int idx = t; idx < (K << 4); idx += 256) {
        const int row = idx >> lg;
        const int kk = idx & kmask;
        *(float4*)(&As[row * as + kk * 4]) =
            *(const float4*)(A + (size_t)(r0 + row) * K + kk * 4);
    }
    for (int idx = t; idx < (K << 4); idx += 256) {
        const int kk = idx >> 4;
        const int nq = idx & 15;
        *(float4*)(&Ws2[kk * 68 + nq * 4]) =
            *(const float4*)(W + (size_t)kk * wstride + n0 + nq * 4);
    }
    __syncthreads();

    const int tx = t & 15, ty = t >> 4;
    float4 acc[4];
#pragma unroll
    for (int i = 0; i < 4; ++i) acc[i] = make_float4(0.f, 0.f, 0.f, 0.f);
    const float* arow = &As[(ty * 4) * as];
    for (int k = 0; k < K; ++k) {
        const float4 wv = *(const float4*)(&Ws2[k * 68 + tx * 4]);
#pragma unroll
        for (int i = 0; i < 4; ++i) {
            const float av = arow[i * as + k];
            acc[i].x += av * wv.x; acc[i].y += av * wv.y;
            acc[i].z += av * wv.z; acc[i].w += av * wv.w;
        }
    }
    const float4 bv = *(const float4*)(bias + n0 + tx * 4);
#pragma unroll
    for (int i = 0; i < 4; ++i) {
        float4 o;
        o.x = acc[i].x + bv.x; o.y = acc[i].y + bv.y;
        o.z = acc[i].z + bv.z; o.w = acc[i].w + bv.w;
        if (relu) {
            o.x = fmaxf(o.x, 0.f); o.y = fmaxf(o.y, 0.f);
            o.z = fmaxf(o.z, 0.f); o.w = fmaxf(o.w, 0.f);
        }
        *(float4*)(C + (size_t)(r0 + ty * 4 + i) * cstride + n0 + tx * 4) = o;
    }
}

// ---------------------------------------------------------------------------
// Fused attention (f32, decoder paths): block per (b,h); K/V in LDS.
// ---------------------------------------------------------------------------
__global__ __launch_bounds__(256) void k_attn(
    const float* __restrict__ qp, int qstride,
    const float* __restrict__ kvp, int kvstride, int koff, int voff,
    float* __restrict__ op, ushort* __restrict__ ob,
    int Lq, int Lk, float scale)
{
    __shared__ float Kl[196 * 36];
    __shared__ float Vl[196 * 32];
    __shared__ float pbuf[4][256];
    const int bh = blockIdx.x;
    const int b = bh >> 2;
    const int h = bh & 3;
    const int t = threadIdx.x;
    const int w = t >> 6;
    const int l = t & 63;

    for (int idx = t; idx < Lk * 8; idx += 256) {
        const int j = idx >> 3;
        const int kq = idx & 7;
        const size_t row = ((size_t)j * 256 + b) * kvstride + h * 32 + kq * 4;
        *(float4*)(&Kl[j * 36 + kq * 4]) = *(const float4*)(kvp + row + koff);
        *(float4*)(&Vl[j * 32 + kq * 4]) = *(const float4*)(kvp + row + voff);
    }
    if ((Lk & 1) && t < 8) *(float4*)(&Vl[Lk * 32 + t * 4]) = make_float4(0.f, 0.f, 0.f, 0.f);
    __syncthreads();

    const int Lh = (Lk + 1) >> 1;
    const int half = l >> 5;
    const int kk = l & 31;
    const int jb = half * Lh;

    for (int jq = w; jq < Lq; jq += 4) {
        const float* qrow = qp + ((size_t)jq * 256 + b) * qstride + h * 32;
        float4 q4[8];
#pragma unroll
        for (int kq = 0; kq < 8; ++kq) q4[kq] = *(const float4*)(qrow + kq * 4);

        float s[4];
#pragma unroll
        for (int r = 0; r < 4; ++r) {
            const int j = l + (r << 6);
            float acc = -3.0e38f;
            if (j < Lk) {
                acc = 0.f;
#pragma unroll
                for (int kq = 0; kq < 8; ++kq) {
                    const float4 kv = *(const float4*)(&Kl[j * 36 + kq * 4]);
                    acc += q4[kq].x * kv.x + q4[kq].y * kv.y +
                           q4[kq].z * kv.z + q4[kq].w * kv.w;
                }
                acc *= scale;
            }
            s[r] = acc;
        }
        float m = fmaxf(fmaxf(s[0], s[1]), fmaxf(s[2], s[3]));
        m = wred_max(m);
        float sum = 0.f;
#pragma unroll
        for (int r = 0; r < 4; ++r) {
            const int j = l + (r << 6);
            float p = __expf(s[r] - m);
            if (j >= Lk) p = 0.f;
            pbuf[w][j] = p;
            sum += p;
        }
        sum = wred_sum(sum);
        const float inv = 1.0f / sum;
        __threadfence_block();

        float o = 0.f;
        for (int jj = 0; jj < Lh; ++jj) {
            const float pv = pbuf[w][jb + jj];
            const float vv = Vl[(jb + jj) * 32 + kk];
            o += pv * vv;
        }
        o += __shfl_xor(o, 32, 64);
        o *= inv;
        if (l < 32) {
            const size_t oi = ((size_t)jq * 256 + b) * 128 + h * 32 + l;
            if (op) op[oi] = o;
            if (ob) ob[oi] = f2bf(o);
        }
        __threadfence_block();
    }
}

// ---------------------------------------------------------------------------
// LayerNorm over D=128, optional residual; f32 and/or bf16 outputs.
// ---------------------------------------------------------------------------
__global__ __launch_bounds__(256) void k_ln(
    const float* __restrict__ a, const float* __restrict__ r,
    const float* __restrict__ s, const float* __restrict__ bi,
    float* __restrict__ o, ushort* __restrict__ ob, int ntok)
{
    const int tok = blockIdx.x * 4 + (threadIdx.x >> 6);
    const int l = threadIdx.x & 63;
    float2 x = ((const float2*)a)[(size_t)tok * 64 + l];
    if (r) {
        const float2 rr = ((const float2*)r)[(size_t)tok * 64 + l];
        x.x += rr.x; x.y += rr.y;
    }
    const float mean = wred_sum(x.x + x.y) * (1.f / 128.f);
    const float dx = x.x - mean, dy = x.y - mean;
    const float var = wred_sum(dx * dx + dy * dy) * (1.f / 128.f);
    const float rstd = rsqrtf(var + 1e-5f);
    const float2 sv = ((const float2*)s)[l];
    const float2 bv = ((const float2*)bi)[l];
    float2 out;
    out.x = dx * rstd * sv.x + bv.x;
    out.y = dy * rstd * sv.y + bv.y;
    if (o) ((float2*)o)[(size_t)tok * 64 + l] = out;
    if (ob) {
        ushort2 ov; ov.x = f2bf(out.x); ov.y = f2bf(out.y);
        ((ushort2*)ob)[(size_t)tok * 64 + l] = ov;
    }
}

__global__ __launch_bounds__(256) void k_smallgemm(
    const float* __restrict__ x, int K,
    const float* __restrict__ W, const float* __restrict__ bi,
    float* __restrict__ o, int N, int relu)
{
    __shared__ float xr[256];
    const int row = blockIdx.x;
    const int t = threadIdx.x;
    if (t < K) xr[t] = x[(size_t)row * K + t];
    __syncthreads();
    if (t < N) {
        float acc = bi[t];
        for (int k = 0; k < K; ++k) acc += xr[k] * W[(size_t)k * N + t];
        if (relu) acc = fmaxf(acc, 0.f);
        o[(size_t)row * N + t] = acc;
    }
}

__global__ __launch_bounds__(128) void k_tgt(
    const float* __restrict__ s3, const float* __restrict__ ang,
    const float* __restrict__ px, const float* __restrict__ py,
    const float* __restrict__ W, const float* __restrict__ bi,
    float* __restrict__ tg)
{
    const int b = blockIdx.x;
    const int d = threadIdx.x;
    float acc = bi[d] + ang[b] * W[15 * 128 + d] + px[b] * W[16 * 128 + d] +
                py[b] * W[17 * 128 + d];
    for (int k = 0; k < 100; ++k) acc += s3[b * 100 + k] * W[(18 + k) * 128 + d];
#pragma unroll
    for (int i = 0; i < 15; ++i)
        tg[((size_t)i * 256 + b) * 128 + d] = acc + W[i * 128 + d];
}

__global__ __launch_bounds__(256) void k_head(
    const float* __restrict__ hbuf, const float* __restrict__ w2,
    const float* __restrict__ b2, float* __restrict__ out)
{
    const int tok = blockIdx.x * 4 + (threadIdx.x >> 6);
    const int l = threadIdx.x & 63;
    const float2 x = ((const float2*)hbuf)[(size_t)tok * 64 + l];
    const float2 wv = ((const float2*)w2)[l];
    const float v = wred_sum(x.x * wv.x + x.y * wv.y);
    if (l == 0) {
        const int i = tok >> 8;
        const int b = tok & 255;
        out[b * 15 + i] = v + b2[0];
    }
}

// ---------------------------------------------------------------------------
extern "C" void kernel_launch(void* const* d_in, const int* in_sizes, int n_in,
                              void* d_out, int out_size, void* d_ws, size_t ws_size,
                              hipStream_t stream)
{
    (void)in_sizes; (void)n_in; (void)out_size; (void)ws_size;
    const float* image      = (const float*)d_in[0];
    const float* angle      = (const float*)d_in[1];
    const float* pos_x      = (const float*)d_in[2];
    const float* pos_y      = (const float*)d_in[3];
    const float* sk         = (const float*)d_in[4];
    const float* patch_W    = (const float*)d_in[5];
    const float* patch_b    = (const float*)d_in[6];
    const float* pos_emb    = (const float*)d_in[7];
    const float* enc_qkv_W  = (const float*)d_in[8];
    const float* enc_qkv_b  = (const float*)d_in[9];
    const float* enc_out_W  = (const float*)d_in[10];
    const float* enc_out_b  = (const float*)d_in[11];
    const float* enc_ln1_s  = (const float*)d_in[12];
    const float* enc_ln1_b  = (const float*)d_in[13];
    const float* enc_ff1_W  = (const float*)d_in[14];
    const float* enc_ff1_b  = (const float*)d_in[15];
    const float* enc_ff2_W  = (const float*)d_in[16];
    const float* enc_ff2_b  = (const float*)d_in[17];
    const float* enc_ln2_s  = (const float*)d_in[18];
    const float* enc_ln2_b  = (const float*)d_in[19];
    const float* dec_sa_qkv_W = (const float*)d_in[20];
    const float* dec_sa_qkv_b = (const float*)d_in[21];
    const float* dec_sa_out_W = (const float*)d_in[22];
    const float* dec_sa_out_b = (const float*)d_in[23];
    const float* dec_ca_qkv_W = (const float*)d_in[24];
    const float* dec_ca_qkv_b = (const float*)d_in[25];
    const float* dec_ca_out_W = (const float*)d_in[26];
    const float* dec_ca_out_b = (const float*)d_in[27];
    const float* dec_ln1_s  = (const float*)d_in[28];
    const float* dec_ln1_b  = (const float*)d_in[29];
    const float* dec_ln2_s  = (const float*)d_in[30];
    const float* dec_ln2_b  = (const float*)d_in[31];
    const float* dec_ln3_s  = (const float*)d_in[32];
    const float* dec_ln3_b  = (const float*)d_in[33];
    const float* dec_ff1_W  = (const float*)d_in[34];
    const float* dec_ff1_b  = (const float*)d_in[35];
    const float* dec_ff2_W  = (const float*)d_in[36];
    const float* dec_ff2_b  = (const float*)d_in[37];
    const float* dec_norm_s = (const float*)d_in[38];
    const float* dec_norm_b = (const float*)d_in[39];
    const float* sk1_W = (const float*)d_in[40];
    const float* sk1_b = (const float*)d_in[41];
    const float* sk2_W = (const float*)d_in[42];
    const float* sk2_b = (const float*)d_in[43];
    const float* sk3_W = (const float*)d_in[44];
    const float* sk3_b = (const float*)d_in[45];
    const float* act_W = (const float*)d_in[46];
    const float* act_b = (const float*)d_in[47];
    const float* l1_W  = (const float*)d_in[48];
    const float* l1_b  = (const float*)d_in[49];
    const float* l2_W  = (const float*)d_in[50];
    const float* l2_b  = (const float*)d_in[51];

    // Workspace layout (float offsets); peak ~195.7 MB.
    float* ws = (float*)d_ws;
    float* S0   = ws;               // src f32                 [6,422,528]
    float* QKVr = ws + 6422528;     // big overlay region      [19,267,584]
    float* T0   = ws + 25690112;    // f32 attn out (decoder)  [6,422,528]
    float* T1   = ws + 32112640;    // proj/ff2 out f32        [6,422,528]
    float* F1   = ws + 38535168;    // [3,211,264] F1b bf16 -> M0b bf16
    float* M0r  = ws + 41746432;    // [6,422,528] srcb/T0b | lnb bf16
    float* S1s  = ws + 48168960;
    float* S2s  = S1s + 65536;
    float* S3s  = S2s + 65536;
    float* TG   = S3s + 25600;
    ushort* WTS = (ushort*)(ws + 48817152);

    // Overlays
    ushort* Apm  = (ushort*)QKVr;            // patch matrix (patch phase)
    ushort* QKVb = (ushort*)QKVr;            // enc QKV bf16 [50176][384]
    float*  KV   = QKVr;                     // cross K/V f32 (after enc attn)
    float* DQKV = QKVr + 12845056;
    float* DQ   = QKVr + 14319616;
    float* DH   = QKVr + 14811136;
    float* DT0  = T0;
    float* DT1  = T1;
    float* DF1  = F1;
    ushort* srcb = (ushort*)M0r;
    ushort* T0b  = (ushort*)M0r;             // disjoint lifetime with srcb
    ushort* lnb  = (ushort*)(M0r + 3211264);
    ushort* F1b  = (ushort*)F1;
    ushort* M0b  = (ushort*)F1;
    ushort* wt_patch = WTS;
    ushort* wt_qkv   = WTS + 98304;
    ushort* wt_out   = WTS + 147456;
    ushort* wt_ff1   = WTS + 163840;
    ushort* wt_ff2   = WTS + 172032;
    ushort* wt_ckv   = WTS + 180224;

    const float rs = 0.17677669529663687f;  // 1/sqrt(32)

    // ---- weight convert + patchify ----
    k_wconv<<<dim3(832), 256, 0, stream>>>(patch_W, enc_qkv_W, enc_out_W,
                                           enc_ff1_W, enc_ff2_W, dec_ca_qkv_W, WTS);
    k_patchify<<<dim3(14, 256), 256, 0, stream>>>(image, Apm);

    // ---- encoder ----
    k_gemm_bf16<128><<<dim3(392, 1), 256, 0, stream>>>(
        Apm, 768, wt_patch, 768, patch_b, S0, srcb, 128, pos_emb, 0);
    k_gemm_bf16<128><<<dim3(392, 3), 256, 0, stream>>>(
        srcb, 128, wt_qkv, 128, enc_qkv_b, nullptr, QKVb, 384, nullptr, 0);
    k_attn_mfma<<<dim3(1024), 256, 0, stream>>>(QKVb, T0b, rs);
    k_gemm_bf16<128><<<dim3(392, 1), 256, 0, stream>>>(
        T0b, 128, wt_out, 128, enc_out_b, T1, nullptr, 128, nullptr, 0);
    k_ln<<<dim3(12544), 256, 0, stream>>>(S0, T1, enc_ln1_s, enc_ln1_b, S0, lnb, 50176);
    k_gemm_bf16<64><<<dim3(392, 1), 256, 0, stream>>>(
        lnb, 128, wt_ff1, 128, enc_ff1_b, nullptr, F1b, 64, nullptr, 1);
    k_gemm_bf16<128><<<dim3(392, 1), 256, 0, stream>>>(
        F1b, 64, wt_ff2, 64, enc_ff2_b, T1, nullptr, 128, nullptr, 0);
    k_ln<<<dim3(12544), 256, 0, stream>>>(S0, T1, enc_ln2_s, enc_ln2_b, nullptr, M0b, 50176);

    // ---- sketch MLP + action tokens ----
    k_smallgemm<<<dim3(256), 256, 0, stream>>>(sk, 200, sk1_W, sk1_b, S1s, 256, 1);
    k_smallgemm<<<dim3(256), 256, 0, stream>>>(S1s, 256, sk2_W, sk2_b, S2s, 256, 1);
    k_smallgemm<<<dim3(256), 256, 0, stream>>>(S2s, 256, sk3_W, sk3_b, S3s, 100, 0);
    k_tgt<<<dim3(256), 128, 0, stream>>>(S3s, angle, pos_x, pos_y, act_W, act_b, TG);

    // ---- decoder self-attention ----
    k_gemm64<<<dim3(60, 6), 256, 0, stream>>>(TG, 128, dec_sa_qkv_W, 384, dec_sa_qkv_b, DQKV, 384, 0);
    k_attn<<<dim3(1024), 256, 0, stream>>>(DQKV, 384, DQKV, 384, 128, 256,
                                           DT0, nullptr, 15, 15, rs);
    k_gemm64<<<dim3(60, 2), 256, 0, stream>>>(DT0, 128, dec_sa_out_W, 128, dec_sa_out_b, DT1, 128, 0);
    k_ln<<<dim3(960), 256, 0, stream>>>(TG, DT1, dec_ln1_s, dec_ln1_b, TG, nullptr, 3840);

    // ---- decoder cross-attention ----
    k_gemm64<<<dim3(60, 2), 256, 0, stream>>>(TG, 128, dec_ca_qkv_W, 384, dec_ca_qkv_b, DQ, 128, 0);
    k_gemm_bf16<128><<<dim3(392, 2), 256, 0, stream>>>(
        M0b, 128, wt_ckv, 128, dec_ca_qkv_b + 128, KV, nullptr, 256, nullptr, 0);
    k_attn<<<dim3(1024), 256, 0, stream>>>(DQ, 128, KV, 256, 0, 128,
                                           DT0, nullptr, 15, 196, rs);
    k_gemm64<<<dim3(60, 2), 256, 0, stream>>>(DT0, 128, dec_ca_out_W, 128, dec_ca_out_b, DT1, 128, 0);
    k_ln<<<dim3(960), 256, 0, stream>>>(TG, DT1, dec_ln2_s, dec_ln2_b, TG, nullptr, 3840);

    // ---- decoder FF + final norms ----
    k_gemm64<<<dim3(60, 1), 256, 0, stream>>>(TG, 128, dec_ff1_W, 64, dec_ff1_b, DF1, 64, 1);
    k_gemm64<<<dim3(60, 2), 256, 0, stream>>>(DF1, 64, dec_ff2_W, 128, dec_ff2_b, DT1, 128, 0);
    k_ln<<<dim3(960), 256, 0, stream>>>(TG, DT1, dec_ln3_s, dec_ln3_b, TG, nullptr, 3840);
    k_ln<<<dim3(960), 256, 0, stream>>>(TG, nullptr, dec_norm_s, dec_norm_b, DT0, nullptr, 3840);

    // ---- head ----
    k_gemm64<<<dim3(60, 2), 256, 0, stream>>>(DT0, 128, l1_W, 128, l1_b, DH, 128, 1);
    k_head<<<dim3(960), 256, 0, stream>>>(DH, l2_W, l2_b, (float*)d_out);
}

// Round 5
// 415.926 us; speedup vs baseline: 3.1603x; 1.1715x over previous
//
#include <hip/hip_runtime.h>
#include <math.h>

#define BSZ 256
#define DIM 128
#define NHD 4
#define NPATCH 196
#define NACT 15

typedef float f32x4 __attribute__((ext_vector_type(4)));
typedef __bf16 bf16x8 __attribute__((ext_vector_type(8)));
typedef short short8 __attribute__((ext_vector_type(8)));

__device__ __forceinline__ float wred_sum(float v) {
#pragma unroll
    for (int m = 1; m < 64; m <<= 1) v += __shfl_xor(v, m, 64);
    return v;
}
__device__ __forceinline__ float wred_max(float v) {
#pragma unroll
    for (int m = 1; m < 64; m <<= 1) v = fmaxf(v, __shfl_xor(v, m, 64));
    return v;
}
__device__ __forceinline__ ushort f2bf(float f) {  // RNE bf16
    unsigned u = __float_as_uint(f);
    return (ushort)((u + 0x7fffu + ((u >> 16) & 1u)) >> 16);
}

// ---------------------------------------------------------------------------
// Patchify (verified r4): image f32 -> Apm bf16, permuted K: k' = c*256+p1*16+p2.
// ---------------------------------------------------------------------------
__global__ __launch_bounds__(256) void k_patchify(
    const float* __restrict__ img, ushort* __restrict__ Apm)
{
    __shared__ ushort xb[14 * 776];
    const int h = blockIdx.x, b = blockIdx.y, t = threadIdx.x;
    const float* g = img + (size_t)b * 150528 + h * (16 * 224);
    for (int idx = t; idx < 2688; idx += 256) {
        const int row = idx / 56;
        const int xq = idx % 56;
        const int c = row >> 4, p1 = row & 15;
        const float4 v = *(const float4*)(g + c * 50176 + p1 * 224 + xq * 4);
        const int wq = xq >> 2;
        const int dst = wq * 776 + c * 256 + p1 * 16 + (xq & 3) * 4;
        ushort4 o;
        o.x = f2bf(v.x); o.y = f2bf(v.y); o.z = f2bf(v.z); o.w = f2bf(v.w);
        *(ushort4*)(xb + dst) = o;
    }
    __syncthreads();
    for (int idx = t; idx < 1344; idx += 256) {
        const int wq = idx / 96, j = idx % 96;
        const size_t o = ((size_t)(h * 14 + wq) * 256 + b) * 768 + j * 8;
        *(short8*)(Apm + o) = *(const short8*)(xb + wq * 776 + j * 8);
    }
}

// ---------------------------------------------------------------------------
// Weight convert+transpose to bf16 [N][K] (patch K-permuted), packed.
// ---------------------------------------------------------------------------
__global__ __launch_bounds__(256) void k_wconv(
    const float* __restrict__ pW, const float* __restrict__ qkvW,
    const float* __restrict__ outW, const float* __restrict__ ff1W,
    const float* __restrict__ ff2W, const float* __restrict__ ckvW,
    ushort* __restrict__ o)
{
    int i = blockIdx.x * 256 + threadIdx.x;
    if (i < 98304) {
        int n = i / 768, kp = i % 768;
        int c = kp >> 8, q = kp & 255;
        o[i] = f2bf(pW[(q * 3 + c) * 128 + n]); return;
    }
    i -= 98304;
    if (i < 49152) { int n = i >> 7, k = i & 127; o[98304 + i] = f2bf(qkvW[k * 384 + n]); return; }
    i -= 49152;
    if (i < 16384) { int n = i >> 7, k = i & 127; o[147456 + i] = f2bf(outW[k * 128 + n]); return; }
    i -= 16384;
    if (i < 8192)  { int n = i >> 7, k = i & 127; o[163840 + i] = f2bf(ff1W[k * 64 + n]); return; }
    i -= 8192;
    if (i < 8192)  { int n = i >> 6, k = i & 63;  o[172032 + i] = f2bf(ff2W[k * 128 + n]); return; }
    i -= 8192;
    if (i < 32768) { int n = i >> 7, k = i & 127; o[180224 + i] = f2bf(ckvW[k * 384 + 128 + n]); return; }
}

// ---------------------------------------------------------------------------
// bf16 MFMA GEMM, BM x BN tile (BM in {64,128}, BN in {64,128}), BK=64.
// ---------------------------------------------------------------------------
template <int BM, int BN>
__global__ __launch_bounds__(256) void k_gemm_bf16(
    const ushort* __restrict__ A, int lda,
    const ushort* __restrict__ Wt, int K,
    const float* __restrict__ bias,
    float* __restrict__ C, ushort* __restrict__ Cb, int ldc,
    const float* __restrict__ pe, int relu)
{
    constexpr int NWN = BN / 64;
    constexpr int NWM = 4 / NWN;
    constexpr int WTM = BM / NWM;
    constexpr int MF = WTM / 16;
    __shared__ ushort As[BM * 64];
    __shared__ ushort Ws[BN * 64];
    const int t = threadIdx.x;
    const int w = t >> 6, l = t & 63;
    const int r0 = blockIdx.x * BM;
    const int n0 = blockIdx.y * BN;
    const int wm = w / NWN, wn = w % NWN;
    const int lrow = l & 15, lk = l >> 4;

    f32x4 acc[MF][4];
#pragma unroll
    for (int m = 0; m < MF; ++m)
#pragma unroll
        for (int n = 0; n < 4; ++n) acc[m][n] = (f32x4)0.f;

    for (int kc = 0; kc < K; kc += 64) {
        __syncthreads();
#pragma unroll
        for (int i = t; i < BM * 8; i += 256) {
            const int row = i >> 3, ch = i & 7;
            const int sw = (ch * 16) ^ ((row & 7) << 4);
            *(short8*)((char*)As + row * 128 + sw) =
                *(const short8*)(A + (size_t)(r0 + row) * lda + kc + ch * 8);
        }
#pragma unroll
        for (int i = t; i < BN * 8; i += 256) {
            const int row = i >> 3, ch = i & 7;
            const int sw = (ch * 16) ^ ((row & 7) << 4);
            *(short8*)((char*)Ws + row * 128 + sw) =
                *(const short8*)(Wt + (size_t)(n0 + row) * K + kc + ch * 8);
        }
        __syncthreads();
#pragma unroll
        for (int ks = 0; ks < 2; ++ks) {
            bf16x8 af[MF], bfr[4];
#pragma unroll
            for (int m = 0; m < MF; ++m) {
                const int row = wm * WTM + m * 16 + lrow;
                const int col = (ks * 64 + lk * 16) ^ ((row & 7) << 4);
                af[m] = *(const bf16x8*)((const char*)As + row * 128 + col);
            }
#pragma unroll
            for (int n = 0; n < 4; ++n) {
                const int row = wn * 64 + n * 16 + lrow;
                const int col = (ks * 64 + lk * 16) ^ ((row & 7) << 4);
                bfr[n] = *(const bf16x8*)((const char*)Ws + row * 128 + col);
            }
#pragma unroll
            for (int m = 0; m < MF; ++m)
#pragma unroll
                for (int n = 0; n < 4; ++n)
                    acc[m][n] = __builtin_amdgcn_mfma_f32_16x16x32_bf16(
                        af[m], bfr[n], acc[m][n], 0, 0, 0);
        }
    }

    const int crow0 = (l >> 4) * 4;
    const int ccol = l & 15;
#pragma unroll
    for (int m = 0; m < MF; ++m) {
        const int growb = r0 + wm * WTM + m * 16 + crow0;
#pragma unroll
        for (int n = 0; n < 4; ++n) {
            const int gcol = n0 + wn * 64 + n * 16 + ccol;
            const float bv = bias[gcol];
#pragma unroll
            for (int j = 0; j < 4; ++j) {
                const int grow = growb + j;
                float v = acc[m][n][j] + bv;
                if (pe) v += pe[(grow >> 8) * 128 + gcol];
                if (relu) v = fmaxf(v, 0.f);
                if (C)  C[(size_t)grow * ldc + gcol] = v;
                if (Cb) Cb[(size_t)grow * ldc + gcol] = f2bf(v);
            }
        }
    }
}

// ---------------------------------------------------------------------------
// bf16 MFMA GEMM 64x128 + residual + LayerNorm fused epilogue.
// out = LN(A@Wt^T + bias + resid) * ln_s + ln_b.  BN=128 == D, so each block
// holds complete rows; row stats via 16-lane shuffles + LDS cross-wave.
// ---------------------------------------------------------------------------
__global__ __launch_bounds__(256) void k_gemm_ln(
    const ushort* __restrict__ A, int lda,
    const ushort* __restrict__ Wt, int K,
    const float* __restrict__ bias,
    const float* __restrict__ resid,
    const float* __restrict__ lns, const float* __restrict__ lnbi,
    float* __restrict__ Co, ushort* __restrict__ Cb)
{
    __shared__ ushort As[64 * 64];
    __shared__ ushort Ws[128 * 64];
    __shared__ float psum[64][2][2];
    const int t = threadIdx.x;
    const int w = t >> 6, l = t & 63;
    const int r0 = blockIdx.x * 64;
    const int wm = w >> 1, wn = w & 1;
    const int lrow = l & 15, lk = l >> 4;

    f32x4 acc[2][4];
#pragma unroll
    for (int m = 0; m < 2; ++m)
#pragma unroll
        for (int n = 0; n < 4; ++n) acc[m][n] = (f32x4)0.f;

    for (int kc = 0; kc < K; kc += 64) {
        __syncthreads();
#pragma unroll
        for (int i = t; i < 64 * 8; i += 256) {
            const int row = i >> 3, ch = i & 7;
            const int sw = (ch * 16) ^ ((row & 7) << 4);
            *(short8*)((char*)As + row * 128 + sw) =
                *(const short8*)(A + (size_t)(r0 + row) * lda + kc + ch * 8);
        }
#pragma unroll
        for (int i = t; i < 128 * 8; i += 256) {
            const int row = i >> 3, ch = i & 7;
            const int sw = (ch * 16) ^ ((row & 7) << 4);
            *(short8*)((char*)Ws + row * 128 + sw) =
                *(const short8*)(Wt + (size_t)row * K + kc + ch * 8);
        }
        __syncthreads();
#pragma unroll
        for (int ks = 0; ks < 2; ++ks) {
            bf16x8 af[2], bfr[4];
#pragma unroll
            for (int m = 0; m < 2; ++m) {
                const int row = wm * 32 + m * 16 + lrow;
                const int col = (ks * 64 + lk * 16) ^ ((row & 7) << 4);
                af[m] = *(const bf16x8*)((const char*)As + row * 128 + col);
            }
#pragma unroll
            for (int n = 0; n < 4; ++n) {
                const int row = wn * 64 + n * 16 + lrow;
                const int col = (ks * 64 + lk * 16) ^ ((row & 7) << 4);
                bfr[n] = *(const bf16x8*)((const char*)Ws + row * 128 + col);
            }
#pragma unroll
            for (int m = 0; m < 2; ++m)
#pragma unroll
                for (int n = 0; n < 4; ++n)
                    acc[m][n] = __builtin_amdgcn_mfma_f32_16x16x32_bf16(
                        af[m], bfr[n], acc[m][n], 0, 0, 0);
        }
    }

    const int crow0 = (l >> 4) * 4;
    const int ccol = l & 15;
    // bias + residual
#pragma unroll
    for (int m = 0; m < 2; ++m) {
        const int growb = r0 + wm * 32 + m * 16 + crow0;
#pragma unroll
        for (int n = 0; n < 4; ++n) {
            const int gcol = wn * 64 + n * 16 + ccol;
            const float bv = bias[gcol];
#pragma unroll
            for (int j = 0; j < 4; ++j) {
                float v = acc[m][n][j] + bv;
                if (resid) v += resid[(size_t)(growb + j) * 128 + gcol];
                acc[m][n][j] = v;
            }
        }
    }
    // row partial stats (sum over n-frags + 16 lanes)
#pragma unroll
    for (int m = 0; m < 2; ++m)
#pragma unroll
        for (int j = 0; j < 4; ++j) {
            float s_ = 0.f, q_ = 0.f;
#pragma unroll
            for (int n = 0; n < 4; ++n) {
                const float x = acc[m][n][j];
                s_ += x; q_ += x * x;
            }
#pragma unroll
            for (int mk = 1; mk < 16; mk <<= 1) {
                s_ += __shfl_xor(s_, mk, 64);
                q_ += __shfl_xor(q_, mk, 64);
            }
            if (ccol == 0) {
                const int r = wm * 32 + m * 16 + crow0 + j;
                psum[r][wn][0] = s_;
                psum[r][wn][1] = q_;
            }
        }
    __syncthreads();
    float mean_[2][4], rstd_[2][4];
#pragma unroll
    for (int m = 0; m < 2; ++m)
#pragma unroll
        for (int j = 0; j < 4; ++j) {
            const int r = wm * 32 + m * 16 + crow0 + j;
            const float sum = psum[r][0][0] + psum[r][1][0];
            const float sq  = psum[r][0][1] + psum[r][1][1];
            const float mean = sum * 0.0078125f;
            const float var = sq * 0.0078125f - mean * mean;
            mean_[m][j] = mean;
            rstd_[m][j] = rsqrtf(var + 1e-5f);
        }
#pragma unroll
    for (int m = 0; m < 2; ++m) {
        const int growb = r0 + wm * 32 + m * 16 + crow0;
#pragma unroll
        for (int n = 0; n < 4; ++n) {
            const int gcol = wn * 64 + n * 16 + ccol;
            const float sv = lns[gcol], bv2 = lnbi[gcol];
#pragma unroll
            for (int j = 0; j < 4; ++j) {
                const float y = (acc[m][n][j] - mean_[m][j]) * rstd_[m][j] * sv + bv2;
                const size_t oi = (size_t)(growb + j) * 128 + gcol;
                if (Co) Co[oi] = y;
                if (Cb) Cb[oi] = f2bf(y);
            }
        }
    }
}

// ---------------------------------------------------------------------------
// MFMA flash attention, encoder self-attn (verified r3).
// ---------------------------------------------------------------------------
__global__ __launch_bounds__(256) void k_attn_mfma(
    const ushort* __restrict__ qkv, ushort* __restrict__ ob, float scale)
{
    __shared__ ushort Ks[208 * 40];
    __shared__ ushort Vt[32 * 232];
    __shared__ ushort Ps[4][16 * 232];
    const int bh = blockIdx.x;
    const int b = bh >> 2, h = bh & 3;
    const int t = threadIdx.x, w = t >> 6, l = t & 63;
    const int lr = l & 15, lg = l >> 4;

    for (int idx = t; idx < 784; idx += 256) {
        const int j = idx >> 2, ch = idx & 3;
        const size_t base = ((size_t)j * 256 + b) * 384 + h * 32 + ch * 8;
        *(short8*)(Ks + j * 40 + ch * 8) = *(const short8*)(qkv + base + 128);
        short8 v = *(const short8*)(qkv + base + 256);
#pragma unroll
        for (int q = 0; q < 8; ++q)
            Vt[(ch * 8 + q) * 232 + j] = (ushort)v[q];
    }
    for (int idx = t; idx < 32 * 36; idx += 256)
        Vt[(idx / 36) * 232 + 196 + (idx % 36)] = 0;
    for (int i = l; i < 256; i += 64)
        Ps[w][(i >> 4) * 232 + 208 + (i & 15)] = 0;
    __syncthreads();

    for (int qt = w; qt < 13; qt += 4) {
        int qr = qt * 16 + lr; if (qr > 195) qr = 195;
        const bf16x8 qf = *(const bf16x8*)(qkv + ((size_t)qr * 256 + b) * 384 + h * 32 + lg * 8);

        f32x4 s[13];
#pragma unroll
        for (int jn = 0; jn < 13; ++jn) {
            const bf16x8 kf = *(const bf16x8*)(Ks + (jn * 16 + lr) * 40 + lg * 8);
            s[jn] = __builtin_amdgcn_mfma_f32_16x16x32_bf16(qf, kf, (f32x4)0.f, 0, 0, 0);
        }
        if (lr >= 4) {
            s[12][0] = -3.0e38f; s[12][1] = -3.0e38f;
            s[12][2] = -3.0e38f; s[12][3] = -3.0e38f;
        }

        float inv[4];
        ushort* pw = Ps[w];
#pragma unroll
        for (int j = 0; j < 4; ++j) {
            float m = s[0][j];
#pragma unroll
            for (int jn = 1; jn < 13; ++jn) m = fmaxf(m, s[jn][j]);
            m = fmaxf(m, __shfl_xor(m, 1, 64));
            m = fmaxf(m, __shfl_xor(m, 2, 64));
            m = fmaxf(m, __shfl_xor(m, 4, 64));
            m = fmaxf(m, __shfl_xor(m, 8, 64));
            float sum = 0.f;
#pragma unroll
            for (int jn = 0; jn < 13; ++jn) {
                const float p = __expf((s[jn][j] - m) * scale);
                s[jn][j] = p;
                sum += p;
            }
            sum += __shfl_xor(sum, 1, 64);
            sum += __shfl_xor(sum, 2, 64);
            sum += __shfl_xor(sum, 4, 64);
            sum += __shfl_xor(sum, 8, 64);
            inv[j] = 1.0f / sum;
        }
#pragma unroll
        for (int jn = 0; jn < 13; ++jn)
#pragma unroll
            for (int j = 0; j < 4; ++j)
                pw[(lg * 4 + j) * 232 + jn * 16 + lr] = f2bf(s[jn][j]);

        f32x4 o0 = (f32x4)0.f, o1 = (f32x4)0.f;
#pragma unroll
        for (int kt = 0; kt < 7; ++kt) {
            const bf16x8 pf = *(const bf16x8*)(pw + lr * 232 + kt * 32 + lg * 8);
            const bf16x8 v0 = *(const bf16x8*)(Vt + lr * 232 + kt * 32 + lg * 8);
            const bf16x8 v1 = *(const bf16x8*)(Vt + (16 + lr) * 232 + kt * 32 + lg * 8);
            o0 = __builtin_amdgcn_mfma_f32_16x16x32_bf16(pf, v0, o0, 0, 0, 0);
            o1 = __builtin_amdgcn_mfma_f32_16x16x32_bf16(pf, v1, o1, 0, 0, 0);
        }
#pragma unroll
        for (int j = 0; j < 4; ++j) {
            const int r = qt * 16 + lg * 4 + j;
            if (r < 196) {
                const size_t o = ((size_t)r * 256 + b) * 128 + h * 32;
                ob[o + lr]      = f2bf(o0[j] * inv[j]);
                ob[o + 16 + lr] = f2bf(o1[j] * inv[j]);
            }
        }
    }
}

// ---------------------------------------------------------------------------
// Decoder f32 GEMM, 64x128 tile, fused epilogue modes:
//   resid+LN [+LN2]; head (relu + dot w2 -> qout); plain C write.
// ---------------------------------------------------------------------------
__global__ __launch_bounds__(256) void k_gdec(
    const float* __restrict__ A, int K,
    const float* __restrict__ W, int wstride,
    const float* __restrict__ bias,
    const float* __restrict__ resid,
    const float* __restrict__ ln1s, const float* __restrict__ ln1b,
    const float* __restrict__ ln2s, const float* __restrict__ ln2b,
    const float* __restrict__ w2, const float* __restrict__ b2h,
    float* __restrict__ C, int ldc, float* __restrict__ qout)
{
    __shared__ float As[64 * 68];
    __shared__ float Ws2[64 * 132];
    const int t = threadIdx.x;
    const int r0 = blockIdx.x * 64;
    const int n0 = blockIdx.y * 128;
    const int tx = t & 31, ty = t >> 5;

    float4 acc[8];
#pragma unroll
    for (int i = 0; i < 8; ++i) acc[i] = make_float4(0.f, 0.f, 0.f, 0.f);

    for (int kc = 0; kc < K; kc += 64) {
        __syncthreads();
        for (int idx = t; idx < 1024; idx += 256) {
            const int row = idx >> 4, kk = idx & 15;
            *(float4*)&As[row * 68 + kk * 4] =
                *(const float4*)(A + (size_t)(r0 + row) * K + kc + kk * 4);
        }
        for (int idx = t; idx < 2048; idx += 256) {
            const int kk = idx >> 5, nq = idx & 31;
            *(float4*)&Ws2[kk * 132 + nq * 4] =
                *(const float4*)(W + (size_t)(kc + kk) * wstride + n0 + nq * 4);
        }
        __syncthreads();
        for (int k = 0; k < 64; ++k) {
            const float4 wv = *(const float4*)&Ws2[k * 132 + tx * 4];
#pragma unroll
            for (int i = 0; i < 8; ++i) {
                const float av = As[(ty * 8 + i) * 68 + k];
                acc[i].x += av * wv.x; acc[i].y += av * wv.y;
                acc[i].z += av * wv.z; acc[i].w += av * wv.w;
            }
        }
    }

    const float4 bv = *(const float4*)(bias + n0 + tx * 4);
#pragma unroll
    for (int i = 0; i < 8; ++i) {
        acc[i].x += bv.x; acc[i].y += bv.y; acc[i].z += bv.z; acc[i].w += bv.w;
        if (resid) {
            const float4 rr = *(const float4*)(resid + (size_t)(r0 + ty * 8 + i) * 128 + tx * 4);
            acc[i].x += rr.x; acc[i].y += rr.y; acc[i].z += rr.z; acc[i].w += rr.w;
        }
    }

    if (ln1s) {
        const float4 s1 = *(const float4*)(ln1s + tx * 4);
        const float4 b1 = *(const float4*)(ln1b + tx * 4);
#pragma unroll
        for (int i = 0; i < 8; ++i) {
            float s_ = acc[i].x + acc[i].y + acc[i].z + acc[i].w;
            float q_ = acc[i].x * acc[i].x + acc[i].y * acc[i].y +
                       acc[i].z * acc[i].z + acc[i].w * acc[i].w;
#pragma unroll
            for (int mk = 1; mk < 32; mk <<= 1) {
                s_ += __shfl_xor(s_, mk, 64);
                q_ += __shfl_xor(q_, mk, 64);
            }
            const float mean = s_ * 0.0078125f;
            const float rstd = rsqrtf(q_ * 0.0078125f - mean * mean + 1e-5f);
            acc[i].x = (acc[i].x - mean) * rstd * s1.x + b1.x;
            acc[i].y = (acc[i].y - mean) * rstd * s1.y + b1.y;
            acc[i].z = (acc[i].z - mean) * rstd * s1.z + b1.z;
            acc[i].w = (acc[i].w - mean) * rstd * s1.w + b1.w;
        }
        if (ln2s) {
            const float4 s2 = *(const float4*)(ln2s + tx * 4);
            const float4 b2 = *(const float4*)(ln2b + tx * 4);
#pragma unroll
            for (int i = 0; i < 8; ++i) {
                float s_ = acc[i].x + acc[i].y + acc[i].z + acc[i].w;
                float q_ = acc[i].x * acc[i].x + acc[i].y * acc[i].y +
                           acc[i].z * acc[i].z + acc[i].w * acc[i].w;
#pragma unroll
                for (int mk = 1; mk < 32; mk <<= 1) {
                    s_ += __shfl_xor(s_, mk, 64);
                    q_ += __shfl_xor(q_, mk, 64);
                }
                const float mean = s_ * 0.0078125f;
                const float rstd = rsqrtf(q_ * 0.0078125f - mean * mean + 1e-5f);
                acc[i].x = (acc[i].x - mean) * rstd * s2.x + b2.x;
                acc[i].y = (acc[i].y - mean) * rstd * s2.y + b2.y;
                acc[i].z = (acc[i].z - mean) * rstd * s2.z + b2.z;
                acc[i].w = (acc[i].w - mean) * rstd * s2.w + b2.w;
            }
        }
    }

    if (w2) {  // head: relu then dot with w2 -> qout[b*15 + i_act]
        const float4 w4 = *(const float4*)(w2 + tx * 4);
        const float bh = b2h[0];
#pragma unroll
        for (int i = 0; i < 8; ++i) {
            const float hx = fmaxf(acc[i].x, 0.f), hy = fmaxf(acc[i].y, 0.f);
            const float hz = fmaxf(acc[i].z, 0.f), hw = fmaxf(acc[i].w, 0.f);
            float d = hx * w4.x + hy * w4.y + hz * w4.z + hw * w4.w;
#pragma unroll
            for (int mk = 1; mk < 32; mk <<= 1) d += __shfl_xor(d, mk, 64);
            if (tx == 0) {
                const int token = r0 + ty * 8 + i;
                qout[(token & 255) * 15 + (token >> 8)] = d + bh;
            }
        }
        return;
    }
#pragma unroll
    for (int i = 0; i < 8; ++i)
        *(float4*)(C + (size_t)(r0 + ty * 8 + i) * ldc + n0 + tx * 4) = acc[i];
}

// ---------------------------------------------------------------------------
// Fused attention (f32, decoder paths; verified r1).
// ---------------------------------------------------------------------------
__global__ __launch_bounds__(256) void k_attn(
    const float* __restrict__ qp, int qstride,
    const float* __restrict__ kvp, int kvstride, int koff, int voff,
    float* __restrict__ op, ushort* __restrict__ ob,
    int Lq, int Lk, float scale)
{
    __shared__ float Kl[196 * 36];
    __shared__ float Vl[196 * 32];
    __shared__ float pbuf[4][256];
    const int bh = blockIdx.x;
    const int b = bh >> 2;
    const int h = bh & 3;
    const int t = threadIdx.x;
    const int w = t >> 6;
    const int l = t & 63;

    for (int idx = t; idx < Lk * 8; idx += 256) {
        const int j = idx >> 3;
        const int kq = idx & 7;
        const size_t row = ((size_t)j * 256 + b) * kvstride + h * 32 + kq * 4;
        *(float4*)(&Kl[j * 36 + kq * 4]) = *(const float4*)(kvp + row + koff);
        *(float4*)(&Vl[j * 32 + kq * 4]) = *(const float4*)(kvp + row + voff);
    }
    if ((Lk & 1) && t < 8) *(float4*)(&Vl[Lk * 32 + t * 4]) = make_float4(0.f, 0.f, 0.f, 0.f);
    __syncthreads();

    const int Lh = (Lk + 1) >> 1;
    const int half = l >> 5;
    const int kk = l & 31;
    const int jb = half * Lh;

    for (int jq = w; jq < Lq; jq += 4) {
        const float* qrow = qp + ((size_t)jq * 256 + b) * qstride + h * 32;
        float4 q4[8];
#pragma unroll
        for (int kq = 0; kq < 8; ++kq) q4[kq] = *(const float4*)(qrow + kq * 4);

        float s[4];
#pragma unroll
        for (int r = 0; r < 4; ++r) {
            const int j = l + (r << 6);
            float acc = -3.0e38f;
            if (j < Lk) {
                acc = 0.f;
#pragma unroll
                for (int kq = 0; kq < 8; ++kq) {
                    const float4 kv = *(const float4*)(&Kl[j * 36 + kq * 4]);
                    acc += q4[kq].x * kv.x + q4[kq].y * kv.y +
                           q4[kq].z * kv.z + q4[kq].w * kv.w;
                }
                acc *= scale;
            }
            s[r] = acc;
        }
        float m = fmaxf(fmaxf(s[0], s[1]), fmaxf(s[2], s[3]));
        m = wred_max(m);
        float sum = 0.f;
#pragma unroll
        for (int r = 0; r < 4; ++r) {
            const int j = l + (r << 6);
            float p = __expf(s[r] - m);
            if (j >= Lk) p = 0.f;
            pbuf[w][j] = p;
            sum += p;
        }
        sum = wred_sum(sum);
        const float inv = 1.0f / sum;
        __threadfence_block();

        float o = 0.f;
        for (int jj = 0; jj < Lh; ++jj) {
            const float pv = pbuf[w][jb + jj];
            const float vv = Vl[(jb + jj) * 32 + kk];
            o += pv * vv;
        }
        o += __shfl_xor(o, 32, 64);
        o *= inv;
        if (l < 32) {
            const size_t oi = ((size_t)jq * 256 + b) * 128 + h * 32 + l;
            if (op) op[oi] = o;
            if (ob) ob[oi] = f2bf(o);
        }
        __threadfence_block();
    }
}

// ---------------------------------------------------------------------------
// f32 tiled GEMM 64x64 (decoder ff1 only now).
// ---------------------------------------------------------------------------
__global__ __launch_bounds__(256) void k_gemm64(
    const float* __restrict__ A, int K,
    const float* __restrict__ W, int wstride,
    const float* __restrict__ bias,
    float* __restrict__ C, int cstride, int relu)
{
    __shared__ float As[64 * 132];
    __shared__ float Ws2[128 * 68];
    const int t = threadIdx.x;
    const int r0 = blockIdx.x * 64;
    const int n0 = blockIdx.y * 64;
    const int as = K + 4;
    const int lg = (K == 128) ? 5 : 4;
    const int kmask = (K >> 2) - 1;

    for (int idx = t; idx < (K << 4); idx += 256) {
        const int row = idx >> lg;
        const int kk = idx & kmask;
        *(float4*)(&As[row * as + kk * 4]) =
            *(const float4*)(A + (size_t)(r0 + row) * K + kk * 4);
    }
    for (int idx = t; idx < (K << 4); idx += 256) {
        const int kk = idx >> 4;
        const int nq = idx & 15;
        *(float4*)(&Ws2[kk * 68 + nq * 4]) =
            *(const float4*)(W + (size_t)kk * wstride + n0 + nq * 4);
    }
    __syncthreads();

    const int tx = t & 15, ty = t >> 4;
    float4 acc[4];
#pragma unroll
    for (int i = 0; i < 4; ++i) acc[i] = make_float4(0.f, 0.f, 0.f, 0.f);
    const float* arow = &As[(ty * 4) * as];
    for (int k = 0; k < K; ++k) {
        const float4 wv = *(const float4*)(&Ws2[k * 68 + tx * 4]);
#pragma unroll
        for (int i = 0; i < 4; ++i) {
            const float av = arow[i * as + k];
            acc[i].x += av * wv.x; acc[i].y += av * wv.y;
            acc[i].z += av * wv.z; acc[i].w += av * wv.w;
        }
    }
    const float4 bv = *(const float4*)(bias + n0 + tx * 4);
#pragma unroll
    for (int i = 0; i < 4; ++i) {
        float4 o;
        o.x = acc[i].x + bv.x; o.y = acc[i].y + bv.y;
        o.z = acc[i].z + bv.z; o.w = acc[i].w + bv.w;
        if (relu) {
            o.x = fmaxf(o.x, 0.f); o.y = fmaxf(o.y, 0.f);
            o.z = fmaxf(o.z, 0.f); o.w = fmaxf(o.w, 0.f);
        }
        *(float4*)(C + (size_t)(r0 + ty * 4 + i) * cstride + n0 + tx * 4) = o;
    }
}

// ---------------------------------------------------------------------------
// Fused sketch MLP (200->256->256->100) + action-token embed -> tg f32.
// One block per batch element b.
// ---------------------------------------------------------------------------
__global__ __launch_bounds__(256) void k_sketch(
    const float* __restrict__ sk,
    const float* __restrict__ W1, const float* __restrict__ b1,
    const float* __restrict__ W2, const float* __restrict__ b2,
    const float* __restrict__ W3, const float* __restrict__ b3,
    const float* __restrict__ ang, const float* __restrict__ px,
    const float* __restrict__ py,
    const float* __restrict__ actW, const float* __restrict__ actb,
    float* __restrict__ tg)
{
    __shared__ float xr[256], h1[256], h2[256], s3[128];
    const int b = blockIdx.x, t = threadIdx.x;
    xr[t] = (t < 200) ? sk[(size_t)b * 200 + t] : 0.f;
    __syncthreads();
    {
        float a = b1[t];
        for (int k = 0; k < 200; ++k) a += xr[k] * W1[k * 256 + t];
        h1[t] = fmaxf(a, 0.f);
    }
    __syncthreads();
    {
        float a = b2[t];
        for (int k = 0; k < 256; ++k) a += h1[k] * W2[k * 256 + t];
        h2[t] = fmaxf(a, 0.f);
    }
    __syncthreads();
    if (t < 100) {
        float a = b3[t];
        for (int k = 0; k < 256; ++k) a += h2[k] * W3[k * 100 + t];
        s3[t] = a;
    }
    __syncthreads();
    if (t < 128) {
        float acc = actb[t] + ang[b] * actW[15 * 128 + t] +
                    px[b] * actW[16 * 128 + t] + py[b] * actW[17 * 128 + t];
        for (int k = 0; k < 100; ++k) acc += s3[k] * actW[(18 + k) * 128 + t];
#pragma unroll
        for (int i = 0; i < 15; ++i)
            tg[((size_t)i * 256 + b) * 128 + t] = acc + actW[i * 128 + t];
    }
}

// ---------------------------------------------------------------------------
extern "C" void kernel_launch(void* const* d_in, const int* in_sizes, int n_in,
                              void* d_out, int out_size, void* d_ws, size_t ws_size,
                              hipStream_t stream)
{
    (void)in_sizes; (void)n_in; (void)out_size; (void)ws_size;
    const float* image      = (const float*)d_in[0];
    const float* angle      = (const float*)d_in[1];
    const float* pos_x      = (const float*)d_in[2];
    const float* pos_y      = (const float*)d_in[3];
    const float* sk         = (const float*)d_in[4];
    const float* patch_W    = (const float*)d_in[5];
    const float* patch_b    = (const float*)d_in[6];
    const float* pos_emb    = (const float*)d_in[7];
    const float* enc_qkv_W  = (const float*)d_in[8];
    const float* enc_qkv_b  = (const float*)d_in[9];
    const float* enc_out_W  = (const float*)d_in[10];
    const float* enc_out_b  = (const float*)d_in[11];
    const float* enc_ln1_s  = (const float*)d_in[12];
    const float* enc_ln1_b  = (const float*)d_in[13];
    const float* enc_ff1_W  = (const float*)d_in[14];
    const float* enc_ff1_b  = (const float*)d_in[15];
    const float* enc_ff2_W  = (const float*)d_in[16];
    const float* enc_ff2_b  = (const float*)d_in[17];
    const float* enc_ln2_s  = (const float*)d_in[18];
    const float* enc_ln2_b  = (const float*)d_in[19];
    const float* dec_sa_qkv_W = (const float*)d_in[20];
    const float* dec_sa_qkv_b = (const float*)d_in[21];
    const float* dec_sa_out_W = (const float*)d_in[22];
    const float* dec_sa_out_b = (const float*)d_in[23];
    const float* dec_ca_qkv_W = (const float*)d_in[24];
    const float* dec_ca_qkv_b = (const float*)d_in[25];
    const float* dec_ca_out_W = (const float*)d_in[26];
    const float* dec_ca_out_b = (const float*)d_in[27];
    const float* dec_ln1_s  = (const float*)d_in[28];
    const float* dec_ln1_b  = (const float*)d_in[29];
    const float* dec_ln2_s  = (const float*)d_in[30];
    const float* dec_ln2_b  = (const float*)d_in[31];
    const float* dec_ln3_s  = (const float*)d_in[32];
    const float* dec_ln3_b  = (const float*)d_in[33];
    const float* dec_ff1_W  = (const float*)d_in[34];
    const float* dec_ff1_b  = (const float*)d_in[35];
    const float* dec_ff2_W  = (const float*)d_in[36];
    const float* dec_ff2_b  = (const float*)d_in[37];
    const float* dec_norm_s = (const float*)d_in[38];
    const float* dec_norm_b = (const float*)d_in[39];
    const float* sk1_W = (const float*)d_in[40];
    const float* sk1_b = (const float*)d_in[41];
    const float* sk2_W = (const float*)d_in[42];
    const float* sk2_b = (const float*)d_in[43];
    const float* sk3_W = (const float*)d_in[44];
    const float* sk3_b = (const float*)d_in[45];
    const float* act_W = (const float*)d_in[46];
    const float* act_b = (const float*)d_in[47];
    const float* l1_W  = (const float*)d_in[48];
    const float* l1_b  = (const float*)d_in[49];
    const float* l2_W  = (const float*)d_in[50];
    const float* l2_b  = (const float*)d_in[51];

    // Workspace (float offsets)
    float* ws = (float*)d_ws;
    float* S0   = ws;               // src f32 residual stream  [6,422,528]
    float* QKVr = ws + 6422528;     // big overlay region       [19,267,584]
    float* T0   = ws + 25690112;    // decoder DT0 f32          [6,422,528]
    float* T1   = ws + 32112640;    // M0b bf16 home            [6,422,528]
    float* F1   = ws + 38535168;    // F1b bf16 / dec DF1       [3,211,264]
    float* M0r  = ws + 41746432;    // srcb/T0b | lnb bf16      [6,422,528]
    float* S1s  = ws + 48168960;    // (unused small)
    float* TG   = S1s + 156672;     // tgt f32 15*256*128
    ushort* WTS = (ushort*)(ws + 48817152);

    // Overlays
    ushort* Apm  = (ushort*)QKVr;            // patch matrix
    ushort* QKVb = (ushort*)QKVr;            // enc QKV bf16 [50176][384]
    float*  KV   = QKVr;                     // cross K/V f32 [50176][256]
    float* DQKV = QKVr + 12845056;           // dec self QKV f32
    float* DQ   = QKVr + 14319616;           // dec cross Q f32
    float* DT0  = T0;
    float* DF1  = F1;
    ushort* srcb = (ushort*)M0r;
    ushort* T0b  = (ushort*)M0r;             // disjoint lifetime with srcb
    ushort* lnb  = (ushort*)(M0r + 3211264);
    ushort* F1b  = (ushort*)F1;
    ushort* M0b  = (ushort*)T1;              // LN2 out bf16 (NOT aliasing F1b)
    ushort* wt_patch = WTS;
    ushort* wt_qkv   = WTS + 98304;
    ushort* wt_out   = WTS + 147456;
    ushort* wt_ff1   = WTS + 163840;
    ushort* wt_ff2   = WTS + 172032;
    ushort* wt_ckv   = WTS + 180224;

    const float rs = 0.17677669529663687f;  // 1/sqrt(32)

    // ---- prep ----
    k_wconv<<<dim3(832), 256, 0, stream>>>(patch_W, enc_qkv_W, enc_out_W,
                                           enc_ff1_W, enc_ff2_W, dec_ca_qkv_W, WTS);
    k_patchify<<<dim3(14, 256), 256, 0, stream>>>(image, Apm);
    k_sketch<<<dim3(256), 256, 0, stream>>>(sk, sk1_W, sk1_b, sk2_W, sk2_b,
                                            sk3_W, sk3_b, angle, pos_x, pos_y,
                                            act_W, act_b, TG);

    // ---- encoder ----
    k_gemm_bf16<64, 128><<<dim3(784, 1), 256, 0, stream>>>(
        Apm, 768, wt_patch, 768, patch_b, S0, srcb, 128, pos_emb, 0);
    k_gemm_bf16<64, 128><<<dim3(784, 3), 256, 0, stream>>>(
        srcb, 128, wt_qkv, 128, enc_qkv_b, nullptr, QKVb, 384, nullptr, 0);
    k_attn_mfma<<<dim3(1024), 256, 0, stream>>>(QKVb, T0b, rs);
    k_gemm_ln<<<dim3(784), 256, 0, stream>>>(                 // out-proj + LN1
        T0b, 128, wt_out, 128, enc_out_b, S0, enc_ln1_s, enc_ln1_b, S0, lnb);
    k_gemm_bf16<64, 64><<<dim3(784, 1), 256, 0, stream>>>(    // FF1 + relu
        lnb, 128, wt_ff1, 128, enc_ff1_b, nullptr, F1b, 64, nullptr, 1);
    k_gemm_ln<<<dim3(784), 256, 0, stream>>>(                 // FF2 + LN2
        F1b, 64, wt_ff2, 64, enc_ff2_b, S0, enc_ln2_s, enc_ln2_b, nullptr, M0b);
    k_gemm_bf16<64, 128><<<dim3(784, 2), 256, 0, stream>>>(   // cross K/V
        M0b, 128, wt_ckv, 128, dec_ca_qkv_b + 128, KV, nullptr, 256, nullptr, 0);

    // ---- decoder ----
    k_gdec<<<dim3(60, 3), 256, 0, stream>>>(                  // self QKV
        TG, 128, dec_sa_qkv_W, 384, dec_sa_qkv_b, nullptr,
        nullptr, nullptr, nullptr, nullptr, nullptr, nullptr, DQKV, 384, nullptr);
    k_attn<<<dim3(1024), 256, 0, stream>>>(DQKV, 384, DQKV, 384, 128, 256,
                                           DT0, nullptr, 15, 15, rs);
    k_gdec<<<dim3(60, 1), 256, 0, stream>>>(                  // self out + LN1
        DT0, 128, dec_sa_out_W, 128, dec_sa_out_b, TG,
        dec_ln1_s, dec_ln1_b, nullptr, nullptr, nullptr, nullptr, TG, 128, nullptr);
    k_gdec<<<dim3(60, 1), 256, 0, stream>>>(                  // cross Q
        TG, 128, dec_ca_qkv_W, 384, dec_ca_qkv_b, nullptr,
        nullptr, nullptr, nullptr, nullptr, nullptr, nullptr, DQ, 128, nullptr);
    k_attn<<<dim3(1024), 256, 0, stream>>>(DQ, 128, KV, 256, 0, 128,
                                           DT0, nullptr, 15, 196, rs);
    k_gdec<<<dim3(60, 1), 256, 0, stream>>>(                  // cross out + LN2
        DT0, 128, dec_ca_out_W, 128, dec_ca_out_b, TG,
        dec_ln2_s, dec_ln2_b, nullptr, nullptr, nullptr, nullptr, TG, 128, nullptr);
    k_gemm64<<<dim3(60, 1), 256, 0, stream>>>(                // dec FF1 + relu
        TG, 128, dec_ff1_W, 64, dec_ff1_b, DF1, 64, 1);
    k_gdec<<<dim3(60, 1), 256, 0, stream>>>(                  // FF2 + LN3 + norm
        DF1, 64, dec_ff2_W, 128, dec_ff2_b, TG,
        dec_ln3_s, dec_ln3_b, dec_norm_s, dec_norm_b, nullptr, nullptr,
        DT0, 128, nullptr);
    k_gdec<<<dim3(60, 1), 256, 0, stream>>>(                  // l1 + head dot
        DT0, 128, l1_W, 128, l1_b, nullptr,
        nullptr, nullptr, nullptr, nullptr, l2_W, l2_b,
        nullptr, 128, (float*)d_out);
}

// Round 6
// 390.771 us; speedup vs baseline: 3.3637x; 1.0644x over previous
//
#include <hip/hip_runtime.h>
#include <math.h>

#define BSZ 256
#define DIM 128
#define NHD 4
#define NPATCH 196
#define NACT 15

typedef float f32x4 __attribute__((ext_vector_type(4)));
typedef __bf16 bf16x8 __attribute__((ext_vector_type(8)));
typedef short short8 __attribute__((ext_vector_type(8)));

__device__ __forceinline__ float wred_sum(float v) {
#pragma unroll
    for (int m = 1; m < 64; m <<= 1) v += __shfl_xor(v, m, 64);
    return v;
}
__device__ __forceinline__ float wred_max(float v) {
#pragma unroll
    for (int m = 1; m < 64; m <<= 1) v = fmaxf(v, __shfl_xor(v, m, 64));
    return v;
}
__device__ __forceinline__ ushort f2bf(float f) {  // RNE bf16
    unsigned u = __float_as_uint(f);
    return (ushort)((u + 0x7fffu + ((u >> 16) & 1u)) >> 16);
}

// ---------------------------------------------------------------------------
// Weight convert+transpose to bf16 [N][K] (patch K-permuted), packed.
// ---------------------------------------------------------------------------
__global__ __launch_bounds__(256) void k_wconv(
    const float* __restrict__ pW, const float* __restrict__ qkvW,
    const float* __restrict__ outW, const float* __restrict__ ff1W,
    const float* __restrict__ ff2W, const float* __restrict__ ckvW,
    ushort* __restrict__ o)
{
    int i = blockIdx.x * 256 + threadIdx.x;
    if (i < 98304) {
        int n = i / 768, kp = i % 768;
        int c = kp >> 8, q = kp & 255;
        o[i] = f2bf(pW[(q * 3 + c) * 128 + n]); return;
    }
    i -= 98304;
    if (i < 49152) { int n = i >> 7, k = i & 127; o[98304 + i] = f2bf(qkvW[k * 384 + n]); return; }
    i -= 49152;
    if (i < 16384) { int n = i >> 7, k = i & 127; o[147456 + i] = f2bf(outW[k * 128 + n]); return; }
    i -= 16384;
    if (i < 8192)  { int n = i >> 7, k = i & 127; o[163840 + i] = f2bf(ff1W[k * 64 + n]); return; }
    i -= 8192;
    if (i < 8192)  { int n = i >> 6, k = i & 63;  o[172032 + i] = f2bf(ff2W[k * 128 + n]); return; }
    i -= 8192;
    if (i < 32768) { int n = i >> 7, k = i & 127; o[180224 + i] = f2bf(ckvW[k * 384 + 128 + n]); return; }
}

// ---------------------------------------------------------------------------
// Fused patchify + patch-embed MFMA GEMM. BM=64 (one patch p, 64 b's), BN=128,
// K=768 permuted k' = c*256 + p1*16 + p2. A-tile staged straight from image
// (float4 -> bf16 -> swizzled LDS); no Apm intermediate.
// grid(784): p = blk>>2, bq = blk&3.
// ---------------------------------------------------------------------------
__global__ __launch_bounds__(256) void k_pgemm(
    const float* __restrict__ img, const ushort* __restrict__ Wt,
    const float* __restrict__ bias, const float* __restrict__ pe,
    float* __restrict__ C, ushort* __restrict__ Cb)
{
    __shared__ ushort As[64 * 64];
    __shared__ ushort Ws[128 * 64];
    const int t = threadIdx.x;
    const int w = t >> 6, l = t & 63;
    const int pb = blockIdx.x;
    const int p = pb >> 2, bq = pb & 3;
    const int hp = p / 14, wp = p % 14;
    const int r0 = p * 256 + bq * 64;
    const int wm = w >> 1, wn = w & 1;
    const int lrow = l & 15, lk = l >> 4;
    const int arow = t >> 2;                 // 0..63
    const int b_img = bq * 64 + arow;
    const float* gimg = img + (size_t)b_img * 150528 + hp * (16 * 224) + wp * 16;

    f32x4 acc[2][4];
#pragma unroll
    for (int m = 0; m < 2; ++m)
#pragma unroll
        for (int n = 0; n < 4; ++n) acc[m][n] = (f32x4)0.f;

    for (int kc = 0; kc < 768; kc += 64) {
        const int c = kc >> 8, p1q = (kc >> 6) & 3;
        const float* gc = gimg + c * 50176 + p1q * 4 * 224;
        __syncthreads();
#pragma unroll
        for (int i = 0; i < 4; ++i) {
            const int kq = (t & 3) + 4 * i;      // 0..15
            const int p1 = kq >> 2, p2q = kq & 3;
            const float4 v = *(const float4*)(gc + p1 * 224 + p2q * 4);
            ushort4 o4;
            o4.x = f2bf(v.x); o4.y = f2bf(v.y); o4.z = f2bf(v.z); o4.w = f2bf(v.w);
            const int bo = (kq * 8) ^ ((arow & 7) << 4);
            *(ushort4*)((char*)As + arow * 128 + bo) = o4;
        }
        for (int i2 = t; i2 < 128 * 8; i2 += 256) {
            const int row = i2 >> 3, ch = i2 & 7;
            const int sw = (ch * 16) ^ ((row & 7) << 4);
            *(short8*)((char*)Ws + row * 128 + sw) =
                *(const short8*)(Wt + (size_t)row * 768 + kc + ch * 8);
        }
        __syncthreads();
#pragma unroll
        for (int ks = 0; ks < 2; ++ks) {
            bf16x8 af[2], bfr[4];
#pragma unroll
            for (int m = 0; m < 2; ++m) {
                const int row = wm * 32 + m * 16 + lrow;
                const int col = (ks * 64 + lk * 16) ^ ((row & 7) << 4);
                af[m] = *(const bf16x8*)((const char*)As + row * 128 + col);
            }
#pragma unroll
            for (int n = 0; n < 4; ++n) {
                const int row = wn * 64 + n * 16 + lrow;
                const int col = (ks * 64 + lk * 16) ^ ((row & 7) << 4);
                bfr[n] = *(const bf16x8*)((const char*)Ws + row * 128 + col);
            }
#pragma unroll
            for (int m = 0; m < 2; ++m)
#pragma unroll
                for (int n = 0; n < 4; ++n)
                    acc[m][n] = __builtin_amdgcn_mfma_f32_16x16x32_bf16(
                        af[m], bfr[n], acc[m][n], 0, 0, 0);
        }
    }

    const int crow0 = (l >> 4) * 4;
    const int ccol = l & 15;
#pragma unroll
    for (int m = 0; m < 2; ++m) {
        const int growb = r0 + wm * 32 + m * 16 + crow0;
#pragma unroll
        for (int n = 0; n < 4; ++n) {
            const int gcol = wn * 64 + n * 16 + ccol;
            const float bv = bias[gcol] + pe[p * 128 + gcol];
#pragma unroll
            for (int j = 0; j < 4; ++j) {
                const int grow = growb + j;
                const float v = acc[m][n][j] + bv;
                C[(size_t)grow * 128 + gcol] = v;
                Cb[(size_t)grow * 128 + gcol] = f2bf(v);
            }
        }
    }
}

// ---------------------------------------------------------------------------
// bf16 MFMA GEMM, BM x BN tile (BM in {64,128}, BN in {64,128}), BK=64.
// ---------------------------------------------------------------------------
template <int BM, int BN>
__global__ __launch_bounds__(256) void k_gemm_bf16(
    const ushort* __restrict__ A, int lda,
    const ushort* __restrict__ Wt, int K,
    const float* __restrict__ bias,
    float* __restrict__ C, ushort* __restrict__ Cb, int ldc,
    const float* __restrict__ pe, int relu)
{
    constexpr int NWN = BN / 64;
    constexpr int NWM = 4 / NWN;
    constexpr int WTM = BM / NWM;
    constexpr int MF = WTM / 16;
    __shared__ ushort As[BM * 64];
    __shared__ ushort Ws[BN * 64];
    const int t = threadIdx.x;
    const int w = t >> 6, l = t & 63;
    const int r0 = blockIdx.x * BM;
    const int n0 = blockIdx.y * BN;
    const int wm = w / NWN, wn = w % NWN;
    const int lrow = l & 15, lk = l >> 4;

    f32x4 acc[MF][4];
#pragma unroll
    for (int m = 0; m < MF; ++m)
#pragma unroll
        for (int n = 0; n < 4; ++n) acc[m][n] = (f32x4)0.f;

    for (int kc = 0; kc < K; kc += 64) {
        __syncthreads();
#pragma unroll
        for (int i = t; i < BM * 8; i += 256) {
            const int row = i >> 3, ch = i & 7;
            const int sw = (ch * 16) ^ ((row & 7) << 4);
            *(short8*)((char*)As + row * 128 + sw) =
                *(const short8*)(A + (size_t)(r0 + row) * lda + kc + ch * 8);
        }
#pragma unroll
        for (int i = t; i < BN * 8; i += 256) {
            const int row = i >> 3, ch = i & 7;
            const int sw = (ch * 16) ^ ((row & 7) << 4);
            *(short8*)((char*)Ws + row * 128 + sw) =
                *(const short8*)(Wt + (size_t)(n0 + row) * K + kc + ch * 8);
        }
        __syncthreads();
#pragma unroll
        for (int ks = 0; ks < 2; ++ks) {
            bf16x8 af[MF], bfr[4];
#pragma unroll
            for (int m = 0; m < MF; ++m) {
                const int row = wm * WTM + m * 16 + lrow;
                const int col = (ks * 64 + lk * 16) ^ ((row & 7) << 4);
                af[m] = *(const bf16x8*)((const char*)As + row * 128 + col);
            }
#pragma unroll
            for (int n = 0; n < 4; ++n) {
                const int row = wn * 64 + n * 16 + lrow;
                const int col = (ks * 64 + lk * 16) ^ ((row & 7) << 4);
                bfr[n] = *(const bf16x8*)((const char*)Ws + row * 128 + col);
            }
#pragma unroll
            for (int m = 0; m < MF; ++m)
#pragma unroll
                for (int n = 0; n < 4; ++n)
                    acc[m][n] = __builtin_amdgcn_mfma_f32_16x16x32_bf16(
                        af[m], bfr[n], acc[m][n], 0, 0, 0);
        }
    }

    const int crow0 = (l >> 4) * 4;
    const int ccol = l & 15;
#pragma unroll
    for (int m = 0; m < MF; ++m) {
        const int growb = r0 + wm * WTM + m * 16 + crow0;
#pragma unroll
        for (int n = 0; n < 4; ++n) {
            const int gcol = n0 + wn * 64 + n * 16 + ccol;
            const float bv = bias[gcol];
#pragma unroll
            for (int j = 0; j < 4; ++j) {
                const int grow = growb + j;
                float v = acc[m][n][j] + bv;
                if (pe) v += pe[(grow >> 8) * 128 + gcol];
                if (relu) v = fmaxf(v, 0.f);
                if (C)  C[(size_t)grow * ldc + gcol] = v;
                if (Cb) Cb[(size_t)grow * ldc + gcol] = f2bf(v);
            }
        }
    }
}

// ---------------------------------------------------------------------------
// bf16 MFMA GEMM 64x128 + residual + LayerNorm fused epilogue (verified r5).
// ---------------------------------------------------------------------------
__global__ __launch_bounds__(256) void k_gemm_ln(
    const ushort* __restrict__ A, int lda,
    const ushort* __restrict__ Wt, int K,
    const float* __restrict__ bias,
    const float* __restrict__ resid,
    const float* __restrict__ lns, const float* __restrict__ lnbi,
    float* __restrict__ Co, ushort* __restrict__ Cb)
{
    __shared__ ushort As[64 * 64];
    __shared__ ushort Ws[128 * 64];
    __shared__ float psum[64][2][2];
    const int t = threadIdx.x;
    const int w = t >> 6, l = t & 63;
    const int r0 = blockIdx.x * 64;
    const int wm = w >> 1, wn = w & 1;
    const int lrow = l & 15, lk = l >> 4;

    f32x4 acc[2][4];
#pragma unroll
    for (int m = 0; m < 2; ++m)
#pragma unroll
        for (int n = 0; n < 4; ++n) acc[m][n] = (f32x4)0.f;

    for (int kc = 0; kc < K; kc += 64) {
        __syncthreads();
#pragma unroll
        for (int i = t; i < 64 * 8; i += 256) {
            const int row = i >> 3, ch = i & 7;
            const int sw = (ch * 16) ^ ((row & 7) << 4);
            *(short8*)((char*)As + row * 128 + sw) =
                *(const short8*)(A + (size_t)(r0 + row) * lda + kc + ch * 8);
        }
#pragma unroll
        for (int i = t; i < 128 * 8; i += 256) {
            const int row = i >> 3, ch = i & 7;
            const int sw = (ch * 16) ^ ((row & 7) << 4);
            *(short8*)((char*)Ws + row * 128 + sw) =
                *(const short8*)(Wt + (size_t)row * K + kc + ch * 8);
        }
        __syncthreads();
#pragma unroll
        for (int ks = 0; ks < 2; ++ks) {
            bf16x8 af[2], bfr[4];
#pragma unroll
            for (int m = 0; m < 2; ++m) {
                const int row = wm * 32 + m * 16 + lrow;
                const int col = (ks * 64 + lk * 16) ^ ((row & 7) << 4);
                af[m] = *(const bf16x8*)((const char*)As + row * 128 + col);
            }
#pragma unroll
            for (int n = 0; n < 4; ++n) {
                const int row = wn * 64 + n * 16 + lrow;
                const int col = (ks * 64 + lk * 16) ^ ((row & 7) << 4);
                bfr[n] = *(const bf16x8*)((const char*)Ws + row * 128 + col);
            }
#pragma unroll
            for (int m = 0; m < 2; ++m)
#pragma unroll
                for (int n = 0; n < 4; ++n)
                    acc[m][n] = __builtin_amdgcn_mfma_f32_16x16x32_bf16(
                        af[m], bfr[n], acc[m][n], 0, 0, 0);
        }
    }

    const int crow0 = (l >> 4) * 4;
    const int ccol = l & 15;
#pragma unroll
    for (int m = 0; m < 2; ++m) {
        const int growb = r0 + wm * 32 + m * 16 + crow0;
#pragma unroll
        for (int n = 0; n < 4; ++n) {
            const int gcol = wn * 64 + n * 16 + ccol;
            const float bv = bias[gcol];
#pragma unroll
            for (int j = 0; j < 4; ++j) {
                float v = acc[m][n][j] + bv;
                if (resid) v += resid[(size_t)(growb + j) * 128 + gcol];
                acc[m][n][j] = v;
            }
        }
    }
#pragma unroll
    for (int m = 0; m < 2; ++m)
#pragma unroll
        for (int j = 0; j < 4; ++j) {
            float s_ = 0.f, q_ = 0.f;
#pragma unroll
            for (int n = 0; n < 4; ++n) {
                const float x = acc[m][n][j];
                s_ += x; q_ += x * x;
            }
#pragma unroll
            for (int mk = 1; mk < 16; mk <<= 1) {
                s_ += __shfl_xor(s_, mk, 64);
                q_ += __shfl_xor(q_, mk, 64);
            }
            if (ccol == 0) {
                const int r = wm * 32 + m * 16 + crow0 + j;
                psum[r][wn][0] = s_;
                psum[r][wn][1] = q_;
            }
        }
    __syncthreads();
    float mean_[2][4], rstd_[2][4];
#pragma unroll
    for (int m = 0; m < 2; ++m)
#pragma unroll
        for (int j = 0; j < 4; ++j) {
            const int r = wm * 32 + m * 16 + crow0 + j;
            const float sum = psum[r][0][0] + psum[r][1][0];
            const float sq  = psum[r][0][1] + psum[r][1][1];
            const float mean = sum * 0.0078125f;
            const float var = sq * 0.0078125f - mean * mean;
            mean_[m][j] = mean;
            rstd_[m][j] = rsqrtf(var + 1e-5f);
        }
#pragma unroll
    for (int m = 0; m < 2; ++m) {
        const int growb = r0 + wm * 32 + m * 16 + crow0;
#pragma unroll
        for (int n = 0; n < 4; ++n) {
            const int gcol = wn * 64 + n * 16 + ccol;
            const float sv = lns[gcol], bv2 = lnbi[gcol];
#pragma unroll
            for (int j = 0; j < 4; ++j) {
                const float y = (acc[m][n][j] - mean_[m][j]) * rstd_[m][j] * sv + bv2;
                const size_t oi = (size_t)(growb + j) * 128 + gcol;
                if (Co) Co[oi] = y;
                if (Cb) Cb[oi] = f2bf(y);
            }
        }
    }
}

// ---------------------------------------------------------------------------
// MFMA flash attention, encoder self-attn (verified r3).
// ---------------------------------------------------------------------------
__global__ __launch_bounds__(256) void k_attn_mfma(
    const ushort* __restrict__ qkv, ushort* __restrict__ ob, float scale)
{
    __shared__ ushort Ks[208 * 40];
    __shared__ ushort Vt[32 * 232];
    __shared__ ushort Ps[4][16 * 232];
    const int bh = blockIdx.x;
    const int b = bh >> 2, h = bh & 3;
    const int t = threadIdx.x, w = t >> 6, l = t & 63;
    const int lr = l & 15, lg = l >> 4;

    for (int idx = t; idx < 784; idx += 256) {
        const int j = idx >> 2, ch = idx & 3;
        const size_t base = ((size_t)j * 256 + b) * 384 + h * 32 + ch * 8;
        *(short8*)(Ks + j * 40 + ch * 8) = *(const short8*)(qkv + base + 128);
        short8 v = *(const short8*)(qkv + base + 256);
#pragma unroll
        for (int q = 0; q < 8; ++q)
            Vt[(ch * 8 + q) * 232 + j] = (ushort)v[q];
    }
    for (int idx = t; idx < 32 * 36; idx += 256)
        Vt[(idx / 36) * 232 + 196 + (idx % 36)] = 0;
    for (int i = l; i < 256; i += 64)
        Ps[w][(i >> 4) * 232 + 208 + (i & 15)] = 0;
    __syncthreads();

    for (int qt = w; qt < 13; qt += 4) {
        int qr = qt * 16 + lr; if (qr > 195) qr = 195;
        const bf16x8 qf = *(const bf16x8*)(qkv + ((size_t)qr * 256 + b) * 384 + h * 32 + lg * 8);

        f32x4 s[13];
#pragma unroll
        for (int jn = 0; jn < 13; ++jn) {
            const bf16x8 kf = *(const bf16x8*)(Ks + (jn * 16 + lr) * 40 + lg * 8);
            s[jn] = __builtin_amdgcn_mfma_f32_16x16x32_bf16(qf, kf, (f32x4)0.f, 0, 0, 0);
        }
        if (lr >= 4) {
            s[12][0] = -3.0e38f; s[12][1] = -3.0e38f;
            s[12][2] = -3.0e38f; s[12][3] = -3.0e38f;
        }

        float inv[4];
        ushort* pw = Ps[w];
#pragma unroll
        for (int j = 0; j < 4; ++j) {
            float m = s[0][j];
#pragma unroll
            for (int jn = 1; jn < 13; ++jn) m = fmaxf(m, s[jn][j]);
            m = fmaxf(m, __shfl_xor(m, 1, 64));
            m = fmaxf(m, __shfl_xor(m, 2, 64));
            m = fmaxf(m, __shfl_xor(m, 4, 64));
            m = fmaxf(m, __shfl_xor(m, 8, 64));
            float sum = 0.f;
#pragma unroll
            for (int jn = 0; jn < 13; ++jn) {
                const float p = __expf((s[jn][j] - m) * scale);
                s[jn][j] = p;
                sum += p;
            }
            sum += __shfl_xor(sum, 1, 64);
            sum += __shfl_xor(sum, 2, 64);
            sum += __shfl_xor(sum, 4, 64);
            sum += __shfl_xor(sum, 8, 64);
            inv[j] = 1.0f / sum;
        }
#pragma unroll
        for (int jn = 0; jn < 13; ++jn)
#pragma unroll
            for (int j = 0; j < 4; ++j)
                pw[(lg * 4 + j) * 232 + jn * 16 + lr] = f2bf(s[jn][j]);

        f32x4 o0 = (f32x4)0.f, o1 = (f32x4)0.f;
#pragma unroll
        for (int kt = 0; kt < 7; ++kt) {
            const bf16x8 pf = *(const bf16x8*)(pw + lr * 232 + kt * 32 + lg * 8);
            const bf16x8 v0 = *(const bf16x8*)(Vt + lr * 232 + kt * 32 + lg * 8);
            const bf16x8 v1 = *(const bf16x8*)(Vt + (16 + lr) * 232 + kt * 32 + lg * 8);
            o0 = __builtin_amdgcn_mfma_f32_16x16x32_bf16(pf, v0, o0, 0, 0, 0);
            o1 = __builtin_amdgcn_mfma_f32_16x16x32_bf16(pf, v1, o1, 0, 0, 0);
        }
#pragma unroll
        for (int j = 0; j < 4; ++j) {
            const int r = qt * 16 + lg * 4 + j;
            if (r < 196) {
                const size_t o = ((size_t)r * 256 + b) * 128 + h * 32;
                ob[o + lr]      = f2bf(o0[j] * inv[j]);
                ob[o + 16 + lr] = f2bf(o1[j] * inv[j]);
            }
        }
    }
}

// ---------------------------------------------------------------------------
// Fused attention (f32, decoder cross path; verified r1).
// ---------------------------------------------------------------------------
__global__ __launch_bounds__(256) void k_attn(
    const float* __restrict__ qp, int qstride,
    const float* __restrict__ kvp, int kvstride, int koff, int voff,
    float* __restrict__ op, ushort* __restrict__ ob,
    int Lq, int Lk, float scale)
{
    __shared__ float Kl[196 * 36];
    __shared__ float Vl[196 * 32];
    __shared__ float pbuf[4][256];
    const int bh = blockIdx.x;
    const int b = bh >> 2;
    const int h = bh & 3;
    const int t = threadIdx.x;
    const int w = t >> 6;
    const int l = t & 63;

    for (int idx = t; idx < Lk * 8; idx += 256) {
        const int j = idx >> 3;
        const int kq = idx & 7;
        const size_t row = ((size_t)j * 256 + b) * kvstride + h * 32 + kq * 4;
        *(float4*)(&Kl[j * 36 + kq * 4]) = *(const float4*)(kvp + row + koff);
        *(float4*)(&Vl[j * 32 + kq * 4]) = *(const float4*)(kvp + row + voff);
    }
    if ((Lk & 1) && t < 8) *(float4*)(&Vl[Lk * 32 + t * 4]) = make_float4(0.f, 0.f, 0.f, 0.f);
    __syncthreads();

    const int Lh = (Lk + 1) >> 1;
    const int half = l >> 5;
    const int kk = l & 31;
    const int jb = half * Lh;

    for (int jq = w; jq < Lq; jq += 4) {
        const float* qrow = qp + ((size_t)jq * 256 + b) * qstride + h * 32;
        float4 q4[8];
#pragma unroll
        for (int kq = 0; kq < 8; ++kq) q4[kq] = *(const float4*)(qrow + kq * 4);

        float s[4];
#pragma unroll
        for (int r = 0; r < 4; ++r) {
            const int j = l + (r << 6);
            float acc = -3.0e38f;
            if (j < Lk) {
                acc = 0.f;
#pragma unroll
                for (int kq = 0; kq < 8; ++kq) {
                    const float4 kv = *(const float4*)(&Kl[j * 36 + kq * 4]);
                    acc += q4[kq].x * kv.x + q4[kq].y * kv.y +
                           q4[kq].z * kv.z + q4[kq].w * kv.w;
                }
                acc *= scale;
            }
            s[r] = acc;
        }
        float m = fmaxf(fmaxf(s[0], s[1]), fmaxf(s[2], s[3]));
        m = wred_max(m);
        float sum = 0.f;
#pragma unroll
        for (int r = 0; r < 4; ++r) {
            const int j = l + (r << 6);
            float p = __expf(s[r] - m);
            if (j >= Lk) p = 0.f;
            pbuf[w][j] = p;
            sum += p;
        }
        sum = wred_sum(sum);
        const float inv = 1.0f / sum;
        __threadfence_block();

        float o = 0.f;
        for (int jj = 0; jj < Lh; ++jj) {
            const float pv = pbuf[w][jb + jj];
            const float vv = Vl[(jb + jj) * 32 + kk];
            o += pv * vv;
        }
        o += __shfl_xor(o, 32, 64);
        o *= inv;
        if (l < 32) {
            const size_t oi = ((size_t)jq * 256 + b) * 128 + h * 32 + l;
            if (op) op[oi] = o;
            if (ob) ob[oi] = f2bf(o);
        }
        __threadfence_block();
    }
}

// ---------------------------------------------------------------------------
// Fused decoder part 1 (one block per batch b):
// sketch MLP -> tgt; self QKV; self-attn; out-proj + resid + LN1 -> TGo, tg;
// cross-Q -> DQ.
// ---------------------------------------------------------------------------
__global__ __launch_bounds__(256) void k_dec1(
    const float* __restrict__ sk,
    const float* __restrict__ W1, const float* __restrict__ b1,
    const float* __restrict__ W2, const float* __restrict__ b2,
    const float* __restrict__ W3, const float* __restrict__ b3,
    const float* __restrict__ ang, const float* __restrict__ px,
    const float* __restrict__ py,
    const float* __restrict__ actW, const float* __restrict__ actb,
    const float* __restrict__ saW, const float* __restrict__ sab,
    const float* __restrict__ saoW, const float* __restrict__ saob,
    const float* __restrict__ ln1s, const float* __restrict__ ln1b,
    const float* __restrict__ caW, const float* __restrict__ cab,
    float* __restrict__ TGo, float* __restrict__ DQ)
{
    __shared__ float tg[15][128];
    __shared__ float qkv[15][388];   // +4 pad: column reads 2-way only
    __shared__ float ao[15][128];
    __shared__ float xr[256], h1[256], h2[256];
    __shared__ float s3[100];
    __shared__ float pbv[4][16];
    const int b = blockIdx.x, t = threadIdx.x;
    const int w = t >> 6, l = t & 63;

    // sketch MLP
    xr[t] = (t < 200) ? sk[(size_t)b * 200 + t] : 0.f;
    __syncthreads();
    { float a = b1[t]; for (int k = 0; k < 200; ++k) a += xr[k] * W1[k * 256 + t];
      h1[t] = fmaxf(a, 0.f); }
    __syncthreads();
    { float a = b2[t]; for (int k = 0; k < 256; ++k) a += h1[k] * W2[k * 256 + t];
      h2[t] = fmaxf(a, 0.f); }
    __syncthreads();
    if (t < 100) { float a = b3[t]; for (int k = 0; k < 256; ++k) a += h2[k] * W3[k * 100 + t];
                   s3[t] = a; }
    __syncthreads();
    if (t < 128) {
        float base = actb[t] + ang[b] * actW[15 * 128 + t] +
                     px[b] * actW[16 * 128 + t] + py[b] * actW[17 * 128 + t];
        for (int k = 0; k < 100; ++k) base += s3[k] * actW[(18 + k) * 128 + t];
#pragma unroll
        for (int i = 0; i < 15; ++i) tg[i][t] = base + actW[i * 128 + t];
    }
    __syncthreads();

    // self QKV
#pragma unroll
    for (int pp = 0; pp < 2; ++pp) {
        const int n = pp * 256 + t;
        if (n < 384) {
            float acc[15];
#pragma unroll
            for (int r = 0; r < 15; ++r) acc[r] = 0.f;
            for (int k = 0; k < 128; ++k) {
                const float wv = saW[(size_t)k * 384 + n];
#pragma unroll
                for (int r = 0; r < 15; ++r) acc[r] += tg[r][k] * wv;
            }
            const float bb = sab[n];
#pragma unroll
            for (int r = 0; r < 15; ++r) qkv[r][n] = acc[r] + bb;
        }
    }
    __syncthreads();

    // self-attn: wave w = head
    const float rs = 0.17677669529663687f;
    for (int qi = 0; qi < 15; ++qi) {
        float s = -3.0e38f;
        if (l < 15) {
            s = 0.f;
            for (int d = 0; d < 32; ++d)
                s += qkv[qi][w * 32 + d] * qkv[l][128 + w * 32 + d];
            s *= rs;
        }
        const float m = wred_max(s);
        const float pv = (l < 15) ? __expf(s - m) : 0.f;
        const float sum = wred_sum(pv);
        if (l < 15) pbv[w][l] = pv;
        if (l < 32) {
            float o = 0.f;
#pragma unroll
            for (int j = 0; j < 15; ++j) o += pbv[w][j] * qkv[j][256 + w * 32 + l];
            ao[qi][w * 32 + l] = o / sum;
        }
    }
    __syncthreads();

    // SA out-proj + residual -> qkv scratch
    {
        const int c = t & 127, rh = t >> 7;
        for (int r = rh; r < 15; r += 2) {
            float acc = saob[c] + tg[r][c];
            for (int k = 0; k < 128; ++k) acc += ao[r][k] * saoW[(size_t)k * 128 + c];
            qkv[r][c] = acc;
        }
    }
    __syncthreads();
    // LN1 -> tg + TGo
    for (int r = w; r < 15; r += 4) {
        const float x0 = qkv[r][l], x1 = qkv[r][l + 64];
        const float sm = wred_sum(x0 + x1);
        const float sq = wred_sum(x0 * x0 + x1 * x1);
        const float mean = sm * 0.0078125f;
        const float rstd = rsqrtf(sq * 0.0078125f - mean * mean + 1e-5f);
        const float y0 = (x0 - mean) * rstd * ln1s[l] + ln1b[l];
        const float y1 = (x1 - mean) * rstd * ln1s[l + 64] + ln1b[l + 64];
        tg[r][l] = y0; tg[r][l + 64] = y1;
        float* g = TGo + ((size_t)r * 256 + b) * 128;
        g[l] = y0; g[l + 64] = y1;
    }
    __syncthreads();

    // cross Q
    {
        const int c = t & 127, rh = t >> 7;
        for (int r = rh; r < 15; r += 2) {
            float acc = cab[c];
            for (int k = 0; k < 128; ++k) acc += tg[r][k] * caW[(size_t)k * 384 + c];
            DQ[((size_t)r * 256 + b) * 128 + c] = acc;
        }
    }
}

// ---------------------------------------------------------------------------
// Fused decoder part 2 (one block per batch b):
// cross-out + resid + LN2; FF1; FF2 + resid + LN3; dec_norm; l1 + head dot.
// ---------------------------------------------------------------------------
__global__ __launch_bounds__(256) void k_dec2(
    const float* __restrict__ TGo, const float* __restrict__ AT,
    const float* __restrict__ caoW, const float* __restrict__ caob,
    const float* __restrict__ ln2s, const float* __restrict__ ln2b,
    const float* __restrict__ ff1W, const float* __restrict__ ff1b,
    const float* __restrict__ ff2W, const float* __restrict__ ff2b,
    const float* __restrict__ ln3s, const float* __restrict__ ln3b,
    const float* __restrict__ ns, const float* __restrict__ nb,
    const float* __restrict__ l1W, const float* __restrict__ l1b,
    const float* __restrict__ l2w, const float* __restrict__ l2b,
    float* __restrict__ qout)
{
    __shared__ float tg[15][128], ao[15][128], o2[15][128];
    __shared__ float ff[15][64];
    const int b = blockIdx.x, t = threadIdx.x;
    const int w = t >> 6, l = t & 63;

    for (int idx = t; idx < 1920; idx += 256) {
        const int r = idx >> 7, c = idx & 127;
        tg[r][c] = TGo[((size_t)r * 256 + b) * 128 + c];
        ao[r][c] = AT[((size_t)r * 256 + b) * 128 + c];
    }
    __syncthreads();

    // CA out-proj + residual
    {
        const int c = t & 127, rh = t >> 7;
        for (int r = rh; r < 15; r += 2) {
            float acc = caob[c] + tg[r][c];
            for (int k = 0; k < 128; ++k) acc += ao[r][k] * caoW[(size_t)k * 128 + c];
            o2[r][c] = acc;
        }
    }
    __syncthreads();
    // LN2 -> tg
    for (int r = w; r < 15; r += 4) {
        const float x0 = o2[r][l], x1 = o2[r][l + 64];
        const float sm = wred_sum(x0 + x1);
        const float sq = wred_sum(x0 * x0 + x1 * x1);
        const float mean = sm * 0.0078125f;
        const float rstd = rsqrtf(sq * 0.0078125f - mean * mean + 1e-5f);
        tg[r][l]      = (x0 - mean) * rstd * ln2s[l] + ln2b[l];
        tg[r][l + 64] = (x1 - mean) * rstd * ln2s[l + 64] + ln2b[l + 64];
    }
    __syncthreads();
    // FF1 (relu)
    {
        const int n = t & 63, rh = t >> 6;
        for (int r = rh; r < 15; r += 4) {
            float acc = ff1b[n];
            for (int k = 0; k < 128; ++k) acc += tg[r][k] * ff1W[(size_t)k * 64 + n];
            ff[r][n] = fmaxf(acc, 0.f);
        }
    }
    __syncthreads();
    // FF2 + residual
    {
        const int c = t & 127, rh = t >> 7;
        for (int r = rh; r < 15; r += 2) {
            float acc = ff2b[c] + tg[r][c];
            for (int k = 0; k < 64; ++k) acc += ff[r][k] * ff2W[(size_t)k * 128 + c];
            o2[r][c] = acc;
        }
    }
    __syncthreads();
    // LN3 then dec_norm -> tg
    for (int r = w; r < 15; r += 4) {
        const float x0 = o2[r][l], x1 = o2[r][l + 64];
        const float sm = wred_sum(x0 + x1);
        const float sq = wred_sum(x0 * x0 + x1 * x1);
        const float mean = sm * 0.0078125f;
        const float rstd = rsqrtf(sq * 0.0078125f - mean * mean + 1e-5f);
        const float y0 = (x0 - mean) * rstd * ln3s[l] + ln3b[l];
        const float y1 = (x1 - mean) * rstd * ln3s[l + 64] + ln3b[l + 64];
        const float sm2 = wred_sum(y0 + y1);
        const float sq2 = wred_sum(y0 * y0 + y1 * y1);
        const float mean2 = sm2 * 0.0078125f;
        const float rstd2 = rsqrtf(sq2 * 0.0078125f - mean2 * mean2 + 1e-5f);
        tg[r][l]      = (y0 - mean2) * rstd2 * ns[l] + nb[l];
        tg[r][l + 64] = (y1 - mean2) * rstd2 * ns[l + 64] + nb[l + 64];
    }
    __syncthreads();
    // l1 (relu)
    {
        const int c = t & 127, rh = t >> 7;
        for (int r = rh; r < 15; r += 2) {
            float acc = l1b[c];
            for (int k = 0; k < 128; ++k) acc += tg[r][k] * l1W[(size_t)k * 128 + c];
            o2[r][c] = fmaxf(acc, 0.f);
        }
    }
    __syncthreads();
    // head dot
    for (int r = w; r < 15; r += 4) {
        const float d = wred_sum(o2[r][l] * l2w[l] + o2[r][l + 64] * l2w[l + 64]);
        if (l == 0) qout[b * 15 + r] = d + l2b[0];
    }
}

// ---------------------------------------------------------------------------
extern "C" void kernel_launch(void* const* d_in, const int* in_sizes, int n_in,
                              void* d_out, int out_size, void* d_ws, size_t ws_size,
                              hipStream_t stream)
{
    (void)in_sizes; (void)n_in; (void)out_size; (void)ws_size;
    const float* image      = (const float*)d_in[0];
    const float* angle      = (const float*)d_in[1];
    const float* pos_x      = (const float*)d_in[2];
    const float* pos_y      = (const float*)d_in[3];
    const float* sk         = (const float*)d_in[4];
    const float* patch_W    = (const float*)d_in[5];
    const float* patch_b    = (const float*)d_in[6];
    const float* pos_emb    = (const float*)d_in[7];
    const float* enc_qkv_W  = (const float*)d_in[8];
    const float* enc_qkv_b  = (const float*)d_in[9];
    const float* enc_out_W  = (const float*)d_in[10];
    const float* enc_out_b  = (const float*)d_in[11];
    const float* enc_ln1_s  = (const float*)d_in[12];
    const float* enc_ln1_b  = (const float*)d_in[13];
    const float* enc_ff1_W  = (const float*)d_in[14];
    const float* enc_ff1_b  = (const float*)d_in[15];
    const float* enc_ff2_W  = (const float*)d_in[16];
    const float* enc_ff2_b  = (const float*)d_in[17];
    const float* enc_ln2_s  = (const float*)d_in[18];
    const float* enc_ln2_b  = (const float*)d_in[19];
    const float* dec_sa_qkv_W = (const float*)d_in[20];
    const float* dec_sa_qkv_b = (const float*)d_in[21];
    const float* dec_sa_out_W = (const float*)d_in[22];
    const float* dec_sa_out_b = (const float*)d_in[23];
    const float* dec_ca_qkv_W = (const float*)d_in[24];
    const float* dec_ca_qkv_b = (const float*)d_in[25];
    const float* dec_ca_out_W = (const float*)d_in[26];
    const float* dec_ca_out_b = (const float*)d_in[27];
    const float* dec_ln1_s  = (const float*)d_in[28];
    const float* dec_ln1_b  = (const float*)d_in[29];
    const float* dec_ln2_s  = (const float*)d_in[30];
    const float* dec_ln2_b  = (const float*)d_in[31];
    const float* dec_ln3_s  = (const float*)d_in[32];
    const float* dec_ln3_b  = (const float*)d_in[33];
    const float* dec_ff1_W  = (const float*)d_in[34];
    const float* dec_ff1_b  = (const float*)d_in[35];
    const float* dec_ff2_W  = (const float*)d_in[36];
    const float* dec_ff2_b  = (const float*)d_in[37];
    const float* dec_norm_s = (const float*)d_in[38];
    const float* dec_norm_b = (const float*)d_in[39];
    const float* sk1_W = (const float*)d_in[40];
    const float* sk1_b = (const float*)d_in[41];
    const float* sk2_W = (const float*)d_in[42];
    const float* sk2_b = (const float*)d_in[43];
    const float* sk3_W = (const float*)d_in[44];
    const float* sk3_b = (const float*)d_in[45];
    const float* act_W = (const float*)d_in[46];
    const float* act_b = (const float*)d_in[47];
    const float* l1_W  = (const float*)d_in[48];
    const float* l1_b  = (const float*)d_in[49];
    const float* l2_W  = (const float*)d_in[50];
    const float* l2_b  = (const float*)d_in[51];

    // Workspace (float offsets)
    float* ws = (float*)d_ws;
    float* S0   = ws;               // src f32 residual stream  [6,422,528]
    float* QKVr = ws + 6422528;     // big overlay region       [19,267,584]
    float* T0   = ws + 25690112;    // decoder cross-attn out   [6,422,528]
    float* T1   = ws + 32112640;    // M0b bf16 home            [6,422,528]
    float* F1   = ws + 38535168;    // F1b bf16                 [3,211,264]
    float* M0r  = ws + 41746432;    // srcb/T0b | lnb bf16      [6,422,528]
    float* S1s  = ws + 48168960;
    float* TG   = S1s + 156672;     // tgt f32 15*256*128
    ushort* WTS = (ushort*)(ws + 48817152);

    // Overlays
    ushort* QKVb = (ushort*)QKVr;            // enc QKV bf16 [50176][384]
    float*  KV   = QKVr;                     // cross K/V f32 [50176][256]
    float* DQ   = QKVr + 14319616;           // dec cross Q f32
    float* DT0  = T0;
    ushort* srcb = (ushort*)M0r;
    ushort* T0b  = (ushort*)M0r;             // disjoint lifetime with srcb
    ushort* lnb  = (ushort*)(M0r + 3211264);
    ushort* F1b  = (ushort*)F1;
    ushort* M0b  = (ushort*)T1;
    ushort* wt_patch = WTS;
    ushort* wt_qkv   = WTS + 98304;
    ushort* wt_out   = WTS + 147456;
    ushort* wt_ff1   = WTS + 163840;
    ushort* wt_ff2   = WTS + 172032;
    ushort* wt_ckv   = WTS + 180224;

    const float rs = 0.17677669529663687f;  // 1/sqrt(32)

    // ---- prep ----
    k_wconv<<<dim3(832), 256, 0, stream>>>(patch_W, enc_qkv_W, enc_out_W,
                                           enc_ff1_W, enc_ff2_W, dec_ca_qkv_W, WTS);
    k_dec1<<<dim3(256), 256, 0, stream>>>(
        sk, sk1_W, sk1_b, sk2_W, sk2_b, sk3_W, sk3_b,
        angle, pos_x, pos_y, act_W, act_b,
        dec_sa_qkv_W, dec_sa_qkv_b, dec_sa_out_W, dec_sa_out_b,
        dec_ln1_s, dec_ln1_b, dec_ca_qkv_W, dec_ca_qkv_b, TG, DQ);

    // ---- encoder ----
    k_pgemm<<<dim3(784), 256, 0, stream>>>(
        image, wt_patch, patch_b, pos_emb, S0, srcb);
    k_gemm_bf16<64, 128><<<dim3(784, 3), 256, 0, stream>>>(
        srcb, 128, wt_qkv, 128, enc_qkv_b, nullptr, QKVb, 384, nullptr, 0);
    k_attn_mfma<<<dim3(1024), 256, 0, stream>>>(QKVb, T0b, rs);
    k_gemm_ln<<<dim3(784), 256, 0, stream>>>(                 // out-proj + LN1
        T0b, 128, wt_out, 128, enc_out_b, S0, enc_ln1_s, enc_ln1_b, S0, lnb);
    k_gemm_bf16<64, 64><<<dim3(784, 1), 256, 0, stream>>>(    // FF1 + relu
        lnb, 128, wt_ff1, 128, enc_ff1_b, nullptr, F1b, 64, nullptr, 1);
    k_gemm_ln<<<dim3(784), 256, 0, stream>>>(                 // FF2 + LN2
        F1b, 64, wt_ff2, 64, enc_ff2_b, S0, enc_ln2_s, enc_ln2_b, nullptr, M0b);
    k_gemm_bf16<64, 128><<<dim3(784, 2), 256, 0, stream>>>(   // cross K/V
        M0b, 128, wt_ckv, 128, dec_ca_qkv_b + 128, KV, nullptr, 256, nullptr, 0);

    // ---- decoder cross-attn + tail ----
    k_attn<<<dim3(1024), 256, 0, stream>>>(DQ, 128, KV, 256, 0, 128,
                                           DT0, nullptr, 15, 196, rs);
    k_dec2<<<dim3(256), 256, 0, stream>>>(
        TG, DT0, dec_ca_out_W, dec_ca_out_b, dec_ln2_s, dec_ln2_b,
        dec_ff1_W, dec_ff1_b, dec_ff2_W, dec_ff2_b,
        dec_ln3_s, dec_ln3_b, dec_norm_s, dec_norm_b,
        l1_W, l1_b, l2_W, l2_b, (float*)d_out);
}